// Round 1
// baseline (1475.267 us; speedup 1.0000x reference)
//
#include <hip/hip_runtime.h>
#include <math.h>

#define BN 131072
#define DD 256
#define NE 4

typedef unsigned short u16;
typedef __bf16 bf16x8 __attribute__((ext_vector_type(8)));
typedef float f32x4 __attribute__((ext_vector_type(4)));

__device__ __forceinline__ u16 f2bf(float f) {
  union { float f; unsigned int u; } v; v.f = f;
  unsigned int u = v.u;
  unsigned int r = (u + 0x7FFFu + ((u >> 16) & 1u)) >> 16;
  return (u16)r;
}
__device__ __forceinline__ float bf2f(u16 x) {
  union { unsigned int u; float f; } v; v.u = ((unsigned int)x) << 16; return v.f;
}

// ---------------- workspace layout (d_ws) ----------------
// [0,32)    double psum[4]
// [32,48)   int    listpos[4]
// [48,64)   float  avg[4]
// [64, 64+4*BN*4)  int lists[4][BN]
//   NOTE: first 256KB of lists[0] is transiently reused as fp32 Wcomb
//   (k_wcomb writes it, k_swz reads it, both BEFORE k_gate writes lists).
// [2097216, +1572864) u16 swizzled bf16 weights (10 matrices)
// [3670080, +1024)    float bcomb[256]  (persists through expert kernels)
#define WS_SWZ_OFF 2097216
#define BCOMB_OFF  3670080

#define OFF_CW1  0
#define OFF_CW2  131072
#define OFF_MW1  196608
#define OFF_MW2  262144
#define OFF_AWQ  327680
#define OFF_AWK  393216
#define OFF_AWV  458752
#define OFF_WCB  524288
#define OFF_WWA  589824
#define OFF_WWO  720896
#define SWZ_TOTAL_GROUPS 98304   // 786432/8

// ============================================================
// init
// ============================================================
__global__ void k_init(int* __restrict__ listpos, double* __restrict__ psum) {
  int t = threadIdx.x;
  if (t < NE) { listpos[t] = 0; psum[t] = 0.0; }
}

// ============================================================
// Wcomb = Wo @ Wfc (fp32), bcomb = bo @ Wfc + bfc
// grid 257: blocks 0..255 -> one output row each; block 256 -> bcomb
// ============================================================
__global__ __launch_bounds__(256) void k_wcomb(
    const float* __restrict__ Wo, const float* __restrict__ bo,
    const float* __restrict__ Wfc, const float* __restrict__ bfc,
    float* __restrict__ Wc, float* __restrict__ bc) {
  int n = threadIdx.x;
  int k = blockIdx.x;
  if (k < 256) {
    float acc = 0.f;
    #pragma unroll 8
    for (int j = 0; j < 256; ++j) acc += Wo[k * 256 + j] * Wfc[j * 256 + n];
    Wc[k * 256 + n] = acc;
  } else {
    float acc = bfc[n];
    #pragma unroll 8
    for (int j = 0; j < 256; ++j) acc += bo[j] * Wfc[j * 256 + n];
    bc[n] = acc;
  }
}

// ============================================================
// weight swizzle: fp32 W[K x 256] -> bf16 in B-fragment order
// ============================================================
struct SwzArgs {
  const float* src[10];
  int KS[10];
  int lks[10];
  int dstoff[10];
  int gbase[10];
};

__global__ __launch_bounds__(256) void k_swz(SwzArgs a, u16* __restrict__ dst) {
  int g = blockIdx.x * 256 + threadIdx.x;
  if (g >= SWZ_TOTAL_GROUPS) return;
  int i = 0;
  #pragma unroll
  for (int t = 1; t < 10; ++t) if (g >= a.gbase[t]) i = t;
  int gl = g - a.gbase[i];
  int KS = a.KS[i], lks = a.lks[i];
  int l = gl & 63, t2 = gl >> 6;
  int ks = t2 & (KS - 1), ct = t2 >> lks;
  const float* src = a.src[i] + (size_t)(ks * 32 + ((l >> 4) << 3)) * 256 + ct * 16 + (l & 15);
  u16 tmp[8];
  #pragma unroll
  for (int j = 0; j < 8; ++j) tmp[j] = f2bf(src[(size_t)j * 256]);
  uint4 pk;
  pk.x = (unsigned)tmp[0] | ((unsigned)tmp[1] << 16);
  pk.y = (unsigned)tmp[2] | ((unsigned)tmp[3] << 16);
  pk.z = (unsigned)tmp[4] | ((unsigned)tmp[5] << 16);
  pk.w = (unsigned)tmp[6] | ((unsigned)tmp[7] << 16);
  *(uint4*)(dst + a.dstoff[i] + (size_t)gl * 8) = pk;
}

// ============================================================
// gating: fp64 accumulation, LDS-staged coalesced reads.
// ============================================================
__global__ __launch_bounds__(256) void k_gate(
    const float* __restrict__ zg, const float* __restrict__ zn,
    const float* __restrict__ gW, const float* __restrict__ gb,
    int* __restrict__ listpos, double* __restrict__ psum,
    int* __restrict__ lists) {
  __shared__ float xs[32 * 257];
  __shared__ double gwd[512 * 4];
  int tid = threadIdx.x, lane = tid & 63;
  int rowbase = blockIdx.x * 256;
  for (int i = tid; i < 2048; i += 256) gwd[i] = (double)gW[i];
  double l0 = (double)gb[0], l1 = (double)gb[1], l2 = (double)gb[2], l3 = (double)gb[3];

  for (int c = 0; c < 16; ++c) {
    const float* src = (c < 8) ? zg : zn;
    int ko = (c & 7) * 32;
    __syncthreads();
    #pragma unroll
    for (int j = 0; j < 8; ++j) {
      int idx = tid + j * 256;
      int row = idx >> 3, off = idx & 7;
      float4 v = *(const float4*)(src + (size_t)(rowbase + row) * DD + ko + off * 4);
      xs[(off * 4 + 0) * 257 + row] = v.x;
      xs[(off * 4 + 1) * 257 + row] = v.y;
      xs[(off * 4 + 2) * 257 + row] = v.z;
      xs[(off * 4 + 3) * 257 + row] = v.w;
    }
    __syncthreads();
    const double* gp = gwd + (size_t)(c * 32) * 4;
    #pragma unroll
    for (int i = 0; i < 32; ++i) {
      double x = (double)xs[i * 257 + tid];
      l0 = fma(x, gp[i * 4 + 0], l0);
      l1 = fma(x, gp[i * 4 + 1], l1);
      l2 = fma(x, gp[i * 4 + 2], l2);
      l3 = fma(x, gp[i * 4 + 3], l3);
    }
  }

  int row = rowbase + tid;
  int e = 0; double lm = l0;
  if (l1 > lm) { lm = l1; e = 1; }
  if (l2 > lm) { lm = l2; e = 2; }
  if (l3 > lm) { lm = l3; e = 3; }
  double s = exp(l0 - lm) + exp(l1 - lm) + exp(l2 - lm) + exp(l3 - lm);
  double p = 1.0 / s;

  #pragma unroll
  for (int ee = 0; ee < NE; ++ee) {
    bool mine = (e == ee);
    unsigned long long mask = __ballot(mine);
    int cnt = __popcll(mask);
    double pv = mine ? p : 0.0;
    #pragma unroll
    for (int off = 32; off; off >>= 1) pv += __shfl_down(pv, off);
    if (cnt) {
      int leader = __ffsll((unsigned long long)mask) - 1;
      int basev = 0;
      if (lane == leader) basev = atomicAdd(&listpos[ee], cnt);
      basev = __shfl(basev, leader);
      if (mine) {
        int rank = __popcll(mask & ((1ull << lane) - 1ull));
        lists[(size_t)ee * BN + basev + rank] = row;
      }
      if (lane == 0) atomicAdd(&psum[ee], pv);
    }
  }
}

__global__ void k_finalize(const int* __restrict__ listpos,
                           const double* __restrict__ psum,
                           float* __restrict__ avg, float* __restrict__ aux_out) {
  if (threadIdx.x == 0) {
    double aux = 0.0;
    for (int ee = 0; ee < NE; ++ee) {
      int c = listpos[ee];
      avg[ee] = (c > 0) ? (float)(psum[ee] / (double)c) : 0.0f;
      double u = (double)c / (double)BN;
      aux += u * u;
    }
    *aux_out = (float)(aux * (double)NE);
  }
}

// ============================================================
// MFMA tile core
// ============================================================
template <int KS, int RB>
__device__ __forceinline__ void mfma_gemm(const u16* __restrict__ A, int strideA,
                                          const u16* __restrict__ W,
                                          int wave, int lane, f32x4 acc[RB][4]) {
  int q = lane >> 4, m = lane & 15;
  #pragma unroll
  for (int ks = 0; ks < KS; ++ks) {
    bf16x8 a[RB];
    #pragma unroll
    for (int rb = 0; rb < RB; ++rb)
      a[rb] = *(const bf16x8*)(A + (rb * 16 + m) * strideA + ks * 32 + (q << 3));
    #pragma unroll
    for (int i = 0; i < 4; ++i) {
      int ct = wave * 4 + i;
      bf16x8 b = *(const bf16x8*)(W + (((ct * KS + ks) * 64 + lane) << 3));
      #pragma unroll
      for (int rb = 0; rb < RB; ++rb)
        acc[rb][i] = __builtin_amdgcn_mfma_f32_16x16x32_bf16(a[rb], b, acc[rb][i], 0, 0, 0);
    }
  }
}

// ============================================================
// Expert 0: concat
// ============================================================
__global__ __launch_bounds__(256) void k_concat(
    const float* __restrict__ zg, const float* __restrict__ zn,
    const u16* __restrict__ W1s, const float* __restrict__ b1,
    const u16* __restrict__ W2s, const float* __restrict__ b2,
    const int* __restrict__ listpos, const int* __restrict__ lists,
    const float* __restrict__ avgp, float* __restrict__ out) {
  __shared__ u16 X[32 * 520];
  __shared__ u16 H[32 * 264];
  __shared__ int rl[32];
  int n = listpos[0];
  const int* lst = lists + 0 * (size_t)BN;
  float scale = avgp[0];
  int tid = threadIdx.x, lane = tid & 63, wave = tid >> 6;
  int q = lane >> 4, m = lane & 15;

  for (int tile = blockIdx.x; tile * 32 < n; tile += gridDim.x) {
    int base = tile * 32;
    __syncthreads();
    if (tid < 32) rl[tid] = (base + tid < n) ? lst[base + tid] : -1;
    __syncthreads();
    #pragma unroll
    for (int j = 0; j < 16; ++j) {
      int t = tid + j * 256;
      int row = t >> 7, off = t & 127;
      int r = rl[row];
      float4 v = make_float4(0.f, 0.f, 0.f, 0.f);
      if (r >= 0)
        v = (off < 64) ? *(const float4*)(zg + (size_t)r * DD + off * 4)
                       : *(const float4*)(zn + (size_t)r * DD + (off - 64) * 4);
      ushort4 pk; pk.x = f2bf(v.x); pk.y = f2bf(v.y); pk.z = f2bf(v.z); pk.w = f2bf(v.w);
      *(ushort4*)(X + row * 520 + off * 4) = pk;
    }
    __syncthreads();
    f32x4 acc[2][4] = {};
    mfma_gemm<16, 2>(X, 520, W1s, wave, lane, acc);
    #pragma unroll
    for (int i = 0; i < 4; ++i) {
      int c = (wave * 4 + i) * 16 + m;
      float bb = b1[c];
      #pragma unroll
      for (int rb = 0; rb < 2; ++rb)
        #pragma unroll
        for (int r = 0; r < 4; ++r)
          H[(rb * 16 + q * 4 + r) * 264 + c] = f2bf(fmaxf(acc[rb][i][r] + bb, 0.f));
    }
    __syncthreads();
    f32x4 acc2[2][4] = {};
    mfma_gemm<8, 2>(H, 264, W2s, wave, lane, acc2);
    #pragma unroll
    for (int i = 0; i < 4; ++i) {
      int c = (wave * 4 + i) * 16 + m;
      float bb = b2[c];
      #pragma unroll
      for (int rb = 0; rb < 2; ++rb)
        #pragma unroll
        for (int r = 0; r < 4; ++r) {
          int row = rl[rb * 16 + q * 4 + r];
          if (row >= 0) out[(size_t)row * DD + c] = (acc2[rb][i][r] + bb) * scale;
        }
    }
  }
}

// ============================================================
// Expert 1: mul
// ============================================================
__global__ __launch_bounds__(256) void k_mul(
    const float* __restrict__ zg, const float* __restrict__ zn,
    const u16* __restrict__ W1s, const float* __restrict__ b1,
    const u16* __restrict__ W2s, const float* __restrict__ b2,
    const int* __restrict__ listpos, const int* __restrict__ lists,
    const float* __restrict__ avgp, float* __restrict__ out) {
  __shared__ u16 X[32 * 264];
  __shared__ u16 H[32 * 264];
  __shared__ int rl[32];
  int n = listpos[1];
  const int* lst = lists + 1 * (size_t)BN;
  float scale = avgp[1];
  int tid = threadIdx.x, lane = tid & 63, wave = tid >> 6;
  int q = lane >> 4, m = lane & 15;

  for (int tile = blockIdx.x; tile * 32 < n; tile += gridDim.x) {
    int base = tile * 32;
    __syncthreads();
    if (tid < 32) rl[tid] = (base + tid < n) ? lst[base + tid] : -1;
    __syncthreads();
    #pragma unroll
    for (int j = 0; j < 8; ++j) {
      int t = tid + j * 256;
      int row = t >> 6, off = t & 63;
      int r = rl[row];
      float4 v = make_float4(0.f, 0.f, 0.f, 0.f);
      if (r >= 0) {
        float4 g = *(const float4*)(zg + (size_t)r * DD + off * 4);
        float4 h = *(const float4*)(zn + (size_t)r * DD + off * 4);
        v = make_float4(g.x * h.x, g.y * h.y, g.z * h.z, g.w * h.w);
      }
      ushort4 pk; pk.x = f2bf(v.x); pk.y = f2bf(v.y); pk.z = f2bf(v.z); pk.w = f2bf(v.w);
      *(ushort4*)(X + row * 264 + off * 4) = pk;
    }
    __syncthreads();
    f32x4 acc[2][4] = {};
    mfma_gemm<8, 2>(X, 264, W1s, wave, lane, acc);
    #pragma unroll
    for (int i = 0; i < 4; ++i) {
      int c = (wave * 4 + i) * 16 + m;
      float bb = b1[c];
      #pragma unroll
      for (int rb = 0; rb < 2; ++rb)
        #pragma unroll
        for (int r = 0; r < 4; ++r)
          H[(rb * 16 + q * 4 + r) * 264 + c] = f2bf(fmaxf(acc[rb][i][r] + bb, 0.f));
    }
    __syncthreads();
    f32x4 acc2[2][4] = {};
    mfma_gemm<8, 2>(H, 264, W2s, wave, lane, acc2);
    #pragma unroll
    for (int i = 0; i < 4; ++i) {
      int c = (wave * 4 + i) * 16 + m;
      float bb = b2[c];
      #pragma unroll
      for (int rb = 0; rb < 2; ++rb)
        #pragma unroll
        for (int r = 0; r < 4; ++r) {
          int row = rl[rb * 16 + q * 4 + r];
          if (row >= 0) out[(size_t)row * DD + c] = (acc2[rb][i][r] + bb) * scale;
        }
    }
  }
}

// ============================================================
// Expert 3: wsum
// ============================================================
__global__ __launch_bounds__(256) void k_wsum(
    const float* __restrict__ zg, const float* __restrict__ zn,
    const u16* __restrict__ Was, const float* __restrict__ ba,
    const u16* __restrict__ Wos, const float* __restrict__ bo,
    const int* __restrict__ listpos, const int* __restrict__ lists,
    const float* __restrict__ avgp, float* __restrict__ out) {
  __shared__ u16 X[32 * 520];
  __shared__ u16 H[32 * 264];
  __shared__ int rl[32];
  int n = listpos[3];
  const int* lst = lists + 3 * (size_t)BN;
  float scale = avgp[3];
  int tid = threadIdx.x, lane = tid & 63, wave = tid >> 6;
  int q = lane >> 4, m = lane & 15;

  for (int tile = blockIdx.x; tile * 32 < n; tile += gridDim.x) {
    int base = tile * 32;
    __syncthreads();
    if (tid < 32) rl[tid] = (base + tid < n) ? lst[base + tid] : -1;
    __syncthreads();
    #pragma unroll
    for (int j = 0; j < 16; ++j) {
      int t = tid + j * 256;
      int row = t >> 7, off = t & 127;
      int r = rl[row];
      float4 v = make_float4(0.f, 0.f, 0.f, 0.f);
      if (r >= 0)
        v = (off < 64) ? *(const float4*)(zg + (size_t)r * DD + off * 4)
                       : *(const float4*)(zn + (size_t)r * DD + (off - 64) * 4);
      ushort4 pk; pk.x = f2bf(v.x); pk.y = f2bf(v.y); pk.z = f2bf(v.z); pk.w = f2bf(v.w);
      *(ushort4*)(X + row * 520 + off * 4) = pk;
    }
    __syncthreads();
    f32x4 acc[2][4] = {};
    mfma_gemm<16, 2>(X, 520, Was, wave, lane, acc);
    #pragma unroll
    for (int i = 0; i < 4; ++i) {
      int c = (wave * 4 + i) * 16 + m;
      float bb = ba[c];
      #pragma unroll
      for (int rb = 0; rb < 2; ++rb)
        #pragma unroll
        for (int r = 0; r < 4; ++r) {
          int vr = rb * 16 + q * 4 + r;
          float al = 1.f / (1.f + __expf(-(acc[rb][i][r] + bb)));
          float xg = bf2f(X[vr * 520 + c]);
          float xn = bf2f(X[vr * 520 + 256 + c]);
          H[vr * 264 + c] = f2bf(al * xg + (1.f - al) * xn);
        }
    }
    __syncthreads();
    f32x4 acc2[2][4] = {};
    mfma_gemm<8, 2>(H, 264, Wos, wave, lane, acc2);
    #pragma unroll
    for (int i = 0; i < 4; ++i) {
      int c = (wave * 4 + i) * 16 + m;
      float bb = bo[c];
      #pragma unroll
      for (int rb = 0; rb < 2; ++rb)
        #pragma unroll
        for (int r = 0; r < 4; ++r) {
          int row = rl[rb * 16 + q * 4 + r];
          if (row >= 0) out[(size_t)row * DD + c] = (acc2[rb][i][r] + bb) * scale;
        }
    }
  }
}

// ============================================================
// Expert 2: attention, restructured.
// Uses the identity: mean_pos(o @ Wo + bo) @ Wfc + bfc
//                  = M @ (Wo@Wfc) + (bo@Wfc + bfc)
// where M[r] = sum_kp c_kp * v[kp],  c_kp = 0.5*(a(0,kp)+a(1,kp)) per head.
// Passes per tile: stage X -> Q -> K -> scores -> {coeffs || V} -> combine -> final GEMM.
// LDS aliasing: V overwrites Qb; M overwrites Kb. 52.3 KB -> 3 blocks/CU.
// ============================================================
__global__ __launch_bounds__(256, 3) void k_attn(
    const float* __restrict__ zg, const float* __restrict__ zn,
    const u16* __restrict__ Wqs, const float* __restrict__ bq,
    const u16* __restrict__ Wks, const float* __restrict__ bk,
    const u16* __restrict__ Wvs, const float* __restrict__ bv,
    const u16* __restrict__ Wcs, const float* __restrict__ bc,
    const int* __restrict__ listpos, const int* __restrict__ lists,
    const float* __restrict__ avgp, float* __restrict__ out) {
  __shared__ u16 X[32 * 264];
  __shared__ u16 Qb[32 * 264];   // Q, later V
  __shared__ u16 Kb[32 * 264];   // K, later M (rows 0..15)
  __shared__ float SC[256];
  __shared__ float CF[128];      // coeffs: [(r*4+h)*2 + kp]
  __shared__ int rl[16];
  int n = listpos[2];
  const int* lst = lists + 2 * (size_t)BN;
  float scale = avgp[2];
  int tid = threadIdx.x, lane = tid & 63, wave = tid >> 6;
  int q = lane >> 4, m = lane & 15;

  for (int tile = blockIdx.x; tile * 16 < n; tile += gridDim.x) {
    int base = tile * 16;
    __syncthreads();
    if (tid < 16) rl[tid] = (base + tid < n) ? lst[base + tid] : -1;
    __syncthreads();
    // stage X: vrow v = 2r+pos; pos0 = zg, pos1 = zn
    #pragma unroll
    for (int j = 0; j < 8; ++j) {
      int t = tid + j * 256;
      int v = t >> 6, off = t & 63;
      int r = rl[v >> 1];
      float4 val = make_float4(0.f, 0.f, 0.f, 0.f);
      if (r >= 0)
        val = (v & 1) ? *(const float4*)(zn + (size_t)r * DD + off * 4)
                      : *(const float4*)(zg + (size_t)r * DD + off * 4);
      ushort4 pk; pk.x = f2bf(val.x); pk.y = f2bf(val.y); pk.z = f2bf(val.z); pk.w = f2bf(val.w);
      *(ushort4*)(X + v * 264 + off * 4) = pk;
    }
    __syncthreads();
    // ---- Q pass ----
    {
      f32x4 a1[2][4] = {};
      mfma_gemm<8, 2>(X, 264, Wqs, wave, lane, a1);
      #pragma unroll
      for (int i = 0; i < 4; ++i) {
        int c = (wave * 4 + i) * 16 + m;
        float bb = bq[c];
        #pragma unroll
        for (int rb = 0; rb < 2; ++rb)
          #pragma unroll
          for (int r = 0; r < 4; ++r)
            Qb[(rb * 16 + q * 4 + r) * 264 + c] = f2bf(a1[rb][i][r] + bb);
      }
    }
    __syncthreads();
    // ---- K pass ----
    {
      f32x4 a1[2][4] = {};
      mfma_gemm<8, 2>(X, 264, Wks, wave, lane, a1);
      #pragma unroll
      for (int i = 0; i < 4; ++i) {
        int c = (wave * 4 + i) * 16 + m;
        float bb = bk[c];
        #pragma unroll
        for (int rb = 0; rb < 2; ++rb)
          #pragma unroll
          for (int r = 0; r < 4; ++r)
            Kb[(rb * 16 + q * 4 + r) * 264 + c] = f2bf(a1[rb][i][r] + bb);
      }
    }
    __syncthreads();
    // scores: t = r*16 + h*4 + qp*2 + kp
    {
      int kp = tid & 1, qp = (tid >> 1) & 1, h = (tid >> 2) & 3, r = tid >> 4;
      const unsigned int* Qu = (const unsigned int*)Qb;
      const unsigned int* Ku = (const unsigned int*)Kb;
      int qrow = (2 * r + qp) * 132 + h * 32;
      int krow = (2 * r + kp) * 132 + h * 32;
      float s = 0.f;
      #pragma unroll 8
      for (int d = 0; d < 32; ++d) {
        unsigned int qu = Qu[qrow + d], ku = Ku[krow + d];
        s += bf2f((u16)(qu & 0xffff)) * bf2f((u16)(ku & 0xffff))
           + bf2f((u16)(qu >> 16)) * bf2f((u16)(ku >> 16));
      }
      SC[tid] = s * 0.125f;
    }
    __syncthreads();
    // coeffs (threads 0..127) run alongside the V pass (all threads).
    if (tid < 128) {
      int kp = tid & 1, h = (tid >> 1) & 3, r = tid >> 3;
      int b4 = r * 16 + h * 4;
      float s0k = SC[b4 + kp],     s0o = SC[b4 + (kp ^ 1)];
      float s1k = SC[b4 + 2 + kp], s1o = SC[b4 + 2 + (kp ^ 1)];
      float a0 = 1.f / (1.f + __expf(s0o - s0k));
      float a1 = 1.f / (1.f + __expf(s1o - s1k));
      CF[(r * 4 + h) * 2 + kp] = 0.5f * (a0 + a1);
    }
    // ---- V pass (writes into Qb region; Q reads completed last pass) ----
    {
      f32x4 a1[2][4] = {};
      mfma_gemm<8, 2>(X, 264, Wvs, wave, lane, a1);
      #pragma unroll
      for (int i = 0; i < 4; ++i) {
        int c = (wave * 4 + i) * 16 + m;
        float bb = bv[c];
        #pragma unroll
        for (int rb = 0; rb < 2; ++rb)
          #pragma unroll
          for (int r = 0; r < 4; ++r)
            Qb[(rb * 16 + q * 4 + r) * 264 + c] = f2bf(a1[rb][i][r] + bb);
      }
    }
    __syncthreads();
    // combine: M[r] = c0*v[2r] + c1*v[2r+1]  -> Kb rows 0..15
    {
      const unsigned int* Vu = (const unsigned int*)Qb;
      unsigned int* Mu = (unsigned int*)Kb;
      #pragma unroll
      for (int j = 0; j < 8; ++j) {
        int idx = tid + j * 256;      // 16 rows x 128 u32-cols
        int r = idx >> 7, cu = idx & 127;
        int h = cu >> 5;
        float c0 = CF[(r * 4 + h) * 2], c1 = CF[(r * 4 + h) * 2 + 1];
        unsigned int v0 = Vu[(2 * r) * 132 + cu], v1 = Vu[(2 * r + 1) * 132 + cu];
        float lo = c0 * bf2f((u16)(v0 & 0xffff)) + c1 * bf2f((u16)(v1 & 0xffff));
        float hi = c0 * bf2f((u16)(v0 >> 16)) + c1 * bf2f((u16)(v1 >> 16));
        Mu[r * 132 + cu] = (unsigned int)f2bf(lo) | ((unsigned int)f2bf(hi) << 16);
      }
    }
    __syncthreads();
    // out = M @ Wcomb + bcomb
    {
      f32x4 acc3[1][4] = {};
      mfma_gemm<8, 1>(Kb, 264, Wcs, wave, lane, acc3);
      #pragma unroll
      for (int i = 0; i < 4; ++i) {
        int c = (wave * 4 + i) * 16 + m;
        float bb = bc[c];
        #pragma unroll
        for (int r = 0; r < 4; ++r) {
          int row = rl[q * 4 + r];
          if (row >= 0) out[(size_t)row * DD + c] = (acc3[0][i][r] + bb) * scale;
        }
      }
    }
  }
}

// ============================================================
// launch
// ============================================================
extern "C" void kernel_launch(void* const* d_in, const int* in_sizes, int n_in,
                              void* d_out, int out_size, void* d_ws, size_t ws_size,
                              hipStream_t stream) {
  const float* zg   = (const float*)d_in[0];
  const float* zn   = (const float*)d_in[1];
  const float* gW   = (const float*)d_in[2];
  const float* gb   = (const float*)d_in[3];
  const float* cW1  = (const float*)d_in[4];
  const float* cb1  = (const float*)d_in[5];
  const float* cW2  = (const float*)d_in[6];
  const float* cb2  = (const float*)d_in[7];
  const float* mW1  = (const float*)d_in[8];
  const float* mb1  = (const float*)d_in[9];
  const float* mW2  = (const float*)d_in[10];
  const float* mb2  = (const float*)d_in[11];
  const float* aWq  = (const float*)d_in[12];
  const float* abq  = (const float*)d_in[13];
  const float* aWk  = (const float*)d_in[14];
  const float* abk  = (const float*)d_in[15];
  const float* aWv  = (const float*)d_in[16];
  const float* abv  = (const float*)d_in[17];
  const float* aWo  = (const float*)d_in[18];
  const float* abo  = (const float*)d_in[19];
  const float* aWfc = (const float*)d_in[20];
  const float* abfc = (const float*)d_in[21];
  const float* wWa  = (const float*)d_in[22];
  const float* wba  = (const float*)d_in[23];
  const float* wWo  = (const float*)d_in[24];
  const float* wbo  = (const float*)d_in[25];
  float* out = (float*)d_out;

  char* ws = (char*)d_ws;
  double* psum  = (double*)ws;
  int* listpos  = (int*)(ws + 32);
  float* avg    = (float*)(ws + 48);
  int* lists    = (int*)(ws + 64);
  u16* wsw      = (u16*)(ws + WS_SWZ_OFF);
  float* wcf32  = (float*)(ws + 64);          // transient: overlaps lists[0]
  float* bcomb  = (float*)(ws + BCOMB_OFF);   // persistent

  SwzArgs sa;
  const float* srcs[10] = {cW1, cW2, mW1, mW2, aWq, aWk, aWv, wcf32, wWa, wWo};
  const int   kss[10]  = {16, 8, 8, 8, 8, 8, 8, 8, 16, 8};
  const int   offs[10] = {OFF_CW1, OFF_CW2, OFF_MW1, OFF_MW2, OFF_AWQ, OFF_AWK,
                          OFF_AWV, OFF_WCB, OFF_WWA, OFF_WWO};
  int gb_acc = 0;
  for (int i = 0; i < 10; ++i) {
    sa.src[i] = srcs[i];
    sa.KS[i] = kss[i];
    sa.lks[i] = (kss[i] == 16) ? 4 : 3;
    sa.dstoff[i] = offs[i];
    sa.gbase[i] = gb_acc;
    gb_acc += kss[i] * 1024;
  }

  hipLaunchKernelGGL(k_init, dim3(1), dim3(64), 0, stream, listpos, psum);
  hipLaunchKernelGGL(k_wcomb, dim3(257), dim3(256), 0, stream,
                     aWo, abo, aWfc, abfc, wcf32, bcomb);
  hipLaunchKernelGGL(k_swz, dim3(SWZ_TOTAL_GROUPS / 256), dim3(256), 0, stream, sa, wsw);
  hipLaunchKernelGGL(k_gate, dim3(BN / 256), dim3(256), 0, stream,
                     zg, zn, gW, gb, listpos, psum, lists);
  hipLaunchKernelGGL(k_finalize, dim3(1), dim3(64), 0, stream,
                     listpos, psum, avg, out + (size_t)BN * DD);
  hipLaunchKernelGGL(k_concat, dim3(1024), dim3(256), 0, stream,
                     zg, zn, wsw + OFF_CW1, cb1, wsw + OFF_CW2, cb2, listpos, lists, avg, out);
  hipLaunchKernelGGL(k_mul, dim3(1024), dim3(256), 0, stream,
                     zg, zn, wsw + OFF_MW1, mb1, wsw + OFF_MW2, mb2, listpos, lists, avg, out);
  hipLaunchKernelGGL(k_attn, dim3(2048), dim3(256), 0, stream,
                     zg, zn, wsw + OFF_AWQ, abq, wsw + OFF_AWK, abk, wsw + OFF_AWV, abv,
                     wsw + OFF_WCB, bcomb, listpos, lists, avg, out);
  hipLaunchKernelGGL(k_wsum, dim3(1024), dim3(256), 0, stream,
                     zg, zn, wsw + OFF_WWA, wba, wsw + OFF_WWO, wbo, listpos, lists, avg, out);
}

// Round 2
// 1129.287 us; speedup vs baseline: 1.3064x; 1.3064x over previous
//
#include <hip/hip_runtime.h>
#include <math.h>

#define BN 131072
#define DD 256
#define NE 4

typedef unsigned short u16;
typedef __bf16 bf16x8 __attribute__((ext_vector_type(8)));
typedef float f32x4 __attribute__((ext_vector_type(4)));

__device__ __forceinline__ u16 f2bf(float f) {
  union { float f; unsigned int u; } v; v.f = f;
  unsigned int u = v.u;
  unsigned int r = (u + 0x7FFFu + ((u >> 16) & 1u)) >> 16;
  return (u16)r;
}
__device__ __forceinline__ float bf2f(u16 x) {
  union { unsigned int u; float f; } v; v.u = ((unsigned int)x) << 16; return v.f;
}

// ---------------- workspace layout (d_ws) ----------------
// [0,32)    double psum[4]
// [32,48)   int    listpos[4]
// [48,64)   float  avg[4]
// [64, 64+4*BN*4)  int lists[4][BN]
//   NOTE: first 256KB of lists[0] is transiently reused as fp32 Wcomb
//   (k_wcomb writes it, k_swz reads it, both BEFORE k_gate writes lists).
// [2097216, +1572864) u16 swizzled bf16 weights (10 matrices)
// [3670080, +1024)    float bcomb[256]  (persists through expert kernels)
#define WS_SWZ_OFF 2097216
#define BCOMB_OFF  3670080

#define OFF_CW1  0
#define OFF_CW2  131072
#define OFF_MW1  196608
#define OFF_MW2  262144
#define OFF_AWQ  327680
#define OFF_AWK  393216
#define OFF_AWV  458752
#define OFF_WCB  524288
#define OFF_WWA  589824
#define OFF_WWO  720896
#define SWZ_TOTAL_GROUPS 98304   // 786432/8

// ============================================================
// init
// ============================================================
__global__ void k_init(int* __restrict__ listpos, double* __restrict__ psum) {
  int t = threadIdx.x;
  if (t < NE) { listpos[t] = 0; psum[t] = 0.0; }
}

// ============================================================
// Wcomb = Wo @ Wfc (fp32), bcomb = bo @ Wfc + bfc
// ============================================================
__global__ __launch_bounds__(256) void k_wcomb(
    const float* __restrict__ Wo, const float* __restrict__ bo,
    const float* __restrict__ Wfc, const float* __restrict__ bfc,
    float* __restrict__ Wc, float* __restrict__ bc) {
  int n = threadIdx.x;
  int k = blockIdx.x;
  if (k < 256) {
    float acc = 0.f;
    #pragma unroll 8
    for (int j = 0; j < 256; ++j) acc += Wo[k * 256 + j] * Wfc[j * 256 + n];
    Wc[k * 256 + n] = acc;
  } else {
    float acc = bfc[n];
    #pragma unroll 8
    for (int j = 0; j < 256; ++j) acc += bo[j] * Wfc[j * 256 + n];
    bc[n] = acc;
  }
}

// ============================================================
// weight swizzle: fp32 W[K x 256] -> bf16 in B-fragment order
// ============================================================
struct SwzArgs {
  const float* src[10];
  int KS[10];
  int lks[10];
  int dstoff[10];
  int gbase[10];
};

__global__ __launch_bounds__(256) void k_swz(SwzArgs a, u16* __restrict__ dst) {
  int g = blockIdx.x * 256 + threadIdx.x;
  if (g >= SWZ_TOTAL_GROUPS) return;
  int i = 0;
  #pragma unroll
  for (int t = 1; t < 10; ++t) if (g >= a.gbase[t]) i = t;
  int gl = g - a.gbase[i];
  int KS = a.KS[i], lks = a.lks[i];
  int l = gl & 63, t2 = gl >> 6;
  int ks = t2 & (KS - 1), ct = t2 >> lks;
  const float* src = a.src[i] + (size_t)(ks * 32 + ((l >> 4) << 3)) * 256 + ct * 16 + (l & 15);
  u16 tmp[8];
  #pragma unroll
  for (int j = 0; j < 8; ++j) tmp[j] = f2bf(src[(size_t)j * 256]);
  uint4 pk;
  pk.x = (unsigned)tmp[0] | ((unsigned)tmp[1] << 16);
  pk.y = (unsigned)tmp[2] | ((unsigned)tmp[3] << 16);
  pk.z = (unsigned)tmp[4] | ((unsigned)tmp[5] << 16);
  pk.w = (unsigned)tmp[6] | ((unsigned)tmp[7] << 16);
  *(uint4*)(dst + a.dstoff[i] + (size_t)gl * 8) = pk;
}

// ============================================================
// gating: fp64 accumulation, LDS-staged coalesced reads.
// ============================================================
__global__ __launch_bounds__(256) void k_gate(
    const float* __restrict__ zg, const float* __restrict__ zn,
    const float* __restrict__ gW, const float* __restrict__ gb,
    int* __restrict__ listpos, double* __restrict__ psum,
    int* __restrict__ lists) {
  __shared__ float xs[32 * 257];
  __shared__ double gwd[512 * 4];
  int tid = threadIdx.x, lane = tid & 63;
  int rowbase = blockIdx.x * 256;
  for (int i = tid; i < 2048; i += 256) gwd[i] = (double)gW[i];
  double l0 = (double)gb[0], l1 = (double)gb[1], l2 = (double)gb[2], l3 = (double)gb[3];

  for (int c = 0; c < 16; ++c) {
    const float* src = (c < 8) ? zg : zn;
    int ko = (c & 7) * 32;
    __syncthreads();
    #pragma unroll
    for (int j = 0; j < 8; ++j) {
      int idx = tid + j * 256;
      int row = idx >> 3, off = idx & 7;
      float4 v = *(const float4*)(src + (size_t)(rowbase + row) * DD + ko + off * 4);
      xs[(off * 4 + 0) * 257 + row] = v.x;
      xs[(off * 4 + 1) * 257 + row] = v.y;
      xs[(off * 4 + 2) * 257 + row] = v.z;
      xs[(off * 4 + 3) * 257 + row] = v.w;
    }
    __syncthreads();
    const double* gp = gwd + (size_t)(c * 32) * 4;
    #pragma unroll
    for (int i = 0; i < 32; ++i) {
      double x = (double)xs[i * 257 + tid];
      l0 = fma(x, gp[i * 4 + 0], l0);
      l1 = fma(x, gp[i * 4 + 1], l1);
      l2 = fma(x, gp[i * 4 + 2], l2);
      l3 = fma(x, gp[i * 4 + 3], l3);
    }
  }

  int row = rowbase + tid;
  int e = 0; double lm = l0;
  if (l1 > lm) { lm = l1; e = 1; }
  if (l2 > lm) { lm = l2; e = 2; }
  if (l3 > lm) { lm = l3; e = 3; }
  double s = exp(l0 - lm) + exp(l1 - lm) + exp(l2 - lm) + exp(l3 - lm);
  double p = 1.0 / s;

  #pragma unroll
  for (int ee = 0; ee < NE; ++ee) {
    bool mine = (e == ee);
    unsigned long long mask = __ballot(mine);
    int cnt = __popcll(mask);
    double pv = mine ? p : 0.0;
    #pragma unroll
    for (int off = 32; off; off >>= 1) pv += __shfl_down(pv, off);
    if (cnt) {
      int leader = __ffsll((unsigned long long)mask) - 1;
      int basev = 0;
      if (lane == leader) basev = atomicAdd(&listpos[ee], cnt);
      basev = __shfl(basev, leader);
      if (mine) {
        int rank = __popcll(mask & ((1ull << lane) - 1ull));
        lists[(size_t)ee * BN + basev + rank] = row;
      }
      if (lane == 0) atomicAdd(&psum[ee], pv);
    }
  }
}

__global__ void k_finalize(const int* __restrict__ listpos,
                           const double* __restrict__ psum,
                           float* __restrict__ avg, float* __restrict__ aux_out) {
  if (threadIdx.x == 0) {
    double aux = 0.0;
    for (int ee = 0; ee < NE; ++ee) {
      int c = listpos[ee];
      avg[ee] = (c > 0) ? (float)(psum[ee] / (double)c) : 0.0f;
      double u = (double)c / (double)BN;
      aux += u * u;
    }
    *aux_out = (float)(aux * (double)NE);
  }
}

// ============================================================
// MFMA tile core
// ============================================================
template <int KS, int RB>
__device__ __forceinline__ void mfma_gemm(const u16* __restrict__ A, int strideA,
                                          const u16* __restrict__ W,
                                          int wave, int lane, f32x4 acc[RB][4]) {
  int q = lane >> 4, m = lane & 15;
  #pragma unroll
  for (int ks = 0; ks < KS; ++ks) {
    bf16x8 a[RB];
    #pragma unroll
    for (int rb = 0; rb < RB; ++rb)
      a[rb] = *(const bf16x8*)(A + (rb * 16 + m) * strideA + ks * 32 + (q << 3));
    #pragma unroll
    for (int i = 0; i < 4; ++i) {
      int ct = wave * 4 + i;
      bf16x8 b = *(const bf16x8*)(W + (((ct * KS + ks) * 64 + lane) << 3));
      #pragma unroll
      for (int rb = 0; rb < RB; ++rb)
        acc[rb][i] = __builtin_amdgcn_mfma_f32_16x16x32_bf16(a[rb], b, acc[rb][i], 0, 0, 0);
    }
  }
}

// ============================================================
// Expert 0: concat
// ============================================================
__global__ __launch_bounds__(256) void k_concat(
    const float* __restrict__ zg, const float* __restrict__ zn,
    const u16* __restrict__ W1s, const float* __restrict__ b1,
    const u16* __restrict__ W2s, const float* __restrict__ b2,
    const int* __restrict__ listpos, const int* __restrict__ lists,
    const float* __restrict__ avgp, float* __restrict__ out) {
  __shared__ u16 X[32 * 520];
  __shared__ u16 H[32 * 264];
  __shared__ int rl[32];
  int n = listpos[0];
  const int* lst = lists + 0 * (size_t)BN;
  float scale = avgp[0];
  int tid = threadIdx.x, lane = tid & 63, wave = tid >> 6;
  int q = lane >> 4, m = lane & 15;

  for (int tile = blockIdx.x; tile * 32 < n; tile += gridDim.x) {
    int base = tile * 32;
    __syncthreads();
    if (tid < 32) rl[tid] = (base + tid < n) ? lst[base + tid] : -1;
    __syncthreads();
    #pragma unroll
    for (int j = 0; j < 16; ++j) {
      int t = tid + j * 256;
      int row = t >> 7, off = t & 127;
      int r = rl[row];
      float4 v = make_float4(0.f, 0.f, 0.f, 0.f);
      if (r >= 0)
        v = (off < 64) ? *(const float4*)(zg + (size_t)r * DD + off * 4)
                       : *(const float4*)(zn + (size_t)r * DD + (off - 64) * 4);
      ushort4 pk; pk.x = f2bf(v.x); pk.y = f2bf(v.y); pk.z = f2bf(v.z); pk.w = f2bf(v.w);
      *(ushort4*)(X + row * 520 + off * 4) = pk;
    }
    __syncthreads();
    f32x4 acc[2][4] = {};
    mfma_gemm<16, 2>(X, 520, W1s, wave, lane, acc);
    #pragma unroll
    for (int i = 0; i < 4; ++i) {
      int c = (wave * 4 + i) * 16 + m;
      float bb = b1[c];
      #pragma unroll
      for (int rb = 0; rb < 2; ++rb)
        #pragma unroll
        for (int r = 0; r < 4; ++r)
          H[(rb * 16 + q * 4 + r) * 264 + c] = f2bf(fmaxf(acc[rb][i][r] + bb, 0.f));
    }
    __syncthreads();
    f32x4 acc2[2][4] = {};
    mfma_gemm<8, 2>(H, 264, W2s, wave, lane, acc2);
    #pragma unroll
    for (int i = 0; i < 4; ++i) {
      int c = (wave * 4 + i) * 16 + m;
      float bb = b2[c];
      #pragma unroll
      for (int rb = 0; rb < 2; ++rb)
        #pragma unroll
        for (int r = 0; r < 4; ++r) {
          int row = rl[rb * 16 + q * 4 + r];
          if (row >= 0) out[(size_t)row * DD + c] = (acc2[rb][i][r] + bb) * scale;
        }
    }
  }
}

// ============================================================
// Expert 1: mul
// ============================================================
__global__ __launch_bounds__(256) void k_mul(
    const float* __restrict__ zg, const float* __restrict__ zn,
    const u16* __restrict__ W1s, const float* __restrict__ b1,
    const u16* __restrict__ W2s, const float* __restrict__ b2,
    const int* __restrict__ listpos, const int* __restrict__ lists,
    const float* __restrict__ avgp, float* __restrict__ out) {
  __shared__ u16 X[32 * 264];
  __shared__ u16 H[32 * 264];
  __shared__ int rl[32];
  int n = listpos[1];
  const int* lst = lists + 1 * (size_t)BN;
  float scale = avgp[1];
  int tid = threadIdx.x, lane = tid & 63, wave = tid >> 6;
  int q = lane >> 4, m = lane & 15;

  for (int tile = blockIdx.x; tile * 32 < n; tile += gridDim.x) {
    int base = tile * 32;
    __syncthreads();
    if (tid < 32) rl[tid] = (base + tid < n) ? lst[base + tid] : -1;
    __syncthreads();
    #pragma unroll
    for (int j = 0; j < 8; ++j) {
      int t = tid + j * 256;
      int row = t >> 6, off = t & 63;
      int r = rl[row];
      float4 v = make_float4(0.f, 0.f, 0.f, 0.f);
      if (r >= 0) {
        float4 g = *(const float4*)(zg + (size_t)r * DD + off * 4);
        float4 h = *(const float4*)(zn + (size_t)r * DD + off * 4);
        v = make_float4(g.x * h.x, g.y * h.y, g.z * h.z, g.w * h.w);
      }
      ushort4 pk; pk.x = f2bf(v.x); pk.y = f2bf(v.y); pk.z = f2bf(v.z); pk.w = f2bf(v.w);
      *(ushort4*)(X + row * 264 + off * 4) = pk;
    }
    __syncthreads();
    f32x4 acc[2][4] = {};
    mfma_gemm<8, 2>(X, 264, W1s, wave, lane, acc);
    #pragma unroll
    for (int i = 0; i < 4; ++i) {
      int c = (wave * 4 + i) * 16 + m;
      float bb = b1[c];
      #pragma unroll
      for (int rb = 0; rb < 2; ++rb)
        #pragma unroll
        for (int r = 0; r < 4; ++r)
          H[(rb * 16 + q * 4 + r) * 264 + c] = f2bf(fmaxf(acc[rb][i][r] + bb, 0.f));
    }
    __syncthreads();
    f32x4 acc2[2][4] = {};
    mfma_gemm<8, 2>(H, 264, W2s, wave, lane, acc2);
    #pragma unroll
    for (int i = 0; i < 4; ++i) {
      int c = (wave * 4 + i) * 16 + m;
      float bb = b2[c];
      #pragma unroll
      for (int rb = 0; rb < 2; ++rb)
        #pragma unroll
        for (int r = 0; r < 4; ++r) {
          int row = rl[rb * 16 + q * 4 + r];
          if (row >= 0) out[(size_t)row * DD + c] = (acc2[rb][i][r] + bb) * scale;
        }
    }
  }
}

// ============================================================
// Expert 3: wsum
// ============================================================
__global__ __launch_bounds__(256) void k_wsum(
    const float* __restrict__ zg, const float* __restrict__ zn,
    const u16* __restrict__ Was, const float* __restrict__ ba,
    const u16* __restrict__ Wos, const float* __restrict__ bo,
    const int* __restrict__ listpos, const int* __restrict__ lists,
    const float* __restrict__ avgp, float* __restrict__ out) {
  __shared__ u16 X[32 * 520];
  __shared__ u16 H[32 * 264];
  __shared__ int rl[32];
  int n = listpos[3];
  const int* lst = lists + 3 * (size_t)BN;
  float scale = avgp[3];
  int tid = threadIdx.x, lane = tid & 63, wave = tid >> 6;
  int q = lane >> 4, m = lane & 15;

  for (int tile = blockIdx.x; tile * 32 < n; tile += gridDim.x) {
    int base = tile * 32;
    __syncthreads();
    if (tid < 32) rl[tid] = (base + tid < n) ? lst[base + tid] : -1;
    __syncthreads();
    #pragma unroll
    for (int j = 0; j < 16; ++j) {
      int t = tid + j * 256;
      int row = t >> 7, off = t & 127;
      int r = rl[row];
      float4 v = make_float4(0.f, 0.f, 0.f, 0.f);
      if (r >= 0)
        v = (off < 64) ? *(const float4*)(zg + (size_t)r * DD + off * 4)
                       : *(const float4*)(zn + (size_t)r * DD + (off - 64) * 4);
      ushort4 pk; pk.x = f2bf(v.x); pk.y = f2bf(v.y); pk.z = f2bf(v.z); pk.w = f2bf(v.w);
      *(ushort4*)(X + row * 520 + off * 4) = pk;
    }
    __syncthreads();
    f32x4 acc[2][4] = {};
    mfma_gemm<16, 2>(X, 520, Was, wave, lane, acc);
    #pragma unroll
    for (int i = 0; i < 4; ++i) {
      int c = (wave * 4 + i) * 16 + m;
      float bb = ba[c];
      #pragma unroll
      for (int rb = 0; rb < 2; ++rb)
        #pragma unroll
        for (int r = 0; r < 4; ++r) {
          int vr = rb * 16 + q * 4 + r;
          float al = 1.f / (1.f + __expf(-(acc[rb][i][r] + bb)));
          float xg = bf2f(X[vr * 520 + c]);
          float xn = bf2f(X[vr * 520 + 256 + c]);
          H[vr * 264 + c] = f2bf(al * xg + (1.f - al) * xn);
        }
    }
    __syncthreads();
    f32x4 acc2[2][4] = {};
    mfma_gemm<8, 2>(H, 264, Wos, wave, lane, acc2);
    #pragma unroll
    for (int i = 0; i < 4; ++i) {
      int c = (wave * 4 + i) * 16 + m;
      float bb = bo[c];
      #pragma unroll
      for (int rb = 0; rb < 2; ++rb)
        #pragma unroll
        for (int r = 0; r < 4; ++r) {
          int row = rl[rb * 16 + q * 4 + r];
          if (row >= 0) out[(size_t)row * DD + c] = (acc2[rb][i][r] + bb) * scale;
        }
    }
  }
}

// ============================================================
// Expert 2: attention. Hybrid of r0 execution style + Wcomb fusion.
//   - Q/K/V: 3 back-to-back GEMM passes into separate buffers, NO
//     barriers between (independent given X) -> compiler can overlap
//     weight loads across passes; no launch_bounds VGPR squeeze.
//   - Then: scores -> coeffs -> combine (M = c0*v0+c1*v1) -> M @ Wcomb.
// LDS 77.6 KB -> 2 blocks/CU.
// ============================================================
__global__ __launch_bounds__(256) void k_attn(
    const float* __restrict__ zg, const float* __restrict__ zn,
    const u16* __restrict__ Wqs, const float* __restrict__ bq,
    const u16* __restrict__ Wks, const float* __restrict__ bk,
    const u16* __restrict__ Wvs, const float* __restrict__ bv,
    const u16* __restrict__ Wcs, const float* __restrict__ bc,
    const int* __restrict__ listpos, const int* __restrict__ lists,
    const float* __restrict__ avgp, float* __restrict__ out) {
  __shared__ u16 X[32 * 264];
  __shared__ u16 Qb[32 * 264];
  __shared__ u16 Kb[32 * 264];
  __shared__ u16 Vb[32 * 264];
  __shared__ u16 Mb[16 * 264];
  __shared__ float SC[256];
  __shared__ float CF[128];      // coeffs: [(r*4+h)*2 + kp]
  __shared__ int rl[16];
  int n = listpos[2];
  const int* lst = lists + 2 * (size_t)BN;
  float scale = avgp[2];
  int tid = threadIdx.x, lane = tid & 63, wave = tid >> 6;
  int q = lane >> 4, m = lane & 15;

  for (int tile = blockIdx.x; tile * 16 < n; tile += gridDim.x) {
    int base = tile * 16;
    __syncthreads();
    if (tid < 16) rl[tid] = (base + tid < n) ? lst[base + tid] : -1;
    __syncthreads();
    // stage X: vrow v = 2r+pos; pos0 = zg, pos1 = zn
    #pragma unroll
    for (int j = 0; j < 8; ++j) {
      int t = tid + j * 256;
      int v = t >> 6, off = t & 63;
      int r = rl[v >> 1];
      float4 val = make_float4(0.f, 0.f, 0.f, 0.f);
      if (r >= 0)
        val = (v & 1) ? *(const float4*)(zn + (size_t)r * DD + off * 4)
                      : *(const float4*)(zg + (size_t)r * DD + off * 4);
      ushort4 pk; pk.x = f2bf(val.x); pk.y = f2bf(val.y); pk.z = f2bf(val.z); pk.w = f2bf(val.w);
      *(ushort4*)(X + v * 264 + off * 4) = pk;
    }
    __syncthreads();
    // ---- Q, K, V passes: independent, no barriers between ----
    {
      f32x4 a1[2][4] = {};
      mfma_gemm<8, 2>(X, 264, Wqs, wave, lane, a1);
      #pragma unroll
      for (int i = 0; i < 4; ++i) {
        int c = (wave * 4 + i) * 16 + m;
        float bb = bq[c];
        #pragma unroll
        for (int rb = 0; rb < 2; ++rb)
          #pragma unroll
          for (int r = 0; r < 4; ++r)
            Qb[(rb * 16 + q * 4 + r) * 264 + c] = f2bf(a1[rb][i][r] + bb);
      }
    }
    {
      f32x4 a1[2][4] = {};
      mfma_gemm<8, 2>(X, 264, Wks, wave, lane, a1);
      #pragma unroll
      for (int i = 0; i < 4; ++i) {
        int c = (wave * 4 + i) * 16 + m;
        float bb = bk[c];
        #pragma unroll
        for (int rb = 0; rb < 2; ++rb)
          #pragma unroll
          for (int r = 0; r < 4; ++r)
            Kb[(rb * 16 + q * 4 + r) * 264 + c] = f2bf(a1[rb][i][r] + bb);
      }
    }
    {
      f32x4 a1[2][4] = {};
      mfma_gemm<8, 2>(X, 264, Wvs, wave, lane, a1);
      #pragma unroll
      for (int i = 0; i < 4; ++i) {
        int c = (wave * 4 + i) * 16 + m;
        float bb = bv[c];
        #pragma unroll
        for (int rb = 0; rb < 2; ++rb)
          #pragma unroll
          for (int r = 0; r < 4; ++r)
            Vb[(rb * 16 + q * 4 + r) * 264 + c] = f2bf(a1[rb][i][r] + bb);
      }
    }
    __syncthreads();
    // scores: t = r*16 + h*4 + qp*2 + kp
    {
      int kp = tid & 1, qp = (tid >> 1) & 1, h = (tid >> 2) & 3, r = tid >> 4;
      const unsigned int* Qu = (const unsigned int*)Qb;
      const unsigned int* Ku = (const unsigned int*)Kb;
      int qrow = (2 * r + qp) * 132 + h * 32;
      int krow = (2 * r + kp) * 132 + h * 32;
      float s = 0.f;
      #pragma unroll 8
      for (int d = 0; d < 32; ++d) {
        unsigned int qu = Qu[qrow + d], ku = Ku[krow + d];
        s += bf2f((u16)(qu & 0xffff)) * bf2f((u16)(ku & 0xffff))
           + bf2f((u16)(qu >> 16)) * bf2f((u16)(ku >> 16));
      }
      SC[tid] = s * 0.125f;
    }
    __syncthreads();
    // coeffs: c_kp = 0.5*(a(qp=0,kp) + a(qp=1,kp)) per (row, head)
    if (tid < 128) {
      int kp = tid & 1, h = (tid >> 1) & 3, r = tid >> 3;
      int b4 = r * 16 + h * 4;
      float s0k = SC[b4 + kp],     s0o = SC[b4 + (kp ^ 1)];
      float s1k = SC[b4 + 2 + kp], s1o = SC[b4 + 2 + (kp ^ 1)];
      float a0 = 1.f / (1.f + __expf(s0o - s0k));
      float a1 = 1.f / (1.f + __expf(s1o - s1k));
      CF[(r * 4 + h) * 2 + kp] = 0.5f * (a0 + a1);
    }
    __syncthreads();
    // combine: M[r] = c0*v[2r] + c1*v[2r+1]  -> Mb
    {
      const unsigned int* Vu = (const unsigned int*)Vb;
      unsigned int* Mu = (unsigned int*)Mb;
      #pragma unroll
      for (int j = 0; j < 8; ++j) {
        int idx = tid + j * 256;      // 16 rows x 128 u32-cols
        int r = idx >> 7, cu = idx & 127;
        int h = cu >> 5;
        float c0 = CF[(r * 4 + h) * 2], c1 = CF[(r * 4 + h) * 2 + 1];
        unsigned int v0 = Vu[(2 * r) * 132 + cu], v1 = Vu[(2 * r + 1) * 132 + cu];
        float lo = c0 * bf2f((u16)(v0 & 0xffff)) + c1 * bf2f((u16)(v1 & 0xffff));
        float hi = c0 * bf2f((u16)(v0 >> 16)) + c1 * bf2f((u16)(v1 >> 16));
        Mu[r * 132 + cu] = (unsigned int)f2bf(lo) | ((unsigned int)f2bf(hi) << 16);
      }
    }
    __syncthreads();
    // out = M @ Wcomb + bcomb
    {
      f32x4 acc3[1][4] = {};
      mfma_gemm<8, 1>(Mb, 264, Wcs, wave, lane, acc3);
      #pragma unroll
      for (int i = 0; i < 4; ++i) {
        int c = (wave * 4 + i) * 16 + m;
        float bb = bc[c];
        #pragma unroll
        for (int r = 0; r < 4; ++r) {
          int row = rl[q * 4 + r];
          if (row >= 0) out[(size_t)row * DD + c] = (acc3[0][i][r] + bb) * scale;
        }
      }
    }
  }
}

// ============================================================
// launch
// ============================================================
extern "C" void kernel_launch(void* const* d_in, const int* in_sizes, int n_in,
                              void* d_out, int out_size, void* d_ws, size_t ws_size,
                              hipStream_t stream) {
  const float* zg   = (const float*)d_in[0];
  const float* zn   = (const float*)d_in[1];
  const float* gW   = (const float*)d_in[2];
  const float* gb   = (const float*)d_in[3];
  const float* cW1  = (const float*)d_in[4];
  const float* cb1  = (const float*)d_in[5];
  const float* cW2  = (const float*)d_in[6];
  const float* cb2  = (const float*)d_in[7];
  const float* mW1  = (const float*)d_in[8];
  const float* mb1  = (const float*)d_in[9];
  const float* mW2  = (const float*)d_in[10];
  const float* mb2  = (const float*)d_in[11];
  const float* aWq  = (const float*)d_in[12];
  const float* abq  = (const float*)d_in[13];
  const float* aWk  = (const float*)d_in[14];
  const float* abk  = (const float*)d_in[15];
  const float* aWv  = (const float*)d_in[16];
  const float* abv  = (const float*)d_in[17];
  const float* aWo  = (const float*)d_in[18];
  const float* abo  = (const float*)d_in[19];
  const float* aWfc = (const float*)d_in[20];
  const float* abfc = (const float*)d_in[21];
  const float* wWa  = (const float*)d_in[22];
  const float* wba  = (const float*)d_in[23];
  const float* wWo  = (const float*)d_in[24];
  const float* wbo  = (const float*)d_in[25];
  float* out = (float*)d_out;

  char* ws = (char*)d_ws;
  double* psum  = (double*)ws;
  int* listpos  = (int*)(ws + 32);
  float* avg    = (float*)(ws + 48);
  int* lists    = (int*)(ws + 64);
  u16* wsw      = (u16*)(ws + WS_SWZ_OFF);
  float* wcf32  = (float*)(ws + 64);          // transient: overlaps lists[0]
  float* bcomb  = (float*)(ws + BCOMB_OFF);   // persistent

  SwzArgs sa;
  const float* srcs[10] = {cW1, cW2, mW1, mW2, aWq, aWk, aWv, wcf32, wWa, wWo};
  const int   kss[10]  = {16, 8, 8, 8, 8, 8, 8, 8, 16, 8};
  const int   offs[10] = {OFF_CW1, OFF_CW2, OFF_MW1, OFF_MW2, OFF_AWQ, OFF_AWK,
                          OFF_AWV, OFF_WCB, OFF_WWA, OFF_WWO};
  int gb_acc = 0;
  for (int i = 0; i < 10; ++i) {
    sa.src[i] = srcs[i];
    sa.KS[i] = kss[i];
    sa.lks[i] = (kss[i] == 16) ? 4 : 3;
    sa.dstoff[i] = offs[i];
    sa.gbase[i] = gb_acc;
    gb_acc += kss[i] * 1024;
  }

  hipLaunchKernelGGL(k_init, dim3(1), dim3(64), 0, stream, listpos, psum);
  hipLaunchKernelGGL(k_wcomb, dim3(257), dim3(256), 0, stream,
                     aWo, abo, aWfc, abfc, wcf32, bcomb);
  hipLaunchKernelGGL(k_swz, dim3(SWZ_TOTAL_GROUPS / 256), dim3(256), 0, stream, sa, wsw);
  hipLaunchKernelGGL(k_gate, dim3(BN / 256), dim3(256), 0, stream,
                     zg, zn, gW, gb, listpos, psum, lists);
  hipLaunchKernelGGL(k_finalize, dim3(1), dim3(64), 0, stream,
                     listpos, psum, avg, out + (size_t)BN * DD);
  hipLaunchKernelGGL(k_concat, dim3(1024), dim3(256), 0, stream,
                     zg, zn, wsw + OFF_CW1, cb1, wsw + OFF_CW2, cb2, listpos, lists, avg, out);
  hipLaunchKernelGGL(k_mul, dim3(1024), dim3(256), 0, stream,
                     zg, zn, wsw + OFF_MW1, mb1, wsw + OFF_MW2, mb2, listpos, lists, avg, out);
  hipLaunchKernelGGL(k_attn, dim3(2048), dim3(256), 0, stream,
                     zg, zn, wsw + OFF_AWQ, abq, wsw + OFF_AWK, abk, wsw + OFF_AWV, abv,
                     wsw + OFF_WCB, bcomb, listpos, lists, avg, out);
  hipLaunchKernelGGL(k_wsum, dim3(1024), dim3(256), 0, stream,
                     zg, zn, wsw + OFF_WWA, wba, wsw + OFF_WWO, wbo, listpos, lists, avg, out);
}

// Round 3
// 1032.529 us; speedup vs baseline: 1.4288x; 1.0937x over previous
//
#include <hip/hip_runtime.h>
#include <math.h>

#define BN 131072
#define DD 256
#define NE 4

typedef unsigned short u16;
typedef __bf16 bf16x8 __attribute__((ext_vector_type(8)));
typedef float f32x4 __attribute__((ext_vector_type(4)));

__device__ __forceinline__ u16 f2bf(float f) {
  union { float f; unsigned int u; } v; v.f = f;
  unsigned int u = v.u;
  unsigned int r = (u + 0x7FFFu + ((u >> 16) & 1u)) >> 16;
  return (u16)r;
}
__device__ __forceinline__ float bf2f(u16 x) {
  union { unsigned int u; float f; } v; v.u = ((unsigned int)x) << 16; return v.f;
}

// ---------------- workspace layout (d_ws) ----------------
// [0,32)    double psum[4]
// [32,48)   int    listpos[4]
// [48,64)   float  avg[4]
// [64, 64+4*BN*4)  int lists[4][BN]
//   NOTE: first 256KB of lists[0] is transiently reused as fp32 Wcomb
//   (k_wcomb writes it, k_swz reads it, both BEFORE k_gate writes lists).
// [2097216, +1572864) u16 swizzled bf16 weights (10 matrices)
// [3670080, +1024)    float bcomb[256]  (persists through expert kernels)
#define WS_SWZ_OFF 2097216
#define BCOMB_OFF  3670080

#define OFF_CW1  0
#define OFF_CW2  131072
#define OFF_MW1  196608
#define OFF_MW2  262144
#define OFF_AWQ  327680
#define OFF_AWK  393216
#define OFF_AWV  458752
#define OFF_WCB  524288
#define OFF_WWA  589824
#define OFF_WWO  720896
#define SWZ_TOTAL_GROUPS 98304   // 786432/8

// ============================================================
// init
// ============================================================
__global__ void k_init(int* __restrict__ listpos, double* __restrict__ psum) {
  int t = threadIdx.x;
  if (t < NE) { listpos[t] = 0; psum[t] = 0.0; }
}

// ============================================================
// Wcomb = Wo @ Wfc (fp32), bcomb = bo @ Wfc + bfc
// ============================================================
__global__ __launch_bounds__(256) void k_wcomb(
    const float* __restrict__ Wo, const float* __restrict__ bo,
    const float* __restrict__ Wfc, const float* __restrict__ bfc,
    float* __restrict__ Wc, float* __restrict__ bc) {
  int n = threadIdx.x;
  int k = blockIdx.x;
  if (k < 256) {
    float acc = 0.f;
    #pragma unroll 8
    for (int j = 0; j < 256; ++j) acc += Wo[k * 256 + j] * Wfc[j * 256 + n];
    Wc[k * 256 + n] = acc;
  } else {
    float acc = bfc[n];
    #pragma unroll 8
    for (int j = 0; j < 256; ++j) acc += bo[j] * Wfc[j * 256 + n];
    bc[n] = acc;
  }
}

// ============================================================
// weight swizzle: fp32 W[K x 256] -> bf16 in B-fragment order
// ============================================================
struct SwzArgs {
  const float* src[10];
  int KS[10];
  int lks[10];
  int dstoff[10];
  int gbase[10];
};

__global__ __launch_bounds__(256) void k_swz(SwzArgs a, u16* __restrict__ dst) {
  int g = blockIdx.x * 256 + threadIdx.x;
  if (g >= SWZ_TOTAL_GROUPS) return;
  int i = 0;
  #pragma unroll
  for (int t = 1; t < 10; ++t) if (g >= a.gbase[t]) i = t;
  int gl = g - a.gbase[i];
  int KS = a.KS[i], lks = a.lks[i];
  int l = gl & 63, t2 = gl >> 6;
  int ks = t2 & (KS - 1), ct = t2 >> lks;
  const float* src = a.src[i] + (size_t)(ks * 32 + ((l >> 4) << 3)) * 256 + ct * 16 + (l & 15);
  u16 tmp[8];
  #pragma unroll
  for (int j = 0; j < 8; ++j) tmp[j] = f2bf(src[(size_t)j * 256]);
  uint4 pk;
  pk.x = (unsigned)tmp[0] | ((unsigned)tmp[1] << 16);
  pk.y = (unsigned)tmp[2] | ((unsigned)tmp[3] << 16);
  pk.z = (unsigned)tmp[4] | ((unsigned)tmp[5] << 16);
  pk.w = (unsigned)tmp[6] | ((unsigned)tmp[7] << 16);
  *(uint4*)(dst + a.dstoff[i] + (size_t)gl * 8) = pk;
}

// ============================================================
// gating: fp64 accumulation, LDS-staged coalesced reads.
// ============================================================
__global__ __launch_bounds__(256) void k_gate(
    const float* __restrict__ zg, const float* __restrict__ zn,
    const float* __restrict__ gW, const float* __restrict__ gb,
    int* __restrict__ listpos, double* __restrict__ psum,
    int* __restrict__ lists) {
  __shared__ float xs[32 * 257];
  __shared__ double gwd[512 * 4];
  int tid = threadIdx.x, lane = tid & 63;
  int rowbase = blockIdx.x * 256;
  for (int i = tid; i < 2048; i += 256) gwd[i] = (double)gW[i];
  double l0 = (double)gb[0], l1 = (double)gb[1], l2 = (double)gb[2], l3 = (double)gb[3];

  for (int c = 0; c < 16; ++c) {
    const float* src = (c < 8) ? zg : zn;
    int ko = (c & 7) * 32;
    __syncthreads();
    #pragma unroll
    for (int j = 0; j < 8; ++j) {
      int idx = tid + j * 256;
      int row = idx >> 3, off = idx & 7;
      float4 v = *(const float4*)(src + (size_t)(rowbase + row) * DD + ko + off * 4);
      xs[(off * 4 + 0) * 257 + row] = v.x;
      xs[(off * 4 + 1) * 257 + row] = v.y;
      xs[(off * 4 + 2) * 257 + row] = v.z;
      xs[(off * 4 + 3) * 257 + row] = v.w;
    }
    __syncthreads();
    const double* gp = gwd + (size_t)(c * 32) * 4;
    #pragma unroll
    for (int i = 0; i < 32; ++i) {
      double x = (double)xs[i * 257 + tid];
      l0 = fma(x, gp[i * 4 + 0], l0);
      l1 = fma(x, gp[i * 4 + 1], l1);
      l2 = fma(x, gp[i * 4 + 2], l2);
      l3 = fma(x, gp[i * 4 + 3], l3);
    }
  }

  int row = rowbase + tid;
  int e = 0; double lm = l0;
  if (l1 > lm) { lm = l1; e = 1; }
  if (l2 > lm) { lm = l2; e = 2; }
  if (l3 > lm) { lm = l3; e = 3; }
  double s = exp(l0 - lm) + exp(l1 - lm) + exp(l2 - lm) + exp(l3 - lm);
  double p = 1.0 / s;

  #pragma unroll
  for (int ee = 0; ee < NE; ++ee) {
    bool mine = (e == ee);
    unsigned long long mask = __ballot(mine);
    int cnt = __popcll(mask);
    double pv = mine ? p : 0.0;
    #pragma unroll
    for (int off = 32; off; off >>= 1) pv += __shfl_down(pv, off);
    if (cnt) {
      int leader = __ffsll((unsigned long long)mask) - 1;
      int basev = 0;
      if (lane == leader) basev = atomicAdd(&listpos[ee], cnt);
      basev = __shfl(basev, leader);
      if (mine) {
        int rank = __popcll(mask & ((1ull << lane) - 1ull));
        lists[(size_t)ee * BN + basev + rank] = row;
      }
      if (lane == 0) atomicAdd(&psum[ee], pv);
    }
  }
}

__global__ void k_finalize(const int* __restrict__ listpos,
                           const double* __restrict__ psum,
                           float* __restrict__ avg, float* __restrict__ aux_out) {
  if (threadIdx.x == 0) {
    double aux = 0.0;
    for (int ee = 0; ee < NE; ++ee) {
      int c = listpos[ee];
      avg[ee] = (c > 0) ? (float)(psum[ee] / (double)c) : 0.0f;
      double u = (double)c / (double)BN;
      aux += u * u;
    }
    *aux_out = (float)(aux * (double)NE);
  }
}

// ============================================================
// MFMA tile core
// ============================================================
template <int KS, int RB>
__device__ __forceinline__ void mfma_gemm(const u16* __restrict__ A, int strideA,
                                          const u16* __restrict__ W,
                                          int wave, int lane, f32x4 acc[RB][4]) {
  int q = lane >> 4, m = lane & 15;
  #pragma unroll
  for (int ks = 0; ks < KS; ++ks) {
    bf16x8 a[RB];
    #pragma unroll
    for (int rb = 0; rb < RB; ++rb)
      a[rb] = *(const bf16x8*)(A + (rb * 16 + m) * strideA + ks * 32 + (q << 3));
    #pragma unroll
    for (int i = 0; i < 4; ++i) {
      int ct = wave * 4 + i;
      bf16x8 b = *(const bf16x8*)(W + (((ct * KS + ks) * 64 + lane) << 3));
      #pragma unroll
      for (int rb = 0; rb < RB; ++rb)
        acc[rb][i] = __builtin_amdgcn_mfma_f32_16x16x32_bf16(a[rb], b, acc[rb][i], 0, 0, 0);
    }
  }
}

// ============================================================
// Expert 0: concat
// ============================================================
__global__ __launch_bounds__(256) void k_concat(
    const float* __restrict__ zg, const float* __restrict__ zn,
    const u16* __restrict__ W1s, const float* __restrict__ b1,
    const u16* __restrict__ W2s, const float* __restrict__ b2,
    const int* __restrict__ listpos, const int* __restrict__ lists,
    const float* __restrict__ avgp, float* __restrict__ out) {
  __shared__ u16 X[32 * 520];
  __shared__ u16 H[32 * 264];
  __shared__ int rl[32];
  int n = listpos[0];
  const int* lst = lists + 0 * (size_t)BN;
  float scale = avgp[0];
  int tid = threadIdx.x, lane = tid & 63, wave = tid >> 6;
  int q = lane >> 4, m = lane & 15;

  for (int tile = blockIdx.x; tile * 32 < n; tile += gridDim.x) {
    int base = tile * 32;
    __syncthreads();
    if (tid < 32) rl[tid] = (base + tid < n) ? lst[base + tid] : -1;
    __syncthreads();
    #pragma unroll
    for (int j = 0; j < 16; ++j) {
      int t = tid + j * 256;
      int row = t >> 7, off = t & 127;
      int r = rl[row];
      float4 v = make_float4(0.f, 0.f, 0.f, 0.f);
      if (r >= 0)
        v = (off < 64) ? *(const float4*)(zg + (size_t)r * DD + off * 4)
                       : *(const float4*)(zn + (size_t)r * DD + (off - 64) * 4);
      ushort4 pk; pk.x = f2bf(v.x); pk.y = f2bf(v.y); pk.z = f2bf(v.z); pk.w = f2bf(v.w);
      *(ushort4*)(X + row * 520 + off * 4) = pk;
    }
    __syncthreads();
    f32x4 acc[2][4] = {};
    mfma_gemm<16, 2>(X, 520, W1s, wave, lane, acc);
    #pragma unroll
    for (int i = 0; i < 4; ++i) {
      int c = (wave * 4 + i) * 16 + m;
      float bb = b1[c];
      #pragma unroll
      for (int rb = 0; rb < 2; ++rb)
        #pragma unroll
        for (int r = 0; r < 4; ++r)
          H[(rb * 16 + q * 4 + r) * 264 + c] = f2bf(fmaxf(acc[rb][i][r] + bb, 0.f));
    }
    __syncthreads();
    f32x4 acc2[2][4] = {};
    mfma_gemm<8, 2>(H, 264, W2s, wave, lane, acc2);
    #pragma unroll
    for (int i = 0; i < 4; ++i) {
      int c = (wave * 4 + i) * 16 + m;
      float bb = b2[c];
      #pragma unroll
      for (int rb = 0; rb < 2; ++rb)
        #pragma unroll
        for (int r = 0; r < 4; ++r) {
          int row = rl[rb * 16 + q * 4 + r];
          if (row >= 0) out[(size_t)row * DD + c] = (acc2[rb][i][r] + bb) * scale;
        }
    }
  }
}

// ============================================================
// Expert 1: mul — 64-row tiles (RB=4) to halve weight streams/row.
// LDS: X 33.8K + H 33.8K = 67.6K -> 2 blocks/CU.
// ============================================================
__global__ __launch_bounds__(256) void k_mul(
    const float* __restrict__ zg, const float* __restrict__ zn,
    const u16* __restrict__ W1s, const float* __restrict__ b1,
    const u16* __restrict__ W2s, const float* __restrict__ b2,
    const int* __restrict__ listpos, const int* __restrict__ lists,
    const float* __restrict__ avgp, float* __restrict__ out) {
  __shared__ u16 X[64 * 264];
  __shared__ u16 H[64 * 264];
  __shared__ int rl[64];
  int n = listpos[1];
  const int* lst = lists + 1 * (size_t)BN;
  float scale = avgp[1];
  int tid = threadIdx.x, lane = tid & 63, wave = tid >> 6;
  int q = lane >> 4, m = lane & 15;

  for (int tile = blockIdx.x; tile * 64 < n; tile += gridDim.x) {
    int base = tile * 64;
    __syncthreads();
    if (tid < 64) rl[tid] = (base + tid < n) ? lst[base + tid] : -1;
    __syncthreads();
    #pragma unroll
    for (int j = 0; j < 16; ++j) {
      int t = tid + j * 256;
      int row = t >> 6, off = t & 63;
      int r = rl[row];
      float4 v = make_float4(0.f, 0.f, 0.f, 0.f);
      if (r >= 0) {
        float4 g = *(const float4*)(zg + (size_t)r * DD + off * 4);
        float4 h = *(const float4*)(zn + (size_t)r * DD + off * 4);
        v = make_float4(g.x * h.x, g.y * h.y, g.z * h.z, g.w * h.w);
      }
      ushort4 pk; pk.x = f2bf(v.x); pk.y = f2bf(v.y); pk.z = f2bf(v.z); pk.w = f2bf(v.w);
      *(ushort4*)(X + row * 264 + off * 4) = pk;
    }
    __syncthreads();
    f32x4 acc[4][4] = {};
    mfma_gemm<8, 4>(X, 264, W1s, wave, lane, acc);
    #pragma unroll
    for (int i = 0; i < 4; ++i) {
      int c = (wave * 4 + i) * 16 + m;
      float bb = b1[c];
      #pragma unroll
      for (int rb = 0; rb < 4; ++rb)
        #pragma unroll
        for (int r = 0; r < 4; ++r)
          H[(rb * 16 + q * 4 + r) * 264 + c] = f2bf(fmaxf(acc[rb][i][r] + bb, 0.f));
    }
    __syncthreads();
    f32x4 acc2[4][4] = {};
    mfma_gemm<8, 4>(H, 264, W2s, wave, lane, acc2);
    #pragma unroll
    for (int i = 0; i < 4; ++i) {
      int c = (wave * 4 + i) * 16 + m;
      float bb = b2[c];
      #pragma unroll
      for (int rb = 0; rb < 4; ++rb)
        #pragma unroll
        for (int r = 0; r < 4; ++r) {
          int row = rl[rb * 16 + q * 4 + r];
          if (row >= 0) out[(size_t)row * DD + c] = (acc2[rb][i][r] + bb) * scale;
        }
    }
  }
}

// ============================================================
// Expert 3: wsum
// ============================================================
__global__ __launch_bounds__(256) void k_wsum(
    const float* __restrict__ zg, const float* __restrict__ zn,
    const u16* __restrict__ Was, const float* __restrict__ ba,
    const u16* __restrict__ Wos, const float* __restrict__ bo,
    const int* __restrict__ listpos, const int* __restrict__ lists,
    const float* __restrict__ avgp, float* __restrict__ out) {
  __shared__ u16 X[32 * 520];
  __shared__ u16 H[32 * 264];
  __shared__ int rl[32];
  int n = listpos[3];
  const int* lst = lists + 3 * (size_t)BN;
  float scale = avgp[3];
  int tid = threadIdx.x, lane = tid & 63, wave = tid >> 6;
  int q = lane >> 4, m = lane & 15;

  for (int tile = blockIdx.x; tile * 32 < n; tile += gridDim.x) {
    int base = tile * 32;
    __syncthreads();
    if (tid < 32) rl[tid] = (base + tid < n) ? lst[base + tid] : -1;
    __syncthreads();
    #pragma unroll
    for (int j = 0; j < 16; ++j) {
      int t = tid + j * 256;
      int row = t >> 7, off = t & 127;
      int r = rl[row];
      float4 v = make_float4(0.f, 0.f, 0.f, 0.f);
      if (r >= 0)
        v = (off < 64) ? *(const float4*)(zg + (size_t)r * DD + off * 4)
                       : *(const float4*)(zn + (size_t)r * DD + (off - 64) * 4);
      ushort4 pk; pk.x = f2bf(v.x); pk.y = f2bf(v.y); pk.z = f2bf(v.z); pk.w = f2bf(v.w);
      *(ushort4*)(X + row * 520 + off * 4) = pk;
    }
    __syncthreads();
    f32x4 acc[2][4] = {};
    mfma_gemm<16, 2>(X, 520, Was, wave, lane, acc);
    #pragma unroll
    for (int i = 0; i < 4; ++i) {
      int c = (wave * 4 + i) * 16 + m;
      float bb = ba[c];
      #pragma unroll
      for (int rb = 0; rb < 2; ++rb)
        #pragma unroll
        for (int r = 0; r < 4; ++r) {
          int vr = rb * 16 + q * 4 + r;
          float al = 1.f / (1.f + __expf(-(acc[rb][i][r] + bb)));
          float xg = bf2f(X[vr * 520 + c]);
          float xn = bf2f(X[vr * 520 + 256 + c]);
          H[vr * 264 + c] = f2bf(al * xg + (1.f - al) * xn);
        }
    }
    __syncthreads();
    f32x4 acc2[2][4] = {};
    mfma_gemm<8, 2>(H, 264, Wos, wave, lane, acc2);
    #pragma unroll
    for (int i = 0; i < 4; ++i) {
      int c = (wave * 4 + i) * 16 + m;
      float bb = bo[c];
      #pragma unroll
      for (int rb = 0; rb < 2; ++rb)
        #pragma unroll
        for (int r = 0; r < 4; ++r) {
          int row = rl[rb * 16 + q * 4 + r];
          if (row >= 0) out[(size_t)row * DD + c] = (acc2[rb][i][r] + bb) * scale;
        }
    }
  }
}

// ============================================================
// Expert 2, stage A: 32-row tiles (64 vrows), RB=4.
// Wave w's accumulator cols == head w (64 dims), so:
//  - K stays in registers; scores = K_regs x Qb(own-wave LDS writes),
//    reduced over m-lanes with shfl_xor butterfly (no barrier).
//  - V stays in registers; M = c0*v_even + c1*v_odd per-lane
//    (row pairs 2r,2r+1 are in-lane), stored f32 directly to out
//    (out rows of expert 2 serve as M workspace; k_attn_fc rewrites).
// LDS: X 33.8K + Qb 33.8K -> 2 blocks/CU. 2 barriers/tile.
// Weight traffic: 3 x 128KB per 32 rows (was 4 x 128KB per 16 rows).
// ============================================================
__global__ __launch_bounds__(256) void k_attn(
    const float* __restrict__ zg, const float* __restrict__ zn,
    const u16* __restrict__ Wqs, const float* __restrict__ bq,
    const u16* __restrict__ Wks, const float* __restrict__ bk,
    const u16* __restrict__ Wvs, const float* __restrict__ bv,
    const int* __restrict__ listpos, const int* __restrict__ lists,
    float* __restrict__ out) {
  __shared__ u16 X[64 * 264];
  __shared__ u16 Qb[64 * 264];
  __shared__ int rl[32];
  int n = listpos[2];
  const int* lst = lists + 2 * (size_t)BN;
  int tid = threadIdx.x, lane = tid & 63, wave = tid >> 6;
  int q = lane >> 4, m = lane & 15;

  // per-lane bias values for this wave's head (cols wave*64 + i*16 + m)
  float bqv[4], bkv[4], bvv[4];
  #pragma unroll
  for (int i = 0; i < 4; ++i) {
    int c = wave * 64 + i * 16 + m;
    bqv[i] = bq[c]; bkv[i] = bk[c]; bvv[i] = bv[c];
  }

  for (int tile = blockIdx.x; tile * 32 < n; tile += gridDim.x) {
    int base = tile * 32;
    __syncthreads();   // protect X/rl from previous iteration's readers
    if (tid < 32) rl[tid] = (base + tid < n) ? lst[base + tid] : -1;
    __syncthreads();
    // stage X: vrow v = 2r+pos; pos0 = zg, pos1 = zn
    #pragma unroll
    for (int j = 0; j < 16; ++j) {
      int t = tid + j * 256;
      int v = t >> 6, off = t & 63;
      int r = rl[v >> 1];
      float4 val = make_float4(0.f, 0.f, 0.f, 0.f);
      if (r >= 0)
        val = (v & 1) ? *(const float4*)(zn + (size_t)r * DD + off * 4)
                      : *(const float4*)(zg + (size_t)r * DD + off * 4);
      ushort4 pk; pk.x = f2bf(val.x); pk.y = f2bf(val.y); pk.z = f2bf(val.z); pk.w = f2bf(val.w);
      *(ushort4*)(X + v * 264 + off * 4) = pk;
    }
    __syncthreads();
    // ---- Q pass -> Qb (bf16, +bias). Wave writes only head-w cols. ----
    {
      f32x4 a1[4][4] = {};
      mfma_gemm<8, 4>(X, 264, Wqs, wave, lane, a1);
      #pragma unroll
      for (int i = 0; i < 4; ++i) {
        int c = (wave * 4 + i) * 16 + m;
        #pragma unroll
        for (int rb = 0; rb < 4; ++rb)
          #pragma unroll
          for (int r = 0; r < 4; ++r)
            Qb[(rb * 16 + q * 4 + r) * 264 + c] = f2bf(a1[rb][i][r] + bqv[i]);
      }
    }
    // ---- K pass in regs + scores vs own-wave Qb + coeffs (no barrier) ----
    float C0[4][2], C1[4][2];
    {
      f32x4 ka[4][4] = {};
      mfma_gemm<8, 4>(X, 264, Wks, wave, lane, ka);
      #pragma unroll
      for (int rb = 0; rb < 4; ++rb) {
        #pragma unroll
        for (int pr = 0; pr < 2; ++pr) {
          int rloc = rb * 8 + q * 2 + pr;     // tile-local row 0..31
          float p00 = 0.f, p01 = 0.f, p10 = 0.f, p11 = 0.f;  // p[qp][kp]
          #pragma unroll
          for (int i = 0; i < 4; ++i) {
            float ke = ka[rb][i][2 * pr] + bkv[i];
            float ko = ka[rb][i][2 * pr + 1] + bkv[i];
            int cidx = wave * 64 + i * 16 + m;
            float q0 = bf2f(Qb[(2 * rloc) * 264 + cidx]);
            float q1 = bf2f(Qb[(2 * rloc + 1) * 264 + cidx]);
            p00 += q0 * ke; p01 += q0 * ko;
            p10 += q1 * ke; p11 += q1 * ko;
          }
          #pragma unroll
          for (int msk = 1; msk < 16; msk <<= 1) {
            p00 += __shfl_xor(p00, msk);
            p01 += __shfl_xor(p01, msk);
            p10 += __shfl_xor(p10, msk);
            p11 += __shfl_xor(p11, msk);
          }
          // softmax over kp per qp, then mean over qp
          float s00 = 1.f / (1.f + __expf((p01 - p00) * 0.125f));
          float s10 = 1.f / (1.f + __expf((p11 - p10) * 0.125f));
          float c0 = 0.5f * (s00 + s10);
          C0[rb][pr] = c0; C1[rb][pr] = 1.f - c0;
        }
      }
    }
    // ---- V pass in regs; M = c0*v_e + c1*v_o -> out (f32 M workspace) ----
    {
      f32x4 va[4][4] = {};
      mfma_gemm<8, 4>(X, 264, Wvs, wave, lane, va);
      #pragma unroll
      for (int rb = 0; rb < 4; ++rb)
        #pragma unroll
        for (int pr = 0; pr < 2; ++pr) {
          int rloc = rb * 8 + q * 2 + pr;
          int grow = rl[rloc];
          if (grow >= 0) {
            #pragma unroll
            for (int i = 0; i < 4; ++i) {
              float mv = C0[rb][pr] * (va[rb][i][2 * pr] + bvv[i])
                       + C1[rb][pr] * (va[rb][i][2 * pr + 1] + bvv[i]);
              out[(size_t)grow * DD + wave * 64 + i * 16 + m] = mv;
            }
          }
        }
    }
  }
}

// ============================================================
// Expert 2, stage B: out(expert2 rows, holding M) @ Wcomb + bcomb -> out.
// Tile-local read-then-write of the same rows (barrier-separated).
// ============================================================
__global__ __launch_bounds__(256) void k_attn_fc(
    const u16* __restrict__ Wcs, const float* __restrict__ bc,
    const int* __restrict__ listpos, const int* __restrict__ lists,
    const float* __restrict__ avgp, float* __restrict__ out) {
  __shared__ u16 Mb[32 * 264];
  __shared__ int rl[32];
  int n = listpos[2];
  const int* lst = lists + 2 * (size_t)BN;
  float scale = avgp[2];
  int tid = threadIdx.x, lane = tid & 63, wave = tid >> 6;
  int q = lane >> 4, m = lane & 15;

  for (int tile = blockIdx.x; tile * 32 < n; tile += gridDim.x) {
    int base = tile * 32;
    __syncthreads();
    if (tid < 32) rl[tid] = (base + tid < n) ? lst[base + tid] : -1;
    __syncthreads();
    #pragma unroll
    for (int j = 0; j < 8; ++j) {
      int t = tid + j * 256;
      int row = t >> 6, off = t & 63;
      int r = rl[row];
      float4 v = make_float4(0.f, 0.f, 0.f, 0.f);
      if (r >= 0) v = *(const float4*)(out + (size_t)r * DD + off * 4);
      ushort4 pk; pk.x = f2bf(v.x); pk.y = f2bf(v.y); pk.z = f2bf(v.z); pk.w = f2bf(v.w);
      *(ushort4*)(Mb + row * 264 + off * 4) = pk;
    }
    __syncthreads();
    f32x4 acc[2][4] = {};
    mfma_gemm<8, 2>(Mb, 264, Wcs, wave, lane, acc);
    #pragma unroll
    for (int i = 0; i < 4; ++i) {
      int c = (wave * 4 + i) * 16 + m;
      float bb = bc[c];
      #pragma unroll
      for (int rb = 0; rb < 2; ++rb)
        #pragma unroll
        for (int r = 0; r < 4; ++r) {
          int row = rl[rb * 16 + q * 4 + r];
          if (row >= 0) out[(size_t)row * DD + c] = (acc[rb][i][r] + bb) * scale;
        }
    }
  }
}

// ============================================================
// launch
// ============================================================
extern "C" void kernel_launch(void* const* d_in, const int* in_sizes, int n_in,
                              void* d_out, int out_size, void* d_ws, size_t ws_size,
                              hipStream_t stream) {
  const float* zg   = (const float*)d_in[0];
  const float* zn   = (const float*)d_in[1];
  const float* gW   = (const float*)d_in[2];
  const float* gb   = (const float*)d_in[3];
  const float* cW1  = (const float*)d_in[4];
  const float* cb1  = (const float*)d_in[5];
  const float* cW2  = (const float*)d_in[6];
  const float* cb2  = (const float*)d_in[7];
  const float* mW1  = (const float*)d_in[8];
  const float* mb1  = (const float*)d_in[9];
  const float* mW2  = (const float*)d_in[10];
  const float* mb2  = (const float*)d_in[11];
  const float* aWq  = (const float*)d_in[12];
  const float* abq  = (const float*)d_in[13];
  const float* aWk  = (const float*)d_in[14];
  const float* abk  = (const float*)d_in[15];
  const float* aWv  = (const float*)d_in[16];
  const float* abv  = (const float*)d_in[17];
  const float* aWo  = (const float*)d_in[18];
  const float* abo  = (const float*)d_in[19];
  const float* aWfc = (const float*)d_in[20];
  const float* abfc = (const float*)d_in[21];
  const float* wWa  = (const float*)d_in[22];
  const float* wba  = (const float*)d_in[23];
  const float* wWo  = (const float*)d_in[24];
  const float* wbo  = (const float*)d_in[25];
  float* out = (float*)d_out;

  char* ws = (char*)d_ws;
  double* psum  = (double*)ws;
  int* listpos  = (int*)(ws + 32);
  float* avg    = (float*)(ws + 48);
  int* lists    = (int*)(ws + 64);
  u16* wsw      = (u16*)(ws + WS_SWZ_OFF);
  float* wcf32  = (float*)(ws + 64);          // transient: overlaps lists[0]
  float* bcomb  = (float*)(ws + BCOMB_OFF);   // persistent

  SwzArgs sa;
  const float* srcs[10] = {cW1, cW2, mW1, mW2, aWq, aWk, aWv, wcf32, wWa, wWo};
  const int   kss[10]  = {16, 8, 8, 8, 8, 8, 8, 8, 16, 8};
  const int   offs[10] = {OFF_CW1, OFF_CW2, OFF_MW1, OFF_MW2, OFF_AWQ, OFF_AWK,
                          OFF_AWV, OFF_WCB, OFF_WWA, OFF_WWO};
  int gb_acc = 0;
  for (int i = 0; i < 10; ++i) {
    sa.src[i] = srcs[i];
    sa.KS[i] = kss[i];
    sa.lks[i] = (kss[i] == 16) ? 4 : 3;
    sa.dstoff[i] = offs[i];
    sa.gbase[i] = gb_acc;
    gb_acc += kss[i] * 1024;
  }

  hipLaunchKernelGGL(k_init, dim3(1), dim3(64), 0, stream, listpos, psum);
  hipLaunchKernelGGL(k_wcomb, dim3(257), dim3(256), 0, stream,
                     aWo, abo, aWfc, abfc, wcf32, bcomb);
  hipLaunchKernelGGL(k_swz, dim3(SWZ_TOTAL_GROUPS / 256), dim3(256), 0, stream, sa, wsw);
  hipLaunchKernelGGL(k_gate, dim3(BN / 256), dim3(256), 0, stream,
                     zg, zn, gW, gb, listpos, psum, lists);
  hipLaunchKernelGGL(k_finalize, dim3(1), dim3(64), 0, stream,
                     listpos, psum, avg, out + (size_t)BN * DD);
  hipLaunchKernelGGL(k_concat, dim3(1024), dim3(256), 0, stream,
                     zg, zn, wsw + OFF_CW1, cb1, wsw + OFF_CW2, cb2, listpos, lists, avg, out);
  hipLaunchKernelGGL(k_mul, dim3(512), dim3(256), 0, stream,
                     zg, zn, wsw + OFF_MW1, mb1, wsw + OFF_MW2, mb2, listpos, lists, avg, out);
  hipLaunchKernelGGL(k_attn, dim3(1024), dim3(256), 0, stream,
                     zg, zn, wsw + OFF_AWQ, abq, wsw + OFF_AWK, abk, wsw + OFF_AWV, abv,
                     listpos, lists, out);
  hipLaunchKernelGGL(k_attn_fc, dim3(1024), dim3(256), 0, stream,
                     wsw + OFF_WCB, bcomb, listpos, lists, avg, out);
  hipLaunchKernelGGL(k_wsum, dim3(1024), dim3(256), 0, stream,
                     zg, zn, wsw + OFF_WWA, wba, wsw + OFF_WWO, wbo, listpos, lists, avg, out);
}

// Round 4
// 858.999 us; speedup vs baseline: 1.7174x; 1.2020x over previous
//
#include <hip/hip_runtime.h>
#include <math.h>

#define BN 131072
#define DD 256
#define NE 4

typedef unsigned short u16;
typedef __bf16 bf16x8 __attribute__((ext_vector_type(8)));
typedef float f32x4 __attribute__((ext_vector_type(4)));

__device__ __forceinline__ u16 f2bf(float f) {
  union { float f; unsigned int u; } v; v.f = f;
  unsigned int u = v.u;
  unsigned int r = (u + 0x7FFFu + ((u >> 16) & 1u)) >> 16;
  return (u16)r;
}
__device__ __forceinline__ float bf2f(u16 x) {
  union { unsigned int u; float f; } v; v.u = ((unsigned int)x) << 16; return v.f;
}

// ---------------- workspace layout (d_ws) ----------------
// [0,32)    double psum[4]
// [32,48)   int    listpos[4]
// [48,64)   float  avg[4]
// [64, 64+4*BN*4)  int lists[4][BN]
//   NOTE: first 256KB of lists[0] is transiently reused as fp32 Wcomb
//   (k_wcomb writes it, k_swz reads it, both BEFORE k_gate writes lists).
// [2097216, +1572864) u16 swizzled bf16 weights (10 matrices)
// [3670080, +1024)    float bcomb[256]  (persists through expert kernels)
#define WS_SWZ_OFF 2097216
#define BCOMB_OFF  3670080

#define OFF_CW1  0
#define OFF_CW2  131072
#define OFF_MW1  196608
#define OFF_MW2  262144
#define OFF_AWQ  327680
#define OFF_AWK  393216
#define OFF_AWV  458752
#define OFF_WCB  524288
#define OFF_WWA  589824
#define OFF_WWO  720896
#define SWZ_TOTAL_GROUPS 98304   // 786432/8

// ============================================================
// init
// ============================================================
__global__ void k_init(int* __restrict__ listpos, double* __restrict__ psum) {
  int t = threadIdx.x;
  if (t < NE) { listpos[t] = 0; psum[t] = 0.0; }
}

// ============================================================
// Wcomb = Wo @ Wfc (fp32), bcomb = bo @ Wfc + bfc
// ============================================================
__global__ __launch_bounds__(256) void k_wcomb(
    const float* __restrict__ Wo, const float* __restrict__ bo,
    const float* __restrict__ Wfc, const float* __restrict__ bfc,
    float* __restrict__ Wc, float* __restrict__ bc) {
  int n = threadIdx.x;
  int k = blockIdx.x;
  if (k < 256) {
    float acc = 0.f;
    #pragma unroll 8
    for (int j = 0; j < 256; ++j) acc += Wo[k * 256 + j] * Wfc[j * 256 + n];
    Wc[k * 256 + n] = acc;
  } else {
    float acc = bfc[n];
    #pragma unroll 8
    for (int j = 0; j < 256; ++j) acc += bo[j] * Wfc[j * 256 + n];
    bc[n] = acc;
  }
}

// ============================================================
// weight swizzle: fp32 W[K x 256] -> bf16 in B-fragment order
// ============================================================
struct SwzArgs {
  const float* src[10];
  int KS[10];
  int lks[10];
  int dstoff[10];
  int gbase[10];
};

__global__ __launch_bounds__(256) void k_swz(SwzArgs a, u16* __restrict__ dst) {
  int g = blockIdx.x * 256 + threadIdx.x;
  if (g >= SWZ_TOTAL_GROUPS) return;
  int i = 0;
  #pragma unroll
  for (int t = 1; t < 10; ++t) if (g >= a.gbase[t]) i = t;
  int gl = g - a.gbase[i];
  int KS = a.KS[i], lks = a.lks[i];
  int l = gl & 63, t2 = gl >> 6;
  int ks = t2 & (KS - 1), ct = t2 >> lks;
  const float* src = a.src[i] + (size_t)(ks * 32 + ((l >> 4) << 3)) * 256 + ct * 16 + (l & 15);
  u16 tmp[8];
  #pragma unroll
  for (int j = 0; j < 8; ++j) tmp[j] = f2bf(src[(size_t)j * 256]);
  uint4 pk;
  pk.x = (unsigned)tmp[0] | ((unsigned)tmp[1] << 16);
  pk.y = (unsigned)tmp[2] | ((unsigned)tmp[3] << 16);
  pk.z = (unsigned)tmp[4] | ((unsigned)tmp[5] << 16);
  pk.w = (unsigned)tmp[6] | ((unsigned)tmp[7] << 16);
  *(uint4*)(dst + a.dstoff[i] + (size_t)gl * 8) = pk;
}

// ============================================================
// gating: fp64 accumulation, LDS-staged coalesced reads.
// r4: register double-buffer of the chunk stream (loads in flight
// across compute) + block-aggregated global atomics.
// ============================================================
__global__ __launch_bounds__(256) void k_gate(
    const float* __restrict__ zg, const float* __restrict__ zn,
    const float* __restrict__ gW, const float* __restrict__ gb,
    int* __restrict__ listpos, double* __restrict__ psum,
    int* __restrict__ lists) {
  __shared__ float xs[32 * 257];
  __shared__ double gwd[512 * 4];
  __shared__ int    wcnt[4][4];   // [wave][expert]
  __shared__ double wps[4][4];
  __shared__ int    wbase[4][4];
  int tid = threadIdx.x, lane = tid & 63, wave = tid >> 6;
  int rowbase = blockIdx.x * 256;
  for (int i = tid; i < 2048; i += 256) gwd[i] = (double)gW[i];
  double l0 = (double)gb[0], l1 = (double)gb[1], l2 = (double)gb[2], l3 = (double)gb[3];

  // stage slice for this thread: 8 float4 per chunk
  float4 pf[8];
  #pragma unroll
  for (int j = 0; j < 8; ++j) {
    int idx = tid + j * 256;
    int row = idx >> 3, off = idx & 7;
    pf[j] = *(const float4*)(zg + (size_t)(rowbase + row) * DD + off * 4);
  }

  for (int c = 0; c < 16; ++c) {
    __syncthreads();   // xs consumers of previous chunk done
    #pragma unroll
    for (int j = 0; j < 8; ++j) {
      int idx = tid + j * 256;
      int row = idx >> 3, off = idx & 7;
      float4 v = pf[j];
      xs[(off * 4 + 0) * 257 + row] = v.x;
      xs[(off * 4 + 1) * 257 + row] = v.y;
      xs[(off * 4 + 2) * 257 + row] = v.z;
      xs[(off * 4 + 3) * 257 + row] = v.w;
    }
    if (c < 15) {
      const float* src = (c + 1 < 8) ? zg : zn;
      int ko = ((c + 1) & 7) * 32;
      #pragma unroll
      for (int j = 0; j < 8; ++j) {
        int idx = tid + j * 256;
        int row = idx >> 3, off = idx & 7;
        pf[j] = *(const float4*)(src + (size_t)(rowbase + row) * DD + ko + off * 4);
      }
    }
    __syncthreads();
    const double* gp = gwd + (size_t)(c * 32) * 4;
    #pragma unroll
    for (int i = 0; i < 32; ++i) {
      double x = (double)xs[i * 257 + tid];
      l0 = fma(x, gp[i * 4 + 0], l0);
      l1 = fma(x, gp[i * 4 + 1], l1);
      l2 = fma(x, gp[i * 4 + 2], l2);
      l3 = fma(x, gp[i * 4 + 3], l3);
    }
  }

  int row = rowbase + tid;
  int e = 0; double lm = l0;
  if (l1 > lm) { lm = l1; e = 1; }
  if (l2 > lm) { lm = l2; e = 2; }
  if (l3 > lm) { lm = l3; e = 3; }
  double s = exp(l0 - lm) + exp(l1 - lm) + exp(l2 - lm) + exp(l3 - lm);
  double p = 1.0 / s;

  // per-wave ballots (static-indexed arrays stay in regs)
  unsigned long long msk[4];
  int cnt[4];
  double pvs[4];
  #pragma unroll
  for (int ee = 0; ee < NE; ++ee) {
    bool mine = (e == ee);
    msk[ee] = __ballot(mine);
    cnt[ee] = __popcll(msk[ee]);
    double pv = mine ? p : 0.0;
    #pragma unroll
    for (int off = 32; off; off >>= 1) pv += __shfl_down(pv, off);
    pvs[ee] = pv;
  }
  if (lane == 0) {
    #pragma unroll
    for (int ee = 0; ee < NE; ++ee) { wcnt[wave][ee] = cnt[ee]; wps[wave][ee] = pvs[ee]; }
  }
  __syncthreads();
  if (tid < NE) {   // one thread per expert: single global atomic pair per block
    int ee = tid;
    int c0 = wcnt[0][ee], c1 = wcnt[1][ee], c2 = wcnt[2][ee], c3 = wcnt[3][ee];
    int tot = c0 + c1 + c2 + c3;
    int base = 0;
    if (tot) {
      base = atomicAdd(&listpos[ee], tot);
      atomicAdd(&psum[ee], wps[0][ee] + wps[1][ee] + wps[2][ee] + wps[3][ee]);
    }
    wbase[0][ee] = base;
    wbase[1][ee] = base + c0;
    wbase[2][ee] = base + c0 + c1;
    wbase[3][ee] = base + c0 + c1 + c2;
  }
  __syncthreads();
  #pragma unroll
  for (int ee = 0; ee < NE; ++ee) {
    if (e == ee) {
      int rank = __popcll(msk[ee] & ((1ull << lane) - 1ull));
      lists[(size_t)ee * BN + wbase[wave][ee] + rank] = row;
    }
  }
}

__global__ void k_finalize(const int* __restrict__ listpos,
                           const double* __restrict__ psum,
                           float* __restrict__ avg, float* __restrict__ aux_out) {
  if (threadIdx.x == 0) {
    double aux = 0.0;
    for (int ee = 0; ee < NE; ++ee) {
      int c = listpos[ee];
      avg[ee] = (c > 0) ? (float)(psum[ee] / (double)c) : 0.0f;
      double u = (double)c / (double)BN;
      aux += u * u;
    }
    *aux_out = (float)(aux * (double)NE);
  }
}

// ============================================================
// MFMA tile core
// ============================================================
template <int KS, int RB>
__device__ __forceinline__ void mfma_gemm(const u16* __restrict__ A, int strideA,
                                          const u16* __restrict__ W,
                                          int wave, int lane, f32x4 acc[RB][4]) {
  int q = lane >> 4, m = lane & 15;
  #pragma unroll
  for (int ks = 0; ks < KS; ++ks) {
    bf16x8 a[RB];
    #pragma unroll
    for (int rb = 0; rb < RB; ++rb)
      a[rb] = *(const bf16x8*)(A + (rb * 16 + m) * strideA + ks * 32 + (q << 3));
    #pragma unroll
    for (int i = 0; i < 4; ++i) {
      int ct = wave * 4 + i;
      bf16x8 b = *(const bf16x8*)(W + (((ct * KS + ks) * 64 + lane) << 3));
      #pragma unroll
      for (int rb = 0; rb < RB; ++rb)
        acc[rb][i] = __builtin_amdgcn_mfma_f32_16x16x32_bf16(a[rb], b, acc[rb][i], 0, 0, 0);
    }
  }
}

// ============================================================
// Expert 0: concat
// ============================================================
__global__ __launch_bounds__(256) void k_concat(
    const float* __restrict__ zg, const float* __restrict__ zn,
    const u16* __restrict__ W1s, const float* __restrict__ b1,
    const u16* __restrict__ W2s, const float* __restrict__ b2,
    const int* __restrict__ listpos, const int* __restrict__ lists,
    const float* __restrict__ avgp, float* __restrict__ out) {
  __shared__ u16 X[32 * 520];
  __shared__ u16 H[32 * 264];
  __shared__ int rl[32];
  int n = listpos[0];
  const int* lst = lists + 0 * (size_t)BN;
  float scale = avgp[0];
  int tid = threadIdx.x, lane = tid & 63, wave = tid >> 6;
  int q = lane >> 4, m = lane & 15;

  for (int tile = blockIdx.x; tile * 32 < n; tile += gridDim.x) {
    int base = tile * 32;
    __syncthreads();
    if (tid < 32) rl[tid] = (base + tid < n) ? lst[base + tid] : -1;
    __syncthreads();
    #pragma unroll
    for (int j = 0; j < 16; ++j) {
      int t = tid + j * 256;
      int row = t >> 7, off = t & 127;
      int r = rl[row];
      float4 v = make_float4(0.f, 0.f, 0.f, 0.f);
      if (r >= 0)
        v = (off < 64) ? *(const float4*)(zg + (size_t)r * DD + off * 4)
                       : *(const float4*)(zn + (size_t)r * DD + (off - 64) * 4);
      ushort4 pk; pk.x = f2bf(v.x); pk.y = f2bf(v.y); pk.z = f2bf(v.z); pk.w = f2bf(v.w);
      *(ushort4*)(X + row * 520 + off * 4) = pk;
    }
    __syncthreads();
    f32x4 acc[2][4] = {};
    mfma_gemm<16, 2>(X, 520, W1s, wave, lane, acc);
    #pragma unroll
    for (int i = 0; i < 4; ++i) {
      int c = (wave * 4 + i) * 16 + m;
      float bb = b1[c];
      #pragma unroll
      for (int rb = 0; rb < 2; ++rb)
        #pragma unroll
        for (int r = 0; r < 4; ++r)
          H[(rb * 16 + q * 4 + r) * 264 + c] = f2bf(fmaxf(acc[rb][i][r] + bb, 0.f));
    }
    __syncthreads();
    f32x4 acc2[2][4] = {};
    mfma_gemm<8, 2>(H, 264, W2s, wave, lane, acc2);
    #pragma unroll
    for (int i = 0; i < 4; ++i) {
      int c = (wave * 4 + i) * 16 + m;
      float bb = b2[c];
      #pragma unroll
      for (int rb = 0; rb < 2; ++rb)
        #pragma unroll
        for (int r = 0; r < 4; ++r) {
          int row = rl[rb * 16 + q * 4 + r];
          if (row >= 0) out[(size_t)row * DD + c] = (acc2[rb][i][r] + bb) * scale;
        }
    }
  }
}

// ============================================================
// Expert 1: mul — 64-row tiles (RB=4).
// ============================================================
__global__ __launch_bounds__(256) void k_mul(
    const float* __restrict__ zg, const float* __restrict__ zn,
    const u16* __restrict__ W1s, const float* __restrict__ b1,
    const u16* __restrict__ W2s, const float* __restrict__ b2,
    const int* __restrict__ listpos, const int* __restrict__ lists,
    const float* __restrict__ avgp, float* __restrict__ out) {
  __shared__ u16 X[64 * 264];
  __shared__ u16 H[64 * 264];
  __shared__ int rl[64];
  int n = listpos[1];
  const int* lst = lists + 1 * (size_t)BN;
  float scale = avgp[1];
  int tid = threadIdx.x, lane = tid & 63, wave = tid >> 6;
  int q = lane >> 4, m = lane & 15;

  for (int tile = blockIdx.x; tile * 64 < n; tile += gridDim.x) {
    int base = tile * 64;
    __syncthreads();
    if (tid < 64) rl[tid] = (base + tid < n) ? lst[base + tid] : -1;
    __syncthreads();
    #pragma unroll
    for (int j = 0; j < 16; ++j) {
      int t = tid + j * 256;
      int row = t >> 6, off = t & 63;
      int r = rl[row];
      float4 v = make_float4(0.f, 0.f, 0.f, 0.f);
      if (r >= 0) {
        float4 g = *(const float4*)(zg + (size_t)r * DD + off * 4);
        float4 h = *(const float4*)(zn + (size_t)r * DD + off * 4);
        v = make_float4(g.x * h.x, g.y * h.y, g.z * h.z, g.w * h.w);
      }
      ushort4 pk; pk.x = f2bf(v.x); pk.y = f2bf(v.y); pk.z = f2bf(v.z); pk.w = f2bf(v.w);
      *(ushort4*)(X + row * 264 + off * 4) = pk;
    }
    __syncthreads();
    f32x4 acc[4][4] = {};
    mfma_gemm<8, 4>(X, 264, W1s, wave, lane, acc);
    #pragma unroll
    for (int i = 0; i < 4; ++i) {
      int c = (wave * 4 + i) * 16 + m;
      float bb = b1[c];
      #pragma unroll
      for (int rb = 0; rb < 4; ++rb)
        #pragma unroll
        for (int r = 0; r < 4; ++r)
          H[(rb * 16 + q * 4 + r) * 264 + c] = f2bf(fmaxf(acc[rb][i][r] + bb, 0.f));
    }
    __syncthreads();
    f32x4 acc2[4][4] = {};
    mfma_gemm<8, 4>(H, 264, W2s, wave, lane, acc2);
    #pragma unroll
    for (int i = 0; i < 4; ++i) {
      int c = (wave * 4 + i) * 16 + m;
      float bb = b2[c];
      #pragma unroll
      for (int rb = 0; rb < 4; ++rb)
        #pragma unroll
        for (int r = 0; r < 4; ++r) {
          int row = rl[rb * 16 + q * 4 + r];
          if (row >= 0) out[(size_t)row * DD + c] = (acc2[rb][i][r] + bb) * scale;
        }
    }
  }
}

// ============================================================
// Expert 3: wsum
// ============================================================
__global__ __launch_bounds__(256) void k_wsum(
    const float* __restrict__ zg, const float* __restrict__ zn,
    const u16* __restrict__ Was, const float* __restrict__ ba,
    const u16* __restrict__ Wos, const float* __restrict__ bo,
    const int* __restrict__ listpos, const int* __restrict__ lists,
    const float* __restrict__ avgp, float* __restrict__ out) {
  __shared__ u16 X[32 * 520];
  __shared__ u16 H[32 * 264];
  __shared__ int rl[32];
  int n = listpos[3];
  const int* lst = lists + 3 * (size_t)BN;
  float scale = avgp[3];
  int tid = threadIdx.x, lane = tid & 63, wave = tid >> 6;
  int q = lane >> 4, m = lane & 15;

  for (int tile = blockIdx.x; tile * 32 < n; tile += gridDim.x) {
    int base = tile * 32;
    __syncthreads();
    if (tid < 32) rl[tid] = (base + tid < n) ? lst[base + tid] : -1;
    __syncthreads();
    #pragma unroll
    for (int j = 0; j < 16; ++j) {
      int t = tid + j * 256;
      int row = t >> 7, off = t & 127;
      int r = rl[row];
      float4 v = make_float4(0.f, 0.f, 0.f, 0.f);
      if (r >= 0)
        v = (off < 64) ? *(const float4*)(zg + (size_t)r * DD + off * 4)
                       : *(const float4*)(zn + (size_t)r * DD + (off - 64) * 4);
      ushort4 pk; pk.x = f2bf(v.x); pk.y = f2bf(v.y); pk.z = f2bf(v.z); pk.w = f2bf(v.w);
      *(ushort4*)(X + row * 520 + off * 4) = pk;
    }
    __syncthreads();
    f32x4 acc[2][4] = {};
    mfma_gemm<16, 2>(X, 520, Was, wave, lane, acc);
    #pragma unroll
    for (int i = 0; i < 4; ++i) {
      int c = (wave * 4 + i) * 16 + m;
      float bb = ba[c];
      #pragma unroll
      for (int rb = 0; rb < 2; ++rb)
        #pragma unroll
        for (int r = 0; r < 4; ++r) {
          int vr = rb * 16 + q * 4 + r;
          float al = 1.f / (1.f + __expf(-(acc[rb][i][r] + bb)));
          float xg = bf2f(X[vr * 520 + c]);
          float xn = bf2f(X[vr * 520 + 256 + c]);
          H[vr * 264 + c] = f2bf(al * xg + (1.f - al) * xn);
        }
    }
    __syncthreads();
    f32x4 acc2[2][4] = {};
    mfma_gemm<8, 2>(H, 264, Wos, wave, lane, acc2);
    #pragma unroll
    for (int i = 0; i < 4; ++i) {
      int c = (wave * 4 + i) * 16 + m;
      float bb = bo[c];
      #pragma unroll
      for (int rb = 0; rb < 2; ++rb)
        #pragma unroll
        for (int r = 0; r < 4; ++r) {
          int row = rl[rb * 16 + q * 4 + r];
          if (row >= 0) out[(size_t)row * DD + c] = (acc2[rb][i][r] + bb) * scale;
        }
    }
  }
}

// ============================================================
// Expert 2, stage A: 32-row tiles (64 vrows), RB=4.
// ============================================================
__global__ __launch_bounds__(256) void k_attn(
    const float* __restrict__ zg, const float* __restrict__ zn,
    const u16* __restrict__ Wqs, const float* __restrict__ bq,
    const u16* __restrict__ Wks, const float* __restrict__ bk,
    const u16* __restrict__ Wvs, const float* __restrict__ bv,
    const int* __restrict__ listpos, const int* __restrict__ lists,
    float* __restrict__ out) {
  __shared__ u16 X[64 * 264];
  __shared__ u16 Qb[64 * 264];
  __shared__ int rl[32];
  int n = listpos[2];
  const int* lst = lists + 2 * (size_t)BN;
  int tid = threadIdx.x, lane = tid & 63, wave = tid >> 6;
  int q = lane >> 4, m = lane & 15;

  float bqv[4], bkv[4], bvv[4];
  #pragma unroll
  for (int i = 0; i < 4; ++i) {
    int c = wave * 64 + i * 16 + m;
    bqv[i] = bq[c]; bkv[i] = bk[c]; bvv[i] = bv[c];
  }

  for (int tile = blockIdx.x; tile * 32 < n; tile += gridDim.x) {
    int base = tile * 32;
    __syncthreads();
    if (tid < 32) rl[tid] = (base + tid < n) ? lst[base + tid] : -1;
    __syncthreads();
    #pragma unroll
    for (int j = 0; j < 16; ++j) {
      int t = tid + j * 256;
      int v = t >> 6, off = t & 63;
      int r = rl[v >> 1];
      float4 val = make_float4(0.f, 0.f, 0.f, 0.f);
      if (r >= 0)
        val = (v & 1) ? *(const float4*)(zn + (size_t)r * DD + off * 4)
                      : *(const float4*)(zg + (size_t)r * DD + off * 4);
      ushort4 pk; pk.x = f2bf(val.x); pk.y = f2bf(val.y); pk.z = f2bf(val.z); pk.w = f2bf(val.w);
      *(ushort4*)(X + v * 264 + off * 4) = pk;
    }
    __syncthreads();
    // ---- Q pass -> Qb ----
    {
      f32x4 a1[4][4] = {};
      mfma_gemm<8, 4>(X, 264, Wqs, wave, lane, a1);
      #pragma unroll
      for (int i = 0; i < 4; ++i) {
        int c = (wave * 4 + i) * 16 + m;
        #pragma unroll
        for (int rb = 0; rb < 4; ++rb)
          #pragma unroll
          for (int r = 0; r < 4; ++r)
            Qb[(rb * 16 + q * 4 + r) * 264 + c] = f2bf(a1[rb][i][r] + bqv[i]);
      }
    }
    // ---- K pass in regs + scores + coeffs ----
    float C0[4][2], C1[4][2];
    {
      f32x4 ka[4][4] = {};
      mfma_gemm<8, 4>(X, 264, Wks, wave, lane, ka);
      #pragma unroll
      for (int rb = 0; rb < 4; ++rb) {
        #pragma unroll
        for (int pr = 0; pr < 2; ++pr) {
          int rloc = rb * 8 + q * 2 + pr;
          float p00 = 0.f, p01 = 0.f, p10 = 0.f, p11 = 0.f;
          #pragma unroll
          for (int i = 0; i < 4; ++i) {
            float ke = ka[rb][i][2 * pr] + bkv[i];
            float ko = ka[rb][i][2 * pr + 1] + bkv[i];
            int cidx = wave * 64 + i * 16 + m;
            float q0 = bf2f(Qb[(2 * rloc) * 264 + cidx]);
            float q1 = bf2f(Qb[(2 * rloc + 1) * 264 + cidx]);
            p00 += q0 * ke; p01 += q0 * ko;
            p10 += q1 * ke; p11 += q1 * ko;
          }
          #pragma unroll
          for (int msk = 1; msk < 16; msk <<= 1) {
            p00 += __shfl_xor(p00, msk);
            p01 += __shfl_xor(p01, msk);
            p10 += __shfl_xor(p10, msk);
            p11 += __shfl_xor(p11, msk);
          }
          float s00 = 1.f / (1.f + __expf((p01 - p00) * 0.125f));
          float s10 = 1.f / (1.f + __expf((p11 - p10) * 0.125f));
          float c0 = 0.5f * (s00 + s10);
          C0[rb][pr] = c0; C1[rb][pr] = 1.f - c0;
        }
      }
    }
    // ---- V pass in regs; M -> out (f32 workspace) ----
    {
      f32x4 va[4][4] = {};
      mfma_gemm<8, 4>(X, 264, Wvs, wave, lane, va);
      #pragma unroll
      for (int rb = 0; rb < 4; ++rb)
        #pragma unroll
        for (int pr = 0; pr < 2; ++pr) {
          int rloc = rb * 8 + q * 2 + pr;
          int grow = rl[rloc];
          if (grow >= 0) {
            #pragma unroll
            for (int i = 0; i < 4; ++i) {
              float mv = C0[rb][pr] * (va[rb][i][2 * pr] + bvv[i])
                       + C1[rb][pr] * (va[rb][i][2 * pr + 1] + bvv[i]);
              out[(size_t)grow * DD + wave * 64 + i * 16 + m] = mv;
            }
          }
        }
    }
  }
}

// ============================================================
// Expert 2, stage B: M @ Wcomb + bcomb -> out.
// ============================================================
__global__ __launch_bounds__(256) void k_attn_fc(
    const u16* __restrict__ Wcs, const float* __restrict__ bc,
    const int* __restrict__ listpos, const int* __restrict__ lists,
    const float* __restrict__ avgp, float* __restrict__ out) {
  __shared__ u16 Mb[32 * 264];
  __shared__ int rl[32];
  int n = listpos[2];
  const int* lst = lists + 2 * (size_t)BN;
  float scale = avgp[2];
  int tid = threadIdx.x, lane = tid & 63, wave = tid >> 6;
  int q = lane >> 4, m = lane & 15;

  for (int tile = blockIdx.x; tile * 32 < n; tile += gridDim.x) {
    int base = tile * 32;
    __syncthreads();
    if (tid < 32) rl[tid] = (base + tid < n) ? lst[base + tid] : -1;
    __syncthreads();
    #pragma unroll
    for (int j = 0; j < 8; ++j) {
      int t = tid + j * 256;
      int row = t >> 6, off = t & 63;
      int r = rl[row];
      float4 v = make_float4(0.f, 0.f, 0.f, 0.f);
      if (r >= 0) v = *(const float4*)(out + (size_t)r * DD + off * 4);
      ushort4 pk; pk.x = f2bf(v.x); pk.y = f2bf(v.y); pk.z = f2bf(v.z); pk.w = f2bf(v.w);
      *(ushort4*)(Mb + row * 264 + off * 4) = pk;
    }
    __syncthreads();
    f32x4 acc[2][4] = {};
    mfma_gemm<8, 2>(Mb, 264, Wcs, wave, lane, acc);
    #pragma unroll
    for (int i = 0; i < 4; ++i) {
      int c = (wave * 4 + i) * 16 + m;
      float bb = bc[c];
      #pragma unroll
      for (int rb = 0; rb < 2; ++rb)
        #pragma unroll
        for (int r = 0; r < 4; ++r) {
          int row = rl[rb * 16 + q * 4 + r];
          if (row >= 0) out[(size_t)row * DD + c] = (acc[rb][i][r] + bb) * scale;
        }
    }
  }
}

// ============================================================
// launch
// ============================================================
extern "C" void kernel_launch(void* const* d_in, const int* in_sizes, int n_in,
                              void* d_out, int out_size, void* d_ws, size_t ws_size,
                              hipStream_t stream) {
  const float* zg   = (const float*)d_in[0];
  const float* zn   = (const float*)d_in[1];
  const float* gW   = (const float*)d_in[2];
  const float* gb   = (const float*)d_in[3];
  const float* cW1  = (const float*)d_in[4];
  const float* cb1  = (const float*)d_in[5];
  const float* cW2  = (const float*)d_in[6];
  const float* cb2  = (const float*)d_in[7];
  const float* mW1  = (const float*)d_in[8];
  const float* mb1  = (const float*)d_in[9];
  const float* mW2  = (const float*)d_in[10];
  const float* mb2  = (const float*)d_in[11];
  const float* aWq  = (const float*)d_in[12];
  const float* abq  = (const float*)d_in[13];
  const float* aWk  = (const float*)d_in[14];
  const float* abk  = (const float*)d_in[15];
  const float* aWv  = (const float*)d_in[16];
  const float* abv  = (const float*)d_in[17];
  const float* aWo  = (const float*)d_in[18];
  const float* abo  = (const float*)d_in[19];
  const float* aWfc = (const float*)d_in[20];
  const float* abfc = (const float*)d_in[21];
  const float* wWa  = (const float*)d_in[22];
  const float* wba  = (const float*)d_in[23];
  const float* wWo  = (const float*)d_in[24];
  const float* wbo  = (const float*)d_in[25];
  float* out = (float*)d_out;

  char* ws = (char*)d_ws;
  double* psum  = (double*)ws;
  int* listpos  = (int*)(ws + 32);
  float* avg    = (float*)(ws + 48);
  int* lists    = (int*)(ws + 64);
  u16* wsw      = (u16*)(ws + WS_SWZ_OFF);
  float* wcf32  = (float*)(ws + 64);          // transient: overlaps lists[0]
  float* bcomb  = (float*)(ws + BCOMB_OFF);   // persistent

  SwzArgs sa;
  const float* srcs[10] = {cW1, cW2, mW1, mW2, aWq, aWk, aWv, wcf32, wWa, wWo};
  const int   kss[10]  = {16, 8, 8, 8, 8, 8, 8, 8, 16, 8};
  const int   offs[10] = {OFF_CW1, OFF_CW2, OFF_MW1, OFF_MW2, OFF_AWQ, OFF_AWK,
                          OFF_AWV, OFF_WCB, OFF_WWA, OFF_WWO};
  int gb_acc = 0;
  for (int i = 0; i < 10; ++i) {
    sa.src[i] = srcs[i];
    sa.KS[i] = kss[i];
    sa.lks[i] = (kss[i] == 16) ? 4 : 3;
    sa.dstoff[i] = offs[i];
    sa.gbase[i] = gb_acc;
    gb_acc += kss[i] * 1024;
  }

  hipLaunchKernelGGL(k_init, dim3(1), dim3(64), 0, stream, listpos, psum);
  hipLaunchKernelGGL(k_wcomb, dim3(257), dim3(256), 0, stream,
                     aWo, abo, aWfc, abfc, wcf32, bcomb);
  hipLaunchKernelGGL(k_swz, dim3(SWZ_TOTAL_GROUPS / 256), dim3(256), 0, stream, sa, wsw);
  hipLaunchKernelGGL(k_gate, dim3(BN / 256), dim3(256), 0, stream,
                     zg, zn, gW, gb, listpos, psum, lists);
  hipLaunchKernelGGL(k_finalize, dim3(1), dim3(64), 0, stream,
                     listpos, psum, avg, out + (size_t)BN * DD);
  hipLaunchKernelGGL(k_concat, dim3(1024), dim3(256), 0, stream,
                     zg, zn, wsw + OFF_CW1, cb1, wsw + OFF_CW2, cb2, listpos, lists, avg, out);
  hipLaunchKernelGGL(k_mul, dim3(512), dim3(256), 0, stream,
                     zg, zn, wsw + OFF_MW1, mb1, wsw + OFF_MW2, mb2, listpos, lists, avg, out);
  hipLaunchKernelGGL(k_attn, dim3(1024), dim3(256), 0, stream,
                     zg, zn, wsw + OFF_AWQ, abq, wsw + OFF_AWK, abk, wsw + OFF_AWV, abv,
                     listpos, lists, out);
  hipLaunchKernelGGL(k_attn_fc, dim3(1024), dim3(256), 0, stream,
                     wsw + OFF_WCB, bcomb, listpos, lists, avg, out);
  hipLaunchKernelGGL(k_wsum, dim3(1024), dim3(256), 0, stream,
                     zg, zn, wsw + OFF_WWA, wba, wsw + OFF_WWO, wbo, listpos, lists, avg, out);
}

// Round 5
// 711.863 us; speedup vs baseline: 2.0724x; 1.2067x over previous
//
#include <hip/hip_runtime.h>
#include <math.h>

#define BN 131072
#define DD 256
#define NE 4

typedef unsigned short u16;
typedef __bf16 bf16x8 __attribute__((ext_vector_type(8)));
typedef float f32x4 __attribute__((ext_vector_type(4)));

__device__ __forceinline__ u16 f2bf(float f) {
  union { float f; unsigned int u; } v; v.f = f;
  unsigned int u = v.u;
  unsigned int r = (u + 0x7FFFu + ((u >> 16) & 1u)) >> 16;
  return (u16)r;
}
__device__ __forceinline__ float bf2f(u16 x) {
  union { unsigned int u; float f; } v; v.u = ((unsigned int)x) << 16; return v.f;
}

// ---------------- workspace layout (d_ws) ----------------
// [0,32)    double psum[4]
// [32,48)   int    listpos[4]
// [48,64)   float  avg[4]
// [64, 64+4*BN*4)  int lists[4][BN]
//   NOTE: first 256KB of lists[0] is transiently reused as fp32 Wcomb
//   (k_wcomb writes it, k_swz reads it, both BEFORE k_gate writes lists).
// [2097216, +1572864) u16 swizzled bf16 weights (10 matrices)
// [3670080, +1024)    float bcomb[256]  (persists through expert kernels)
#define WS_SWZ_OFF 2097216
#define BCOMB_OFF  3670080

#define OFF_CW1  0
#define OFF_CW2  131072
#define OFF_MW1  196608
#define OFF_MW2  262144
#define OFF_AWQ  327680
#define OFF_AWK  393216
#define OFF_AWV  458752
#define OFF_WCB  524288
#define OFF_WWA  589824
#define OFF_WWO  720896
#define SWZ_TOTAL_GROUPS 98304   // 786432/8

// ============================================================
// init
// ============================================================
__global__ void k_init(int* __restrict__ listpos, double* __restrict__ psum) {
  int t = threadIdx.x;
  if (t < NE) { listpos[t] = 0; psum[t] = 0.0; }
}

// ============================================================
// Wcomb = Wo @ Wfc (fp32), bcomb = bo @ Wfc + bfc
// ============================================================
__global__ __launch_bounds__(256) void k_wcomb(
    const float* __restrict__ Wo, const float* __restrict__ bo,
    const float* __restrict__ Wfc, const float* __restrict__ bfc,
    float* __restrict__ Wc, float* __restrict__ bc) {
  int n = threadIdx.x;
  int k = blockIdx.x;
  if (k < 256) {
    float acc = 0.f;
    #pragma unroll 8
    for (int j = 0; j < 256; ++j) acc += Wo[k * 256 + j] * Wfc[j * 256 + n];
    Wc[k * 256 + n] = acc;
  } else {
    float acc = bfc[n];
    #pragma unroll 8
    for (int j = 0; j < 256; ++j) acc += bo[j] * Wfc[j * 256 + n];
    bc[n] = acc;
  }
}

// ============================================================
// weight swizzle: fp32 W[K x 256] -> bf16 in B-fragment order
// ============================================================
struct SwzArgs {
  const float* src[10];
  int KS[10];
  int lks[10];
  int dstoff[10];
  int gbase[10];
};

__global__ __launch_bounds__(256) void k_swz(SwzArgs a, u16* __restrict__ dst) {
  int g = blockIdx.x * 256 + threadIdx.x;
  if (g >= SWZ_TOTAL_GROUPS) return;
  int i = 0;
  #pragma unroll
  for (int t = 1; t < 10; ++t) if (g >= a.gbase[t]) i = t;
  int gl = g - a.gbase[i];
  int KS = a.KS[i], lks = a.lks[i];
  int l = gl & 63, t2 = gl >> 6;
  int ks = t2 & (KS - 1), ct = t2 >> lks;
  const float* src = a.src[i] + (size_t)(ks * 32 + ((l >> 4) << 3)) * 256 + ct * 16 + (l & 15);
  u16 tmp[8];
  #pragma unroll
  for (int j = 0; j < 8; ++j) tmp[j] = f2bf(src[(size_t)j * 256]);
  uint4 pk;
  pk.x = (unsigned)tmp[0] | ((unsigned)tmp[1] << 16);
  pk.y = (unsigned)tmp[2] | ((unsigned)tmp[3] << 16);
  pk.z = (unsigned)tmp[4] | ((unsigned)tmp[5] << 16);
  pk.w = (unsigned)tmp[6] | ((unsigned)tmp[7] << 16);
  *(uint4*)(dst + a.dstoff[i] + (size_t)gl * 8) = pk;
}

// ============================================================
// gating: fp64 accumulation, LDS-staged coalesced reads,
// register double-buffer, block-aggregated atomics.
// ============================================================
__global__ __launch_bounds__(256) void k_gate(
    const float* __restrict__ zg, const float* __restrict__ zn,
    const float* __restrict__ gW, const float* __restrict__ gb,
    int* __restrict__ listpos, double* __restrict__ psum,
    int* __restrict__ lists) {
  __shared__ float xs[32 * 257];
  __shared__ double gwd[512 * 4];
  __shared__ int    wcnt[4][4];   // [wave][expert]
  __shared__ double wps[4][4];
  __shared__ int    wbase[4][4];
  int tid = threadIdx.x, lane = tid & 63, wave = tid >> 6;
  int rowbase = blockIdx.x * 256;
  for (int i = tid; i < 2048; i += 256) gwd[i] = (double)gW[i];
  double l0 = (double)gb[0], l1 = (double)gb[1], l2 = (double)gb[2], l3 = (double)gb[3];

  float4 pf[8];
  #pragma unroll
  for (int j = 0; j < 8; ++j) {
    int idx = tid + j * 256;
    int row = idx >> 3, off = idx & 7;
    pf[j] = *(const float4*)(zg + (size_t)(rowbase + row) * DD + off * 4);
  }

  for (int c = 0; c < 16; ++c) {
    __syncthreads();
    #pragma unroll
    for (int j = 0; j < 8; ++j) {
      int idx = tid + j * 256;
      int row = idx >> 3, off = idx & 7;
      float4 v = pf[j];
      xs[(off * 4 + 0) * 257 + row] = v.x;
      xs[(off * 4 + 1) * 257 + row] = v.y;
      xs[(off * 4 + 2) * 257 + row] = v.z;
      xs[(off * 4 + 3) * 257 + row] = v.w;
    }
    if (c < 15) {
      const float* src = (c + 1 < 8) ? zg : zn;
      int ko = ((c + 1) & 7) * 32;
      #pragma unroll
      for (int j = 0; j < 8; ++j) {
        int idx = tid + j * 256;
        int row = idx >> 3, off = idx & 7;
        pf[j] = *(const float4*)(src + (size_t)(rowbase + row) * DD + ko + off * 4);
      }
    }
    __syncthreads();
    const double* gp = gwd + (size_t)(c * 32) * 4;
    #pragma unroll
    for (int i = 0; i < 32; ++i) {
      double x = (double)xs[i * 257 + tid];
      l0 = fma(x, gp[i * 4 + 0], l0);
      l1 = fma(x, gp[i * 4 + 1], l1);
      l2 = fma(x, gp[i * 4 + 2], l2);
      l3 = fma(x, gp[i * 4 + 3], l3);
    }
  }

  int row = rowbase + tid;
  int e = 0; double lm = l0;
  if (l1 > lm) { lm = l1; e = 1; }
  if (l2 > lm) { lm = l2; e = 2; }
  if (l3 > lm) { lm = l3; e = 3; }
  double s = exp(l0 - lm) + exp(l1 - lm) + exp(l2 - lm) + exp(l3 - lm);
  double p = 1.0 / s;

  unsigned long long msk[4];
  int cnt[4];
  double pvs[4];
  #pragma unroll
  for (int ee = 0; ee < NE; ++ee) {
    bool mine = (e == ee);
    msk[ee] = __ballot(mine);
    cnt[ee] = __popcll(msk[ee]);
    double pv = mine ? p : 0.0;
    #pragma unroll
    for (int off = 32; off; off >>= 1) pv += __shfl_down(pv, off);
    pvs[ee] = pv;
  }
  if (lane == 0) {
    #pragma unroll
    for (int ee = 0; ee < NE; ++ee) { wcnt[wave][ee] = cnt[ee]; wps[wave][ee] = pvs[ee]; }
  }
  __syncthreads();
  if (tid < NE) {
    int ee = tid;
    int c0 = wcnt[0][ee], c1 = wcnt[1][ee], c2 = wcnt[2][ee], c3 = wcnt[3][ee];
    int tot = c0 + c1 + c2 + c3;
    int base = 0;
    if (tot) {
      base = atomicAdd(&listpos[ee], tot);
      atomicAdd(&psum[ee], wps[0][ee] + wps[1][ee] + wps[2][ee] + wps[3][ee]);
    }
    wbase[0][ee] = base;
    wbase[1][ee] = base + c0;
    wbase[2][ee] = base + c0 + c1;
    wbase[3][ee] = base + c0 + c1 + c2;
  }
  __syncthreads();
  #pragma unroll
  for (int ee = 0; ee < NE; ++ee) {
    if (e == ee) {
      int rank = __popcll(msk[ee] & ((1ull << lane) - 1ull));
      lists[(size_t)ee * BN + wbase[wave][ee] + rank] = row;
    }
  }
}

__global__ void k_finalize(const int* __restrict__ listpos,
                           const double* __restrict__ psum,
                           float* __restrict__ avg, float* __restrict__ aux_out) {
  if (threadIdx.x == 0) {
    double aux = 0.0;
    for (int ee = 0; ee < NE; ++ee) {
      int c = listpos[ee];
      avg[ee] = (c > 0) ? (float)(psum[ee] / (double)c) : 0.0f;
      double u = (double)c / (double)BN;
      aux += u * u;
    }
    *aux_out = (float)(aux * (double)NE);
  }
}

// ============================================================
// MFMA tile cores.
// mfma_gemm: fully-unrolled (RB<=2 only; deep compiler prefetch OK).
// mfma_gemm_p: #pragma unroll 1 + explicit 2-deep B double-buffer —
//   caps live B regs at 32 so RB=4 kernels don't spill to scratch.
// ============================================================
template <int KS, int RB>
__device__ __forceinline__ void mfma_gemm(const u16* __restrict__ A, int strideA,
                                          const u16* __restrict__ W,
                                          int wave, int lane, f32x4 acc[RB][4]) {
  int q = lane >> 4, m = lane & 15;
  #pragma unroll
  for (int ks = 0; ks < KS; ++ks) {
    bf16x8 a[RB];
    #pragma unroll
    for (int rb = 0; rb < RB; ++rb)
      a[rb] = *(const bf16x8*)(A + (rb * 16 + m) * strideA + ks * 32 + (q << 3));
    #pragma unroll
    for (int i = 0; i < 4; ++i) {
      int ct = wave * 4 + i;
      bf16x8 b = *(const bf16x8*)(W + (((ct * KS + ks) * 64 + lane) << 3));
      #pragma unroll
      for (int rb = 0; rb < RB; ++rb)
        acc[rb][i] = __builtin_amdgcn_mfma_f32_16x16x32_bf16(a[rb], b, acc[rb][i], 0, 0, 0);
    }
  }
}

template <int KS, int RB>
__device__ __forceinline__ void mfma_gemm_p(const u16* __restrict__ A, int strideA,
                                            const u16* __restrict__ W,
                                            int wave, int lane, f32x4 acc[RB][4]) {
  int q = lane >> 4, m = lane & 15;
  const u16* wb = W + (((size_t)(wave * 4 * KS) * 64 + lane) << 3);
  // fragment (i, ks) at wb + ((i*KS + ks)*64)<<3
  bf16x8 b0[4], b1[4];
  #pragma unroll
  for (int i = 0; i < 4; ++i)
    b0[i] = *(const bf16x8*)(wb + (((size_t)(i * KS) * 64) << 3));
  #pragma unroll 1
  for (int ks = 0; ks < KS; ks += 2) {
    #pragma unroll
    for (int i = 0; i < 4; ++i)
      b1[i] = *(const bf16x8*)(wb + (((size_t)(i * KS + ks + 1) * 64) << 3));
    bf16x8 a[RB];
    #pragma unroll
    for (int rb = 0; rb < RB; ++rb)
      a[rb] = *(const bf16x8*)(A + (rb * 16 + m) * strideA + ks * 32 + (q << 3));
    #pragma unroll
    for (int i = 0; i < 4; ++i)
      #pragma unroll
      for (int rb = 0; rb < RB; ++rb)
        acc[rb][i] = __builtin_amdgcn_mfma_f32_16x16x32_bf16(a[rb], b0[i], acc[rb][i], 0, 0, 0);
    if (ks + 2 < KS) {
      #pragma unroll
      for (int i = 0; i < 4; ++i)
        b0[i] = *(const bf16x8*)(wb + (((size_t)(i * KS + ks + 2) * 64) << 3));
    }
    #pragma unroll
    for (int rb = 0; rb < RB; ++rb)
      a[rb] = *(const bf16x8*)(A + (rb * 16 + m) * strideA + (ks + 1) * 32 + (q << 3));
    #pragma unroll
    for (int i = 0; i < 4; ++i)
      #pragma unroll
      for (int rb = 0; rb < RB; ++rb)
        acc[rb][i] = __builtin_amdgcn_mfma_f32_16x16x32_bf16(a[rb], b1[i], acc[rb][i], 0, 0, 0);
  }
}

// ============================================================
// Expert 0: concat
// ============================================================
__global__ __launch_bounds__(256) void k_concat(
    const float* __restrict__ zg, const float* __restrict__ zn,
    const u16* __restrict__ W1s, const float* __restrict__ b1,
    const u16* __restrict__ W2s, const float* __restrict__ b2,
    const int* __restrict__ listpos, const int* __restrict__ lists,
    const float* __restrict__ avgp, float* __restrict__ out) {
  __shared__ u16 X[32 * 520];
  __shared__ u16 H[32 * 264];
  __shared__ int rl[32];
  int n = listpos[0];
  const int* lst = lists + 0 * (size_t)BN;
  float scale = avgp[0];
  int tid = threadIdx.x, lane = tid & 63, wave = tid >> 6;
  int q = lane >> 4, m = lane & 15;

  for (int tile = blockIdx.x; tile * 32 < n; tile += gridDim.x) {
    int base = tile * 32;
    __syncthreads();
    if (tid < 32) rl[tid] = (base + tid < n) ? lst[base + tid] : -1;
    __syncthreads();
    #pragma unroll
    for (int j = 0; j < 16; ++j) {
      int t = tid + j * 256;
      int row = t >> 7, off = t & 127;
      int r = rl[row];
      float4 v = make_float4(0.f, 0.f, 0.f, 0.f);
      if (r >= 0)
        v = (off < 64) ? *(const float4*)(zg + (size_t)r * DD + off * 4)
                       : *(const float4*)(zn + (size_t)r * DD + (off - 64) * 4);
      ushort4 pk; pk.x = f2bf(v.x); pk.y = f2bf(v.y); pk.z = f2bf(v.z); pk.w = f2bf(v.w);
      *(ushort4*)(X + row * 520 + off * 4) = pk;
    }
    __syncthreads();
    f32x4 acc[2][4] = {};
    mfma_gemm<16, 2>(X, 520, W1s, wave, lane, acc);
    #pragma unroll
    for (int i = 0; i < 4; ++i) {
      int c = (wave * 4 + i) * 16 + m;
      float bb = b1[c];
      #pragma unroll
      for (int rb = 0; rb < 2; ++rb)
        #pragma unroll
        for (int r = 0; r < 4; ++r)
          H[(rb * 16 + q * 4 + r) * 264 + c] = f2bf(fmaxf(acc[rb][i][r] + bb, 0.f));
    }
    __syncthreads();
    f32x4 acc2[2][4] = {};
    mfma_gemm<8, 2>(H, 264, W2s, wave, lane, acc2);
    #pragma unroll
    for (int i = 0; i < 4; ++i) {
      int c = (wave * 4 + i) * 16 + m;
      float bb = b2[c];
      #pragma unroll
      for (int rb = 0; rb < 2; ++rb)
        #pragma unroll
        for (int r = 0; r < 4; ++r) {
          int row = rl[rb * 16 + q * 4 + r];
          if (row >= 0) out[(size_t)row * DD + c] = (acc2[rb][i][r] + bb) * scale;
        }
    }
  }
}

// ============================================================
// Expert 1: mul — 64-row tiles (RB=4), pipelined gemm (no spills).
// ============================================================
__global__ __launch_bounds__(256) void k_mul(
    const float* __restrict__ zg, const float* __restrict__ zn,
    const u16* __restrict__ W1s, const float* __restrict__ b1,
    const u16* __restrict__ W2s, const float* __restrict__ b2,
    const int* __restrict__ listpos, const int* __restrict__ lists,
    const float* __restrict__ avgp, float* __restrict__ out) {
  __shared__ u16 X[64 * 264];
  __shared__ u16 H[64 * 264];
  __shared__ int rl[64];
  int n = listpos[1];
  const int* lst = lists + 1 * (size_t)BN;
  float scale = avgp[1];
  int tid = threadIdx.x, lane = tid & 63, wave = tid >> 6;
  int q = lane >> 4, m = lane & 15;

  for (int tile = blockIdx.x; tile * 64 < n; tile += gridDim.x) {
    int base = tile * 64;
    __syncthreads();
    if (tid < 64) rl[tid] = (base + tid < n) ? lst[base + tid] : -1;
    __syncthreads();
    #pragma unroll
    for (int j = 0; j < 16; ++j) {
      int t = tid + j * 256;
      int row = t >> 6, off = t & 63;
      int r = rl[row];
      float4 v = make_float4(0.f, 0.f, 0.f, 0.f);
      if (r >= 0) {
        float4 g = *(const float4*)(zg + (size_t)r * DD + off * 4);
        float4 h = *(const float4*)(zn + (size_t)r * DD + off * 4);
        v = make_float4(g.x * h.x, g.y * h.y, g.z * h.z, g.w * h.w);
      }
      ushort4 pk; pk.x = f2bf(v.x); pk.y = f2bf(v.y); pk.z = f2bf(v.z); pk.w = f2bf(v.w);
      *(ushort4*)(X + row * 264 + off * 4) = pk;
    }
    __syncthreads();
    f32x4 acc[4][4] = {};
    mfma_gemm_p<8, 4>(X, 264, W1s, wave, lane, acc);
    #pragma unroll
    for (int i = 0; i < 4; ++i) {
      int c = (wave * 4 + i) * 16 + m;
      float bb = b1[c];
      #pragma unroll
      for (int rb = 0; rb < 4; ++rb)
        #pragma unroll
        for (int r = 0; r < 4; ++r)
          H[(rb * 16 + q * 4 + r) * 264 + c] = f2bf(fmaxf(acc[rb][i][r] + bb, 0.f));
    }
    __syncthreads();
    f32x4 acc2[4][4] = {};
    mfma_gemm_p<8, 4>(H, 264, W2s, wave, lane, acc2);
    #pragma unroll
    for (int i = 0; i < 4; ++i) {
      int c = (wave * 4 + i) * 16 + m;
      float bb = b2[c];
      #pragma unroll
      for (int rb = 0; rb < 4; ++rb)
        #pragma unroll
        for (int r = 0; r < 4; ++r) {
          int row = rl[rb * 16 + q * 4 + r];
          if (row >= 0) out[(size_t)row * DD + c] = (acc2[rb][i][r] + bb) * scale;
        }
    }
  }
}

// ============================================================
// Expert 3: wsum
// ============================================================
__global__ __launch_bounds__(256) void k_wsum(
    const float* __restrict__ zg, const float* __restrict__ zn,
    const u16* __restrict__ Was, const float* __restrict__ ba,
    const u16* __restrict__ Wos, const float* __restrict__ bo,
    const int* __restrict__ listpos, const int* __restrict__ lists,
    const float* __restrict__ avgp, float* __restrict__ out) {
  __shared__ u16 X[32 * 520];
  __shared__ u16 H[32 * 264];
  __shared__ int rl[32];
  int n = listpos[3];
  const int* lst = lists + 3 * (size_t)BN;
  float scale = avgp[3];
  int tid = threadIdx.x, lane = tid & 63, wave = tid >> 6;
  int q = lane >> 4, m = lane & 15;

  for (int tile = blockIdx.x; tile * 32 < n; tile += gridDim.x) {
    int base = tile * 32;
    __syncthreads();
    if (tid < 32) rl[tid] = (base + tid < n) ? lst[base + tid] : -1;
    __syncthreads();
    #pragma unroll
    for (int j = 0; j < 16; ++j) {
      int t = tid + j * 256;
      int row = t >> 7, off = t & 127;
      int r = rl[row];
      float4 v = make_float4(0.f, 0.f, 0.f, 0.f);
      if (r >= 0)
        v = (off < 64) ? *(const float4*)(zg + (size_t)r * DD + off * 4)
                       : *(const float4*)(zn + (size_t)r * DD + (off - 64) * 4);
      ushort4 pk; pk.x = f2bf(v.x); pk.y = f2bf(v.y); pk.z = f2bf(v.z); pk.w = f2bf(v.w);
      *(ushort4*)(X + row * 520 + off * 4) = pk;
    }
    __syncthreads();
    f32x4 acc[2][4] = {};
    mfma_gemm<16, 2>(X, 520, Was, wave, lane, acc);
    #pragma unroll
    for (int i = 0; i < 4; ++i) {
      int c = (wave * 4 + i) * 16 + m;
      float bb = ba[c];
      #pragma unroll
      for (int rb = 0; rb < 2; ++rb)
        #pragma unroll
        for (int r = 0; r < 4; ++r) {
          int vr = rb * 16 + q * 4 + r;
          float al = 1.f / (1.f + __expf(-(acc[rb][i][r] + bb)));
          float xg = bf2f(X[vr * 520 + c]);
          float xn = bf2f(X[vr * 520 + 256 + c]);
          H[vr * 264 + c] = f2bf(al * xg + (1.f - al) * xn);
        }
    }
    __syncthreads();
    f32x4 acc2[2][4] = {};
    mfma_gemm<8, 2>(H, 264, Wos, wave, lane, acc2);
    #pragma unroll
    for (int i = 0; i < 4; ++i) {
      int c = (wave * 4 + i) * 16 + m;
      float bb = bo[c];
      #pragma unroll
      for (int rb = 0; rb < 2; ++rb)
        #pragma unroll
        for (int r = 0; r < 4; ++r) {
          int row = rl[rb * 16 + q * 4 + r];
          if (row >= 0) out[(size_t)row * DD + c] = (acc2[rb][i][r] + bb) * scale;
        }
    }
  }
}

// ============================================================
// Expert 2, stage A: 32-row tiles (64 vrows), RB=4, pipelined gemm.
// Q, K, V ALL in registers: thread (q,m) holds Q[row rb*16+q*4+r]
// and K[same rows] for its own wave's head cols — the score's Q and
// K values coexist in-lane, so QK^T needs no LDS at all.
// LDS = X only (33.9 KB) -> 4 blocks/CU. 3 barriers/tile.
// ============================================================
__global__ __launch_bounds__(256) void k_attn(
    const float* __restrict__ zg, const float* __restrict__ zn,
    const u16* __restrict__ Wqs, const float* __restrict__ bq,
    const u16* __restrict__ Wks, const float* __restrict__ bk,
    const u16* __restrict__ Wvs, const float* __restrict__ bv,
    const int* __restrict__ listpos, const int* __restrict__ lists,
    float* __restrict__ out) {
  __shared__ u16 X[64 * 264];
  __shared__ int rl[32];
  int n = listpos[2];
  const int* lst = lists + 2 * (size_t)BN;
  int tid = threadIdx.x, lane = tid & 63, wave = tid >> 6;
  int q = lane >> 4, m = lane & 15;

  float bqv[4], bkv[4], bvv[4];
  #pragma unroll
  for (int i = 0; i < 4; ++i) {
    int c = wave * 64 + i * 16 + m;
    bqv[i] = bq[c]; bkv[i] = bk[c]; bvv[i] = bv[c];
  }

  for (int tile = blockIdx.x; tile * 32 < n; tile += gridDim.x) {
    int base = tile * 32;
    __syncthreads();   // previous iteration's X readers done
    if (tid < 32) rl[tid] = (base + tid < n) ? lst[base + tid] : -1;
    __syncthreads();
    // stage X: vrow v = 2r+pos; pos0 = zg, pos1 = zn
    #pragma unroll
    for (int j = 0; j < 16; ++j) {
      int t = tid + j * 256;
      int v = t >> 6, off = t & 63;
      int r = rl[v >> 1];
      float4 val = make_float4(0.f, 0.f, 0.f, 0.f);
      if (r >= 0)
        val = (v & 1) ? *(const float4*)(zn + (size_t)r * DD + off * 4)
                      : *(const float4*)(zg + (size_t)r * DD + off * 4);
      ushort4 pk; pk.x = f2bf(val.x); pk.y = f2bf(val.y); pk.z = f2bf(val.z); pk.w = f2bf(val.w);
      *(ushort4*)(X + v * 264 + off * 4) = pk;
    }
    __syncthreads();
    // ---- Q pass -> regs ----
    f32x4 qa[4][4] = {};
    mfma_gemm_p<8, 4>(X, 264, Wqs, wave, lane, qa);
    #pragma unroll
    for (int rb = 0; rb < 4; ++rb)
      #pragma unroll
      for (int i = 0; i < 4; ++i)
        #pragma unroll
        for (int r = 0; r < 4; ++r) qa[rb][i][r] += bqv[i];
    // ---- K pass -> regs ----
    f32x4 ka[4][4] = {};
    mfma_gemm_p<8, 4>(X, 264, Wks, wave, lane, ka);
    #pragma unroll
    for (int rb = 0; rb < 4; ++rb)
      #pragma unroll
      for (int i = 0; i < 4; ++i)
        #pragma unroll
        for (int r = 0; r < 4; ++r) ka[rb][i][r] += bkv[i];
    // ---- scores + coeffs fully in-register ----
    float C0[4][2], C1[4][2];
    #pragma unroll
    for (int rb = 0; rb < 4; ++rb) {
      #pragma unroll
      for (int pr = 0; pr < 2; ++pr) {
        float p00 = 0.f, p01 = 0.f, p10 = 0.f, p11 = 0.f;  // p[qp][kp]
        #pragma unroll
        for (int i = 0; i < 4; ++i) {
          float q0 = qa[rb][i][2 * pr], q1 = qa[rb][i][2 * pr + 1];
          float ke = ka[rb][i][2 * pr], ko = ka[rb][i][2 * pr + 1];
          p00 += q0 * ke; p01 += q0 * ko;
          p10 += q1 * ke; p11 += q1 * ko;
        }
        #pragma unroll
        for (int msk = 1; msk < 16; msk <<= 1) {
          p00 += __shfl_xor(p00, msk);
          p01 += __shfl_xor(p01, msk);
          p10 += __shfl_xor(p10, msk);
          p11 += __shfl_xor(p11, msk);
        }
        float s00 = 1.f / (1.f + __expf((p01 - p00) * 0.125f));
        float s10 = 1.f / (1.f + __expf((p11 - p10) * 0.125f));
        float c0 = 0.5f * (s00 + s10);
        C0[rb][pr] = c0; C1[rb][pr] = 1.f - c0;
      }
    }
    // ---- V pass -> regs; M = c0*v_e + c1*v_o + bv -> out (f32 ws) ----
    f32x4 va[4][4] = {};
    mfma_gemm_p<8, 4>(X, 264, Wvs, wave, lane, va);
    #pragma unroll
    for (int rb = 0; rb < 4; ++rb)
      #pragma unroll
      for (int pr = 0; pr < 2; ++pr) {
        int rloc = rb * 8 + q * 2 + pr;
        int grow = rl[rloc];
        if (grow >= 0) {
          #pragma unroll
          for (int i = 0; i < 4; ++i) {
            float mv = C0[rb][pr] * va[rb][i][2 * pr]
                     + C1[rb][pr] * va[rb][i][2 * pr + 1] + bvv[i];
            out[(size_t)grow * DD + wave * 64 + i * 16 + m] = mv;
          }
        }
      }
  }
}

// ============================================================
// Expert 2, stage B: M @ Wcomb + bcomb -> out.
// ============================================================
__global__ __launch_bounds__(256) void k_attn_fc(
    const u16* __restrict__ Wcs, const float* __restrict__ bc,
    const int* __restrict__ listpos, const int* __restrict__ lists,
    const float* __restrict__ avgp, float* __restrict__ out) {
  __shared__ u16 Mb[32 * 264];
  __shared__ int rl[32];
  int n = listpos[2];
  const int* lst = lists + 2 * (size_t)BN;
  float scale = avgp[2];
  int tid = threadIdx.x, lane = tid & 63, wave = tid >> 6;
  int q = lane >> 4, m = lane & 15;

  for (int tile = blockIdx.x; tile * 32 < n; tile += gridDim.x) {
    int base = tile * 32;
    __syncthreads();
    if (tid < 32) rl[tid] = (base + tid < n) ? lst[base + tid] : -1;
    __syncthreads();
    #pragma unroll
    for (int j = 0; j < 8; ++j) {
      int t = tid + j * 256;
      int row = t >> 6, off = t & 63;
      int r = rl[row];
      float4 v = make_float4(0.f, 0.f, 0.f, 0.f);
      if (r >= 0) v = *(const float4*)(out + (size_t)r * DD + off * 4);
      ushort4 pk; pk.x = f2bf(v.x); pk.y = f2bf(v.y); pk.z = f2bf(v.z); pk.w = f2bf(v.w);
      *(ushort4*)(Mb + row * 264 + off * 4) = pk;
    }
    __syncthreads();
    f32x4 acc[2][4] = {};
    mfma_gemm<8, 2>(Mb, 264, Wcs, wave, lane, acc);
    #pragma unroll
    for (int i = 0; i < 4; ++i) {
      int c = (wave * 4 + i) * 16 + m;
      float bb = bc[c];
      #pragma unroll
      for (int rb = 0; rb < 2; ++rb)
        #pragma unroll
        for (int r = 0; r < 4; ++r) {
          int row = rl[rb * 16 + q * 4 + r];
          if (row >= 0) out[(size_t)row * DD + c] = (acc[rb][i][r] + bb) * scale;
        }
    }
  }
}

// ============================================================
// launch
// ============================================================
extern "C" void kernel_launch(void* const* d_in, const int* in_sizes, int n_in,
                              void* d_out, int out_size, void* d_ws, size_t ws_size,
                              hipStream_t stream) {
  const float* zg   = (const float*)d_in[0];
  const float* zn   = (const float*)d_in[1];
  const float* gW   = (const float*)d_in[2];
  const float* gb   = (const float*)d_in[3];
  const float* cW1  = (const float*)d_in[4];
  const float* cb1  = (const float*)d_in[5];
  const float* cW2  = (const float*)d_in[6];
  const float* cb2  = (const float*)d_in[7];
  const float* mW1  = (const float*)d_in[8];
  const float* mb1  = (const float*)d_in[9];
  const float* mW2  = (const float*)d_in[10];
  const float* mb2  = (const float*)d_in[11];
  const float* aWq  = (const float*)d_in[12];
  const float* abq  = (const float*)d_in[13];
  const float* aWk  = (const float*)d_in[14];
  const float* abk  = (const float*)d_in[15];
  const float* aWv  = (const float*)d_in[16];
  const float* abv  = (const float*)d_in[17];
  const float* aWo  = (const float*)d_in[18];
  const float* abo  = (const float*)d_in[19];
  const float* aWfc = (const float*)d_in[20];
  const float* abfc = (const float*)d_in[21];
  const float* wWa  = (const float*)d_in[22];
  const float* wba  = (const float*)d_in[23];
  const float* wWo  = (const float*)d_in[24];
  const float* wbo  = (const float*)d_in[25];
  float* out = (float*)d_out;

  char* ws = (char*)d_ws;
  double* psum  = (double*)ws;
  int* listpos  = (int*)(ws + 32);
  float* avg    = (float*)(ws + 48);
  int* lists    = (int*)(ws + 64);
  u16* wsw      = (u16*)(ws + WS_SWZ_OFF);
  float* wcf32  = (float*)(ws + 64);          // transient: overlaps lists[0]
  float* bcomb  = (float*)(ws + BCOMB_OFF);   // persistent

  SwzArgs sa;
  const float* srcs[10] = {cW1, cW2, mW1, mW2, aWq, aWk, aWv, wcf32, wWa, wWo};
  const int   kss[10]  = {16, 8, 8, 8, 8, 8, 8, 8, 16, 8};
  const int   offs[10] = {OFF_CW1, OFF_CW2, OFF_MW1, OFF_MW2, OFF_AWQ, OFF_AWK,
                          OFF_AWV, OFF_WCB, OFF_WWA, OFF_WWO};
  int gb_acc = 0;
  for (int i = 0; i < 10; ++i) {
    sa.src[i] = srcs[i];
    sa.KS[i] = kss[i];
    sa.lks[i] = (kss[i] == 16) ? 4 : 3;
    sa.dstoff[i] = offs[i];
    sa.gbase[i] = gb_acc;
    gb_acc += kss[i] * 1024;
  }

  hipLaunchKernelGGL(k_init, dim3(1), dim3(64), 0, stream, listpos, psum);
  hipLaunchKernelGGL(k_wcomb, dim3(257), dim3(256), 0, stream,
                     aWo, abo, aWfc, abfc, wcf32, bcomb);
  hipLaunchKernelGGL(k_swz, dim3(SWZ_TOTAL_GROUPS / 256), dim3(256), 0, stream, sa, wsw);
  hipLaunchKernelGGL(k_gate, dim3(BN / 256), dim3(256), 0, stream,
                     zg, zn, gW, gb, listpos, psum, lists);
  hipLaunchKernelGGL(k_finalize, dim3(1), dim3(64), 0, stream,
                     listpos, psum, avg, out + (size_t)BN * DD);
  hipLaunchKernelGGL(k_concat, dim3(1024), dim3(256), 0, stream,
                     zg, zn, wsw + OFF_CW1, cb1, wsw + OFF_CW2, cb2, listpos, lists, avg, out);
  hipLaunchKernelGGL(k_mul, dim3(512), dim3(256), 0, stream,
                     zg, zn, wsw + OFF_MW1, mb1, wsw + OFF_MW2, mb2, listpos, lists, avg, out);
  hipLaunchKernelGGL(k_attn, dim3(1024), dim3(256), 0, stream,
                     zg, zn, wsw + OFF_AWQ, abq, wsw + OFF_AWK, abk, wsw + OFF_AWV, abv,
                     listpos, lists, out);
  hipLaunchKernelGGL(k_attn_fc, dim3(1024), dim3(256), 0, stream,
                     wsw + OFF_WCB, bcomb, listpos, lists, avg, out);
  hipLaunchKernelGGL(k_wsum, dim3(1024), dim3(256), 0, stream,
                     zg, zn, wsw + OFF_WWA, wba, wsw + OFF_WWO, wbo, listpos, lists, avg, out);
}

// Round 6
// 614.252 us; speedup vs baseline: 2.4017x; 1.1589x over previous
//
#include <hip/hip_runtime.h>
#include <math.h>

#define BN 131072
#define DD 256
#define NE 4

typedef unsigned short u16;
typedef __bf16 bf16x8 __attribute__((ext_vector_type(8)));
typedef float f32x4 __attribute__((ext_vector_type(4)));

__device__ __forceinline__ u16 f2bf(float f) {
  union { float f; unsigned int u; } v; v.f = f;
  unsigned int u = v.u;
  unsigned int r = (u + 0x7FFFu + ((u >> 16) & 1u)) >> 16;
  return (u16)r;
}
__device__ __forceinline__ float bf2f(u16 x) {
  union { unsigned int u; float f; } v; v.u = ((unsigned int)x) << 16; return v.f;
}

// ---------------- workspace layout (d_ws) ----------------
// [0,32)    double psum[4]
// [32,48)   int    listpos[4]
// [48,64)   float  avg[4]
// [64, 64+4*BN*4)  int lists[4][BN]
//   NOTE: first 256KB of lists[0] is transiently reused as fp32 Wcomb
//   (k_wcomb writes it, k_swz reads it, both BEFORE k_gate writes lists).
// [2097216, +1572864) u16 swizzled bf16 weights (10 matrices)
// [3670080, +1024)    float bcomb[256]  (persists through expert kernels)
#define WS_SWZ_OFF 2097216
#define BCOMB_OFF  3670080

#define OFF_CW1  0
#define OFF_CW2  131072
#define OFF_MW1  196608
#define OFF_MW2  262144
#define OFF_AWQ  327680
#define OFF_AWK  393216
#define OFF_AWV  458752
#define OFF_WCB  524288
#define OFF_WWA  589824
#define OFF_WWO  720896
#define SWZ_TOTAL_GROUPS 98304   // 786432/8

// merged expert kernel grid partition
#define G_ATTN   768
#define G_CONCAT 768
#define G_MUL    768
#define G_WSUM   768
#define G_TOTAL  3072

// ============================================================
// init
// ============================================================
__global__ void k_init(int* __restrict__ listpos, double* __restrict__ psum) {
  int t = threadIdx.x;
  if (t < NE) { listpos[t] = 0; psum[t] = 0.0; }
}

// ============================================================
// Wcomb = Wo @ Wfc (fp32), bcomb = bo @ Wfc + bfc
// ============================================================
__global__ __launch_bounds__(256) void k_wcomb(
    const float* __restrict__ Wo, const float* __restrict__ bo,
    const float* __restrict__ Wfc, const float* __restrict__ bfc,
    float* __restrict__ Wc, float* __restrict__ bc) {
  int n = threadIdx.x;
  int k = blockIdx.x;
  if (k < 256) {
    float acc = 0.f;
    #pragma unroll 8
    for (int j = 0; j < 256; ++j) acc += Wo[k * 256 + j] * Wfc[j * 256 + n];
    Wc[k * 256 + n] = acc;
  } else {
    float acc = bfc[n];
    #pragma unroll 8
    for (int j = 0; j < 256; ++j) acc += bo[j] * Wfc[j * 256 + n];
    bc[n] = acc;
  }
}

// ============================================================
// weight swizzle: fp32 W[K x 256] -> bf16 in B-fragment order
// ============================================================
struct SwzArgs {
  const float* src[10];
  int KS[10];
  int lks[10];
  int dstoff[10];
  int gbase[10];
};

__global__ __launch_bounds__(256) void k_swz(SwzArgs a, u16* __restrict__ dst) {
  int g = blockIdx.x * 256 + threadIdx.x;
  if (g >= SWZ_TOTAL_GROUPS) return;
  int i = 0;
  #pragma unroll
  for (int t = 1; t < 10; ++t) if (g >= a.gbase[t]) i = t;
  int gl = g - a.gbase[i];
  int KS = a.KS[i], lks = a.lks[i];
  int l = gl & 63, t2 = gl >> 6;
  int ks = t2 & (KS - 1), ct = t2 >> lks;
  const float* src = a.src[i] + (size_t)(ks * 32 + ((l >> 4) << 3)) * 256 + ct * 16 + (l & 15);
  u16 tmp[8];
  #pragma unroll
  for (int j = 0; j < 8; ++j) tmp[j] = f2bf(src[(size_t)j * 256]);
  uint4 pk;
  pk.x = (unsigned)tmp[0] | ((unsigned)tmp[1] << 16);
  pk.y = (unsigned)tmp[2] | ((unsigned)tmp[3] << 16);
  pk.z = (unsigned)tmp[4] | ((unsigned)tmp[5] << 16);
  pk.w = (unsigned)tmp[6] | ((unsigned)tmp[7] << 16);
  *(uint4*)(dst + a.dstoff[i] + (size_t)gl * 8) = pk;
}

// ============================================================
// gating: fp64, 128 rows/block (grid 1024, ~37KB LDS -> 4 blk/CU),
// 2 half-K workers per row, register double-buffer, block atomics.
// ============================================================
__global__ __launch_bounds__(256) void k_gate(
    const float* __restrict__ zg, const float* __restrict__ zn,
    const float* __restrict__ gW, const float* __restrict__ gb,
    int* __restrict__ listpos, double* __restrict__ psum,
    int* __restrict__ lists) {
  __shared__ float xs[32 * 129];
  __shared__ double gwd[512 * 4];
  __shared__ double xr[128 * 4];
  __shared__ int    wcnt[4][4];
  __shared__ double wps[4][4];
  __shared__ int    wbase[4][4];
  int tid = threadIdx.x, lane = tid & 63, wave = tid >> 6;
  int rlocal = tid & 127, khalf = tid >> 7;
  int rowbase = blockIdx.x * 128;
  for (int i = tid; i < 2048; i += 256) gwd[i] = (double)gW[i];
  double l0, l1, l2, l3;
  if (khalf) { l0 = l1 = l2 = l3 = 0.0; }
  else { l0 = (double)gb[0]; l1 = (double)gb[1]; l2 = (double)gb[2]; l3 = (double)gb[3]; }

  float4 pf[4];
  #pragma unroll
  for (int j = 0; j < 4; ++j) {
    int idx = tid + j * 256;
    int row = idx >> 3, off = idx & 7;
    pf[j] = *(const float4*)(zg + (size_t)(rowbase + row) * DD + off * 4);
  }

  for (int c = 0; c < 16; ++c) {
    __syncthreads();
    #pragma unroll
    for (int j = 0; j < 4; ++j) {
      int idx = tid + j * 256;
      int row = idx >> 3, off = idx & 7;
      float4 v = pf[j];
      xs[(off * 4 + 0) * 129 + row] = v.x;
      xs[(off * 4 + 1) * 129 + row] = v.y;
      xs[(off * 4 + 2) * 129 + row] = v.z;
      xs[(off * 4 + 3) * 129 + row] = v.w;
    }
    if (c < 15) {
      const float* src = (c + 1 < 8) ? zg : zn;
      int ko = ((c + 1) & 7) * 32;
      #pragma unroll
      for (int j = 0; j < 4; ++j) {
        int idx = tid + j * 256;
        int row = idx >> 3, off = idx & 7;
        pf[j] = *(const float4*)(src + (size_t)(rowbase + row) * DD + ko + off * 4);
      }
    }
    __syncthreads();
    const double* gp = gwd + (size_t)(c * 32 + khalf * 16) * 4;
    int xbase = (khalf * 16) * 129 + rlocal;
    #pragma unroll
    for (int i = 0; i < 16; ++i) {
      double x = (double)xs[xbase + i * 129];
      l0 = fma(x, gp[i * 4 + 0], l0);
      l1 = fma(x, gp[i * 4 + 1], l1);
      l2 = fma(x, gp[i * 4 + 2], l2);
      l3 = fma(x, gp[i * 4 + 3], l3);
    }
  }

  // cross-half reduce
  __syncthreads();
  if (khalf) {
    xr[rlocal * 4 + 0] = l0; xr[rlocal * 4 + 1] = l1;
    xr[rlocal * 4 + 2] = l2; xr[rlocal * 4 + 3] = l3;
  }
  __syncthreads();
  int e = -1;
  double p = 0.0;
  if (!khalf) {
    l0 += xr[rlocal * 4 + 0]; l1 += xr[rlocal * 4 + 1];
    l2 += xr[rlocal * 4 + 2]; l3 += xr[rlocal * 4 + 3];
    e = 0; double lm = l0;
    if (l1 > lm) { lm = l1; e = 1; }
    if (l2 > lm) { lm = l2; e = 2; }
    if (l3 > lm) { lm = l3; e = 3; }
    double s = exp(l0 - lm) + exp(l1 - lm) + exp(l2 - lm) + exp(l3 - lm);
    p = 1.0 / s;
  }
  int row = rowbase + rlocal;

  unsigned long long msk[4];
  int cnt[4];
  double pvs[4];
  #pragma unroll
  for (int ee = 0; ee < NE; ++ee) {
    bool mine = (e == ee);
    msk[ee] = __ballot(mine);
    cnt[ee] = __popcll(msk[ee]);
    double pv = mine ? p : 0.0;
    #pragma unroll
    for (int off = 32; off; off >>= 1) pv += __shfl_down(pv, off);
    pvs[ee] = pv;
  }
  if (lane == 0) {
    #pragma unroll
    for (int ee = 0; ee < NE; ++ee) { wcnt[wave][ee] = cnt[ee]; wps[wave][ee] = pvs[ee]; }
  }
  __syncthreads();
  if (tid < NE) {
    int ee = tid;
    int c0 = wcnt[0][ee], c1 = wcnt[1][ee], c2 = wcnt[2][ee], c3 = wcnt[3][ee];
    int tot = c0 + c1 + c2 + c3;
    int base = 0;
    if (tot) {
      base = atomicAdd(&listpos[ee], tot);
      atomicAdd(&psum[ee], wps[0][ee] + wps[1][ee] + wps[2][ee] + wps[3][ee]);
    }
    wbase[0][ee] = base;
    wbase[1][ee] = base + c0;
    wbase[2][ee] = base + c0 + c1;
    wbase[3][ee] = base + c0 + c1 + c2;
  }
  __syncthreads();
  #pragma unroll
  for (int ee = 0; ee < NE; ++ee) {
    if (e == ee) {
      int rank = __popcll(msk[ee] & ((1ull << lane) - 1ull));
      lists[(size_t)ee * BN + wbase[wave][ee] + rank] = row;
    }
  }
}

__global__ void k_finalize(const int* __restrict__ listpos,
                           const double* __restrict__ psum,
                           float* __restrict__ avg, float* __restrict__ aux_out) {
  if (threadIdx.x == 0) {
    double aux = 0.0;
    for (int ee = 0; ee < NE; ++ee) {
      int c = listpos[ee];
      avg[ee] = (c > 0) ? (float)(psum[ee] / (double)c) : 0.0f;
      double u = (double)c / (double)BN;
      aux += u * u;
    }
    *aux_out = (float)(aux * (double)NE);
  }
}

// ============================================================
// MFMA tile core: #pragma unroll 1 + 2-deep B double-buffer
// (caps live B regs at 32 -> no scratch spills).
// ============================================================
template <int KS, int RB>
__device__ __forceinline__ void mfma_gemm_p(const u16* __restrict__ A, int strideA,
                                            const u16* __restrict__ W,
                                            int wave, int lane, f32x4 acc[RB][4]) {
  int q = lane >> 4, m = lane & 15;
  const u16* wb = W + (((size_t)(wave * 4 * KS) * 64 + lane) << 3);
  bf16x8 b0[4], b1[4];
  #pragma unroll
  for (int i = 0; i < 4; ++i)
    b0[i] = *(const bf16x8*)(wb + (((size_t)(i * KS) * 64) << 3));
  #pragma unroll 1
  for (int ks = 0; ks < KS; ks += 2) {
    #pragma unroll
    for (int i = 0; i < 4; ++i)
      b1[i] = *(const bf16x8*)(wb + (((size_t)(i * KS + ks + 1) * 64) << 3));
    bf16x8 a[RB];
    #pragma unroll
    for (int rb = 0; rb < RB; ++rb)
      a[rb] = *(const bf16x8*)(A + (rb * 16 + m) * strideA + ks * 32 + (q << 3));
    #pragma unroll
    for (int i = 0; i < 4; ++i)
      #pragma unroll
      for (int rb = 0; rb < RB; ++rb)
        acc[rb][i] = __builtin_amdgcn_mfma_f32_16x16x32_bf16(a[rb], b0[i], acc[rb][i], 0, 0, 0);
    if (ks + 2 < KS) {
      #pragma unroll
      for (int i = 0; i < 4; ++i)
        b0[i] = *(const bf16x8*)(wb + (((size_t)(i * KS + ks + 2) * 64) << 3));
    }
    #pragma unroll
    for (int rb = 0; rb < RB; ++rb)
      a[rb] = *(const bf16x8*)(A + (rb * 16 + m) * strideA + (ks + 1) * 32 + (q << 3));
    #pragma unroll
    for (int i = 0; i < 4; ++i)
      #pragma unroll
      for (int rb = 0; rb < RB; ++rb)
        acc[rb][i] = __builtin_amdgcn_mfma_f32_16x16x32_bf16(a[rb], b1[i], acc[rb][i], 0, 0, 0);
  }
}

// ============================================================
// Merged expert kernel: blockIdx-range dispatch.
//   [0,768)      attn  (16-row tiles, fc fused in-block)
//   [768,1536)   concat (32-row tiles)
//   [1536,2304)  mul    (32-row tiles)
//   [2304,3072)  wsum   (32-row tiles)
// Shared carve: max 25088 u16 = 50.2 KB -> 3 blocks/CU.
// ============================================================
struct ExpArgs {
  const float* zg; const float* zn;
  const u16* CW1; const u16* CW2; const float* cb1; const float* cb2;
  const u16* MW1; const u16* MW2; const float* mb1; const float* mb2;
  const u16* AWQ; const u16* AWK; const u16* AWV;
  const float* abq; const float* abk; const float* abv;
  const u16* WCB; const float* bcomb;
  const u16* WWA; const u16* WWO; const float* wba; const float* wbo;
  const int* listpos; const int* lists; const float* avgp;
  float* out;
};

__global__ __launch_bounds__(256) void k_experts(ExpArgs A) {
  __shared__ __align__(16) u16 smem[25088];
  __shared__ int rl[32];
  int tid = threadIdx.x, lane = tid & 63, wave = tid >> 6;
  int q = lane >> 4, m = lane & 15;
  int bid = blockIdx.x;

  if (bid < G_ATTN) {
    // ---------------- attention (fc fused) ----------------
    int bidl = bid;
    int n = A.listpos[2];
    const int* lst = A.lists + 2 * (size_t)BN;
    float scale = A.avgp[2];
    u16* X  = smem;           // 32 vrows x 264
    u16* Mb = smem + 8448;    // 16 rows  x 264
    float bqv[4], bkv[4], bvv[4];
    #pragma unroll
    for (int i = 0; i < 4; ++i) {
      int c = wave * 64 + i * 16 + m;
      bqv[i] = A.abq[c]; bkv[i] = A.abk[c]; bvv[i] = A.abv[c];
    }
    for (int tile = bidl; tile * 16 < n; tile += G_ATTN) {
      int base = tile * 16;
      __syncthreads();
      if (tid < 16) rl[tid] = (base + tid < n) ? lst[base + tid] : -1;
      __syncthreads();
      #pragma unroll
      for (int j = 0; j < 8; ++j) {
        int t = tid + j * 256;
        int v = t >> 6, off = t & 63;
        int r = rl[v >> 1];
        float4 val = make_float4(0.f, 0.f, 0.f, 0.f);
        if (r >= 0)
          val = (v & 1) ? *(const float4*)(A.zn + (size_t)r * DD + off * 4)
                        : *(const float4*)(A.zg + (size_t)r * DD + off * 4);
        ushort4 pk; pk.x = f2bf(val.x); pk.y = f2bf(val.y); pk.z = f2bf(val.z); pk.w = f2bf(val.w);
        *(ushort4*)(X + v * 264 + off * 4) = pk;
      }
      __syncthreads();
      f32x4 qa[2][4] = {};
      mfma_gemm_p<8, 2>(X, 264, A.AWQ, wave, lane, qa);
      #pragma unroll
      for (int rb = 0; rb < 2; ++rb)
        #pragma unroll
        for (int i = 0; i < 4; ++i)
          #pragma unroll
          for (int r = 0; r < 4; ++r) qa[rb][i][r] += bqv[i];
      f32x4 ka[2][4] = {};
      mfma_gemm_p<8, 2>(X, 264, A.AWK, wave, lane, ka);
      #pragma unroll
      for (int rb = 0; rb < 2; ++rb)
        #pragma unroll
        for (int i = 0; i < 4; ++i)
          #pragma unroll
          for (int r = 0; r < 4; ++r) ka[rb][i][r] += bkv[i];
      float C0[2][2], C1[2][2];
      #pragma unroll
      for (int rb = 0; rb < 2; ++rb) {
        #pragma unroll
        for (int pr = 0; pr < 2; ++pr) {
          float p00 = 0.f, p01 = 0.f, p10 = 0.f, p11 = 0.f;
          #pragma unroll
          for (int i = 0; i < 4; ++i) {
            float q0 = qa[rb][i][2 * pr], q1 = qa[rb][i][2 * pr + 1];
            float ke = ka[rb][i][2 * pr], ko = ka[rb][i][2 * pr + 1];
            p00 += q0 * ke; p01 += q0 * ko;
            p10 += q1 * ke; p11 += q1 * ko;
          }
          #pragma unroll
          for (int msk = 1; msk < 16; msk <<= 1) {
            p00 += __shfl_xor(p00, msk);
            p01 += __shfl_xor(p01, msk);
            p10 += __shfl_xor(p10, msk);
            p11 += __shfl_xor(p11, msk);
          }
          float s00 = 1.f / (1.f + __expf((p01 - p00) * 0.125f));
          float s10 = 1.f / (1.f + __expf((p11 - p10) * 0.125f));
          float c0 = 0.5f * (s00 + s10);
          C0[rb][pr] = c0; C1[rb][pr] = 1.f - c0;
        }
      }
      f32x4 va[2][4] = {};
      mfma_gemm_p<8, 2>(X, 264, A.AWV, wave, lane, va);
      #pragma unroll
      for (int rb = 0; rb < 2; ++rb)
        #pragma unroll
        for (int pr = 0; pr < 2; ++pr) {
          int rloc = rb * 8 + q * 2 + pr;
          #pragma unroll
          for (int i = 0; i < 4; ++i) {
            float mv = C0[rb][pr] * va[rb][i][2 * pr]
                     + C1[rb][pr] * va[rb][i][2 * pr + 1] + bvv[i];
            Mb[rloc * 264 + wave * 64 + i * 16 + m] = f2bf(mv);
          }
        }
      __syncthreads();
      f32x4 ac[1][4] = {};
      mfma_gemm_p<8, 1>(Mb, 264, A.WCB, wave, lane, ac);
      #pragma unroll
      for (int i = 0; i < 4; ++i) {
        int c = (wave * 4 + i) * 16 + m;
        float bb = A.bcomb[c];
        #pragma unroll
        for (int r = 0; r < 4; ++r) {
          int row = rl[q * 4 + r];
          if (row >= 0) A.out[(size_t)row * DD + c] = (ac[0][i][r] + bb) * scale;
        }
      }
    }
  } else if (bid < G_ATTN + G_CONCAT) {
    // ---------------- concat ----------------
    int bidl = bid - G_ATTN;
    int n = A.listpos[0];
    const int* lst = A.lists + 0 * (size_t)BN;
    float scale = A.avgp[0];
    u16* X = smem;            // 32 x 520
    u16* H = smem + 16640;    // 32 x 264
    for (int tile = bidl; tile * 32 < n; tile += G_CONCAT) {
      int base = tile * 32;
      __syncthreads();
      if (tid < 32) rl[tid] = (base + tid < n) ? lst[base + tid] : -1;
      __syncthreads();
      #pragma unroll
      for (int j = 0; j < 16; ++j) {
        int t = tid + j * 256;
        int row = t >> 7, off = t & 127;
        int r = rl[row];
        float4 v = make_float4(0.f, 0.f, 0.f, 0.f);
        if (r >= 0)
          v = (off < 64) ? *(const float4*)(A.zg + (size_t)r * DD + off * 4)
                         : *(const float4*)(A.zn + (size_t)r * DD + (off - 64) * 4);
        ushort4 pk; pk.x = f2bf(v.x); pk.y = f2bf(v.y); pk.z = f2bf(v.z); pk.w = f2bf(v.w);
        *(ushort4*)(X + row * 520 + off * 4) = pk;
      }
      __syncthreads();
      f32x4 acc[2][4] = {};
      mfma_gemm_p<16, 2>(X, 520, A.CW1, wave, lane, acc);
      #pragma unroll
      for (int i = 0; i < 4; ++i) {
        int c = (wave * 4 + i) * 16 + m;
        float bb = A.cb1[c];
        #pragma unroll
        for (int rb = 0; rb < 2; ++rb)
          #pragma unroll
          for (int r = 0; r < 4; ++r)
            H[(rb * 16 + q * 4 + r) * 264 + c] = f2bf(fmaxf(acc[rb][i][r] + bb, 0.f));
      }
      __syncthreads();
      f32x4 acc2[2][4] = {};
      mfma_gemm_p<8, 2>(H, 264, A.CW2, wave, lane, acc2);
      #pragma unroll
      for (int i = 0; i < 4; ++i) {
        int c = (wave * 4 + i) * 16 + m;
        float bb = A.cb2[c];
        #pragma unroll
        for (int rb = 0; rb < 2; ++rb)
          #pragma unroll
          for (int r = 0; r < 4; ++r) {
            int row = rl[rb * 16 + q * 4 + r];
            if (row >= 0) A.out[(size_t)row * DD + c] = (acc2[rb][i][r] + bb) * scale;
          }
      }
    }
  } else if (bid < G_ATTN + G_CONCAT + G_MUL) {
    // ---------------- mul ----------------
    int bidl = bid - (G_ATTN + G_CONCAT);
    int n = A.listpos[1];
    const int* lst = A.lists + 1 * (size_t)BN;
    float scale = A.avgp[1];
    u16* X = smem;            // 32 x 264
    u16* H = smem + 8448;     // 32 x 264
    for (int tile = bidl; tile * 32 < n; tile += G_MUL) {
      int base = tile * 32;
      __syncthreads();
      if (tid < 32) rl[tid] = (base + tid < n) ? lst[base + tid] : -1;
      __syncthreads();
      #pragma unroll
      for (int j = 0; j < 8; ++j) {
        int t = tid + j * 256;
        int row = t >> 6, off = t & 63;
        int r = rl[row];
        float4 v = make_float4(0.f, 0.f, 0.f, 0.f);
        if (r >= 0) {
          float4 g = *(const float4*)(A.zg + (size_t)r * DD + off * 4);
          float4 h = *(const float4*)(A.zn + (size_t)r * DD + off * 4);
          v = make_float4(g.x * h.x, g.y * h.y, g.z * h.z, g.w * h.w);
        }
        ushort4 pk; pk.x = f2bf(v.x); pk.y = f2bf(v.y); pk.z = f2bf(v.z); pk.w = f2bf(v.w);
        *(ushort4*)(X + row * 264 + off * 4) = pk;
      }
      __syncthreads();
      f32x4 acc[2][4] = {};
      mfma_gemm_p<8, 2>(X, 264, A.MW1, wave, lane, acc);
      #pragma unroll
      for (int i = 0; i < 4; ++i) {
        int c = (wave * 4 + i) * 16 + m;
        float bb = A.mb1[c];
        #pragma unroll
        for (int rb = 0; rb < 2; ++rb)
          #pragma unroll
          for (int r = 0; r < 4; ++r)
            H[(rb * 16 + q * 4 + r) * 264 + c] = f2bf(fmaxf(acc[rb][i][r] + bb, 0.f));
      }
      __syncthreads();
      f32x4 acc2[2][4] = {};
      mfma_gemm_p<8, 2>(H, 264, A.MW2, wave, lane, acc2);
      #pragma unroll
      for (int i = 0; i < 4; ++i) {
        int c = (wave * 4 + i) * 16 + m;
        float bb = A.mb2[c];
        #pragma unroll
        for (int rb = 0; rb < 2; ++rb)
          #pragma unroll
          for (int r = 0; r < 4; ++r) {
            int row = rl[rb * 16 + q * 4 + r];
            if (row >= 0) A.out[(size_t)row * DD + c] = (acc2[rb][i][r] + bb) * scale;
          }
      }
    }
  } else {
    // ---------------- wsum ----------------
    int bidl = bid - (G_ATTN + G_CONCAT + G_MUL);
    int n = A.listpos[3];
    const int* lst = A.lists + 3 * (size_t)BN;
    float scale = A.avgp[3];
    u16* X = smem;            // 32 x 520
    u16* H = smem + 16640;    // 32 x 264
    for (int tile = bidl; tile * 32 < n; tile += G_WSUM) {
      int base = tile * 32;
      __syncthreads();
      if (tid < 32) rl[tid] = (base + tid < n) ? lst[base + tid] : -1;
      __syncthreads();
      #pragma unroll
      for (int j = 0; j < 16; ++j) {
        int t = tid + j * 256;
        int row = t >> 7, off = t & 127;
        int r = rl[row];
        float4 v = make_float4(0.f, 0.f, 0.f, 0.f);
        if (r >= 0)
          v = (off < 64) ? *(const float4*)(A.zg + (size_t)r * DD + off * 4)
                         : *(const float4*)(A.zn + (size_t)r * DD + (off - 64) * 4);
        ushort4 pk; pk.x = f2bf(v.x); pk.y = f2bf(v.y); pk.z = f2bf(v.z); pk.w = f2bf(v.w);
        *(ushort4*)(X + row * 520 + off * 4) = pk;
      }
      __syncthreads();
      f32x4 acc[2][4] = {};
      mfma_gemm_p<16, 2>(X, 520, A.WWA, wave, lane, acc);
      #pragma unroll
      for (int i = 0; i < 4; ++i) {
        int c = (wave * 4 + i) * 16 + m;
        float bb = A.wba[c];
        #pragma unroll
        for (int rb = 0; rb < 2; ++rb)
          #pragma unroll
          for (int r = 0; r < 4; ++r) {
            int vr = rb * 16 + q * 4 + r;
            float al = 1.f / (1.f + __expf(-(acc[rb][i][r] + bb)));
            float xg = bf2f(X[vr * 520 + c]);
            float xn = bf2f(X[vr * 520 + 256 + c]);
            H[vr * 264 + c] = f2bf(al * xg + (1.f - al) * xn);
          }
      }
      __syncthreads();
      f32x4 acc2[2][4] = {};
      mfma_gemm_p<8, 2>(H, 264, A.WWO, wave, lane, acc2);
      #pragma unroll
      for (int i = 0; i < 4; ++i) {
        int c = (wave * 4 + i) * 16 + m;
        float bb = A.wbo[c];
        #pragma unroll
        for (int rb = 0; rb < 2; ++rb)
          #pragma unroll
          for (int r = 0; r < 4; ++r) {
            int row = rl[rb * 16 + q * 4 + r];
            if (row >= 0) A.out[(size_t)row * DD + c] = (acc2[rb][i][r] + bb) * scale;
          }
      }
    }
  }
}

// ============================================================
// launch
// ============================================================
extern "C" void kernel_launch(void* const* d_in, const int* in_sizes, int n_in,
                              void* d_out, int out_size, void* d_ws, size_t ws_size,
                              hipStream_t stream) {
  const float* zg   = (const float*)d_in[0];
  const float* zn   = (const float*)d_in[1];
  const float* gW   = (const float*)d_in[2];
  const float* gb   = (const float*)d_in[3];
  const float* cW1  = (const float*)d_in[4];
  const float* cb1  = (const float*)d_in[5];
  const float* cW2  = (const float*)d_in[6];
  const float* cb2  = (const float*)d_in[7];
  const float* mW1  = (const float*)d_in[8];
  const float* mb1  = (const float*)d_in[9];
  const float* mW2  = (const float*)d_in[10];
  const float* mb2  = (const float*)d_in[11];
  const float* aWq  = (const float*)d_in[12];
  const float* abq  = (const float*)d_in[13];
  const float* aWk  = (const float*)d_in[14];
  const float* abk  = (const float*)d_in[15];
  const float* aWv  = (const float*)d_in[16];
  const float* abv  = (const float*)d_in[17];
  const float* aWo  = (const float*)d_in[18];
  const float* abo  = (const float*)d_in[19];
  const float* aWfc = (const float*)d_in[20];
  const float* abfc = (const float*)d_in[21];
  const float* wWa  = (const float*)d_in[22];
  const float* wba  = (const float*)d_in[23];
  const float* wWo  = (const float*)d_in[24];
  const float* wbo  = (const float*)d_in[25];
  float* out = (float*)d_out;

  char* ws = (char*)d_ws;
  double* psum  = (double*)ws;
  int* listpos  = (int*)(ws + 32);
  float* avg    = (float*)(ws + 48);
  int* lists    = (int*)(ws + 64);
  u16* wsw      = (u16*)(ws + WS_SWZ_OFF);
  float* wcf32  = (float*)(ws + 64);          // transient: overlaps lists[0]
  float* bcomb  = (float*)(ws + BCOMB_OFF);   // persistent

  SwzArgs sa;
  const float* srcs[10] = {cW1, cW2, mW1, mW2, aWq, aWk, aWv, wcf32, wWa, wWo};
  const int   kss[10]  = {16, 8, 8, 8, 8, 8, 8, 8, 16, 8};
  const int   offs[10] = {OFF_CW1, OFF_CW2, OFF_MW1, OFF_MW2, OFF_AWQ, OFF_AWK,
                          OFF_AWV, OFF_WCB, OFF_WWA, OFF_WWO};
  int gb_acc = 0;
  for (int i = 0; i < 10; ++i) {
    sa.src[i] = srcs[i];
    sa.KS[i] = kss[i];
    sa.lks[i] = (kss[i] == 16) ? 4 : 3;
    sa.dstoff[i] = offs[i];
    sa.gbase[i] = gb_acc;
    gb_acc += kss[i] * 1024;
  }

  ExpArgs ea;
  ea.zg = zg; ea.zn = zn;
  ea.CW1 = wsw + OFF_CW1; ea.CW2 = wsw + OFF_CW2; ea.cb1 = cb1; ea.cb2 = cb2;
  ea.MW1 = wsw + OFF_MW1; ea.MW2 = wsw + OFF_MW2; ea.mb1 = mb1; ea.mb2 = mb2;
  ea.AWQ = wsw + OFF_AWQ; ea.AWK = wsw + OFF_AWK; ea.AWV = wsw + OFF_AWV;
  ea.abq = abq; ea.abk = abk; ea.abv = abv;
  ea.WCB = wsw + OFF_WCB; ea.bcomb = bcomb;
  ea.WWA = wsw + OFF_WWA; ea.WWO = wsw + OFF_WWO; ea.wba = wba; ea.wbo = wbo;
  ea.listpos = listpos; ea.lists = lists; ea.avgp = avg;
  ea.out = out;

  hipLaunchKernelGGL(k_init, dim3(1), dim3(64), 0, stream, listpos, psum);
  hipLaunchKernelGGL(k_wcomb, dim3(257), dim3(256), 0, stream,
                     aWo, abo, aWfc, abfc, wcf32, bcomb);
  hipLaunchKernelGGL(k_swz, dim3(SWZ_TOTAL_GROUPS / 256), dim3(256), 0, stream, sa, wsw);
  hipLaunchKernelGGL(k_gate, dim3(BN / 128), dim3(256), 0, stream,
                     zg, zn, gW, gb, listpos, psum, lists);
  hipLaunchKernelGGL(k_finalize, dim3(1), dim3(64), 0, stream,
                     listpos, psum, avg, out + (size_t)BN * DD);
  hipLaunchKernelGGL(k_experts, dim3(G_TOTAL), dim3(256), 0, stream, ea);
}

// Round 7
// 605.546 us; speedup vs baseline: 2.4363x; 1.0144x over previous
//
#include <hip/hip_runtime.h>
#include <math.h>

#define BN 131072
#define DD 256
#define NE 4

typedef unsigned short u16;
typedef __bf16 bf16x8 __attribute__((ext_vector_type(8)));
typedef float f32x4 __attribute__((ext_vector_type(4)));

__device__ __forceinline__ u16 f2bf(float f) {
  union { float f; unsigned int u; } v; v.f = f;
  unsigned int u = v.u;
  unsigned int r = (u + 0x7FFFu + ((u >> 16) & 1u)) >> 16;
  return (u16)r;
}
__device__ __forceinline__ float bf2f(u16 x) {
  union { unsigned int u; float f; } v; v.u = ((unsigned int)x) << 16; return v.f;
}

// ---------------- workspace layout (d_ws) ----------------
// [0,32)    double psum[4]
// [32,48)   int    listpos[4]
// [48,64)   float  avg[4]
// [64, 64+4*BN*4)  int lists[4][BN]
//   NOTE: first 256KB of lists[0] is transiently reused as fp32 Wcomb
//   (k_wcomb writes it, k_swz reads it, both BEFORE k_gate writes lists).
// [2097216, +1572864) u16 swizzled bf16 weights (10 matrices)
// [3670080, +1024)    float bcomb[256]  (persists through expert kernels)
#define WS_SWZ_OFF 2097216
#define BCOMB_OFF  3670080

#define OFF_CW1  0
#define OFF_CW2  131072
#define OFF_MW1  196608
#define OFF_MW2  262144
#define OFF_AWQ  327680
#define OFF_AWK  393216
#define OFF_AWV  458752
#define OFF_WCB  524288
#define OFF_WWA  589824
#define OFF_WWO  720896

// merged expert kernel: interleaved cost-balanced partition (mod 48)
// 48-block group: 22 attn, 10 concat, 6 mul, 10 wsum  (grid 3072 = 64 groups)
#define GRP      48
#define A_END    22
#define C_END    32
#define M_END    38
#define G_ATTN   (64 * 22)
#define G_CONCAT (64 * 10)
#define G_MUL    (64 * 6)
#define G_WSUM   (64 * 10)
#define G_TOTAL  3072

// ============================================================
// init
// ============================================================
__global__ void k_init(int* __restrict__ listpos, double* __restrict__ psum) {
  int t = threadIdx.x;
  if (t < NE) { listpos[t] = 0; psum[t] = 0.0; }
}

// ============================================================
// Wcomb = Wo @ Wfc (fp32), bcomb = bo @ Wfc + bfc
// ============================================================
__global__ __launch_bounds__(256) void k_wcomb(
    const float* __restrict__ Wo, const float* __restrict__ bo,
    const float* __restrict__ Wfc, const float* __restrict__ bfc,
    float* __restrict__ Wc, float* __restrict__ bc) {
  int n = threadIdx.x;
  int k = blockIdx.x;
  if (k < 256) {
    float acc = 0.f;
    #pragma unroll 8
    for (int j = 0; j < 256; ++j) acc += Wo[k * 256 + j] * Wfc[j * 256 + n];
    Wc[k * 256 + n] = acc;
  } else {
    float acc = bfc[n];
    #pragma unroll 8
    for (int j = 0; j < 256; ++j) acc += bo[j] * Wfc[j * 256 + n];
    bc[n] = acc;
  }
}

// ============================================================
// weight swizzle v2: one block per (matrix, ks) slice.
// Coalesced float4 loads of 32x256 fp32 -> LDS (padded) ->
// packed uint4 fragment stores. Grid = 96.
// ============================================================
struct SwzArgs {
  const float* src[10];
  int KS[10];
  int dstoff[10];
  int ksbase[10];
};

__global__ __launch_bounds__(256) void k_swz(SwzArgs a, u16* __restrict__ dst) {
  __shared__ float ls[32][261];
  int b = blockIdx.x, tid = threadIdx.x;
  int i = 0;
  #pragma unroll
  for (int t = 1; t < 10; ++t) if (b >= a.ksbase[t]) i = t;
  int ks = b - a.ksbase[i];
  int KS = a.KS[i];
  const float* src = a.src[i] + (size_t)ks * 32 * 256;
  #pragma unroll
  for (int j = 0; j < 8; ++j) {
    int idx = tid + j * 256;           // 2048 float4 = 32 rows x 64
    int row = idx >> 6, col4 = idx & 63;
    float4 v = *(const float4*)(src + (size_t)row * 256 + col4 * 4);
    ls[row][col4 * 4 + 0] = v.x;
    ls[row][col4 * 4 + 1] = v.y;
    ls[row][col4 * 4 + 2] = v.z;
    ls[row][col4 * 4 + 3] = v.w;
  }
  __syncthreads();
  #pragma unroll
  for (int t = 0; t < 4; ++t) {
    int cidx = tid + t * 256;          // 1024 (ct,l) combos
    int ct = cidx >> 6, l = cidx & 63;
    u16 tmp[8];
    #pragma unroll
    for (int j = 0; j < 8; ++j)
      tmp[j] = f2bf(ls[(l >> 4) * 8 + j][ct * 16 + (l & 15)]);
    uint4 pk;
    pk.x = (unsigned)tmp[0] | ((unsigned)tmp[1] << 16);
    pk.y = (unsigned)tmp[2] | ((unsigned)tmp[3] << 16);
    pk.z = (unsigned)tmp[4] | ((unsigned)tmp[5] << 16);
    pk.w = (unsigned)tmp[6] | ((unsigned)tmp[7] << 16);
    *(uint4*)(dst + a.dstoff[i] + (((size_t)(ct * KS + ks) * 64 + l) << 3)) = pk;
  }
}

// ============================================================
// gating: fp64, 128 rows/block, depth-2 register pipeline
// (chunk c+2 in flight through all of iteration c), block atomics.
// ============================================================
__global__ __launch_bounds__(256) void k_gate(
    const float* __restrict__ zg, const float* __restrict__ zn,
    const float* __restrict__ gW, const float* __restrict__ gb,
    int* __restrict__ listpos, double* __restrict__ psum,
    int* __restrict__ lists) {
  __shared__ float xs[32 * 129];
  __shared__ double gwd[512 * 4];
  __shared__ double xr[128 * 4];
  __shared__ int    wcnt[4][4];
  __shared__ double wps[4][4];
  __shared__ int    wbase[4][4];
  int tid = threadIdx.x, lane = tid & 63, wave = tid >> 6;
  int rlocal = tid & 127, khalf = tid >> 7;
  int rowbase = blockIdx.x * 128;
  for (int i = tid; i < 2048; i += 256) gwd[i] = (double)gW[i];
  double l0, l1, l2, l3;
  if (khalf) { l0 = l1 = l2 = l3 = 0.0; }
  else { l0 = (double)gb[0]; l1 = (double)gb[1]; l2 = (double)gb[2]; l3 = (double)gb[3]; }

  int prow = tid >> 3, poff = tid & 7;   // shared by all chunk loads
  const float* rowp = zg + (size_t)(rowbase + prow) * DD;
  const float* rown = zn + (size_t)(rowbase + prow) * DD;

  float4 pfA[4], pfB[4];
  #pragma unroll
  for (int j = 0; j < 4; ++j) {
    int idx = tid + j * 256;
    int row = idx >> 3, off = idx & 7;
    pfA[j] = *(const float4*)(zg + (size_t)(rowbase + row) * DD + off * 4);
    pfB[j] = *(const float4*)(zg + (size_t)(rowbase + row) * DD + 32 + off * 4);
  }

  for (int c = 0; c < 16; ++c) {
    __syncthreads();
    #pragma unroll
    for (int j = 0; j < 4; ++j) {
      int idx = tid + j * 256;
      int row = idx >> 3, off = idx & 7;
      float4 v = pfA[j];
      xs[(off * 4 + 0) * 129 + row] = v.x;
      xs[(off * 4 + 1) * 129 + row] = v.y;
      xs[(off * 4 + 2) * 129 + row] = v.z;
      xs[(off * 4 + 3) * 129 + row] = v.w;
    }
    #pragma unroll
    for (int j = 0; j < 4; ++j) pfA[j] = pfB[j];
    if (c + 2 < 16) {
      const float* src = (c + 2 < 8) ? zg : zn;
      int ko = ((c + 2) & 7) * 32;
      #pragma unroll
      for (int j = 0; j < 4; ++j) {
        int idx = tid + j * 256;
        int row = idx >> 3, off = idx & 7;
        pfB[j] = *(const float4*)(src + (size_t)(rowbase + row) * DD + ko + off * 4);
      }
    }
    __syncthreads();
    const double* gp = gwd + (size_t)(c * 32 + khalf * 16) * 4;
    int xbase = (khalf * 16) * 129 + rlocal;
    #pragma unroll
    for (int i = 0; i < 16; ++i) {
      double x = (double)xs[xbase + i * 129];
      l0 = fma(x, gp[i * 4 + 0], l0);
      l1 = fma(x, gp[i * 4 + 1], l1);
      l2 = fma(x, gp[i * 4 + 2], l2);
      l3 = fma(x, gp[i * 4 + 3], l3);
    }
  }
  (void)rowp; (void)rown; (void)poff;

  // cross-half reduce
  __syncthreads();
  if (khalf) {
    xr[rlocal * 4 + 0] = l0; xr[rlocal * 4 + 1] = l1;
    xr[rlocal * 4 + 2] = l2; xr[rlocal * 4 + 3] = l3;
  }
  __syncthreads();
  int e = -1;
  double p = 0.0;
  if (!khalf) {
    l0 += xr[rlocal * 4 + 0]; l1 += xr[rlocal * 4 + 1];
    l2 += xr[rlocal * 4 + 2]; l3 += xr[rlocal * 4 + 3];
    e = 0; double lm = l0;
    if (l1 > lm) { lm = l1; e = 1; }
    if (l2 > lm) { lm = l2; e = 2; }
    if (l3 > lm) { lm = l3; e = 3; }
    double s = exp(l0 - lm) + exp(l1 - lm) + exp(l2 - lm) + exp(l3 - lm);
    p = 1.0 / s;
  }
  int row = rowbase + rlocal;

  unsigned long long msk[4];
  int cnt[4];
  double pvs[4];
  #pragma unroll
  for (int ee = 0; ee < NE; ++ee) {
    bool mine = (e == ee);
    msk[ee] = __ballot(mine);
    cnt[ee] = __popcll(msk[ee]);
    double pv = mine ? p : 0.0;
    #pragma unroll
    for (int off = 32; off; off >>= 1) pv += __shfl_down(pv, off);
    pvs[ee] = pv;
  }
  if (lane == 0) {
    #pragma unroll
    for (int ee = 0; ee < NE; ++ee) { wcnt[wave][ee] = cnt[ee]; wps[wave][ee] = pvs[ee]; }
  }
  __syncthreads();
  if (tid < NE) {
    int ee = tid;
    int c0 = wcnt[0][ee], c1 = wcnt[1][ee], c2 = wcnt[2][ee], c3 = wcnt[3][ee];
    int tot = c0 + c1 + c2 + c3;
    int base = 0;
    if (tot) {
      base = atomicAdd(&listpos[ee], tot);
      atomicAdd(&psum[ee], wps[0][ee] + wps[1][ee] + wps[2][ee] + wps[3][ee]);
    }
    wbase[0][ee] = base;
    wbase[1][ee] = base + c0;
    wbase[2][ee] = base + c0 + c1;
    wbase[3][ee] = base + c0 + c1 + c2;
  }
  __syncthreads();
  #pragma unroll
  for (int ee = 0; ee < NE; ++ee) {
    if (e == ee) {
      int rank = __popcll(msk[ee] & ((1ull << lane) - 1ull));
      lists[(size_t)ee * BN + wbase[wave][ee] + rank] = row;
    }
  }
}

__global__ void k_finalize(const int* __restrict__ listpos,
                           const double* __restrict__ psum,
                           float* __restrict__ avg, float* __restrict__ aux_out) {
  if (threadIdx.x == 0) {
    double aux = 0.0;
    for (int ee = 0; ee < NE; ++ee) {
      int c = listpos[ee];
      avg[ee] = (c > 0) ? (float)(psum[ee] / (double)c) : 0.0f;
      double u = (double)c / (double)BN;
      aux += u * u;
    }
    *aux_out = (float)(aux * (double)NE);
  }
}

// ============================================================
// MFMA tile core: #pragma unroll 1 + 2-deep B double-buffer
// (caps live B regs at 32 -> no scratch spills).
// ============================================================
template <int KS, int RB>
__device__ __forceinline__ void mfma_gemm_p(const u16* __restrict__ A, int strideA,
                                            const u16* __restrict__ W,
                                            int wave, int lane, f32x4 acc[RB][4]) {
  int q = lane >> 4, m = lane & 15;
  const u16* wb = W + (((size_t)(wave * 4 * KS) * 64 + lane) << 3);
  bf16x8 b0[4], b1[4];
  #pragma unroll
  for (int i = 0; i < 4; ++i)
    b0[i] = *(const bf16x8*)(wb + (((size_t)(i * KS) * 64) << 3));
  #pragma unroll 1
  for (int ks = 0; ks < KS; ks += 2) {
    #pragma unroll
    for (int i = 0; i < 4; ++i)
      b1[i] = *(const bf16x8*)(wb + (((size_t)(i * KS + ks + 1) * 64) << 3));
    bf16x8 a[RB];
    #pragma unroll
    for (int rb = 0; rb < RB; ++rb)
      a[rb] = *(const bf16x8*)(A + (rb * 16 + m) * strideA + ks * 32 + (q << 3));
    #pragma unroll
    for (int i = 0; i < 4; ++i)
      #pragma unroll
      for (int rb = 0; rb < RB; ++rb)
        acc[rb][i] = __builtin_amdgcn_mfma_f32_16x16x32_bf16(a[rb], b0[i], acc[rb][i], 0, 0, 0);
    if (ks + 2 < KS) {
      #pragma unroll
      for (int i = 0; i < 4; ++i)
        b0[i] = *(const bf16x8*)(wb + (((size_t)(i * KS + ks + 2) * 64) << 3));
    }
    #pragma unroll
    for (int rb = 0; rb < RB; ++rb)
      a[rb] = *(const bf16x8*)(A + (rb * 16 + m) * strideA + (ks + 1) * 32 + (q << 3));
    #pragma unroll
    for (int i = 0; i < 4; ++i)
      #pragma unroll
      for (int rb = 0; rb < RB; ++rb)
        acc[rb][i] = __builtin_amdgcn_mfma_f32_16x16x32_bf16(a[rb], b1[i], acc[rb][i], 0, 0, 0);
  }
}

// ============================================================
// Merged expert kernel: interleaved cost-balanced dispatch.
// bid%48: [0,22)=attn [22,32)=concat [32,38)=mul [38,48)=wsum.
// Shared carve: max 25088 u16 = 50.2 KB -> 3 blocks/CU.
// ============================================================
struct ExpArgs {
  const float* zg; const float* zn;
  const u16* CW1; const u16* CW2; const float* cb1; const float* cb2;
  const u16* MW1; const u16* MW2; const float* mb1; const float* mb2;
  const u16* AWQ; const u16* AWK; const u16* AWV;
  const float* abq; const float* abk; const float* abv;
  const u16* WCB; const float* bcomb;
  const u16* WWA; const u16* WWO; const float* wba; const float* wbo;
  const int* listpos; const int* lists; const float* avgp;
  float* out;
};

__global__ __launch_bounds__(256) void k_experts(ExpArgs A) {
  __shared__ __align__(16) u16 smem[25088];
  __shared__ int rl[32];
  int tid = threadIdx.x, lane = tid & 63, wave = tid >> 6;
  int q = lane >> 4, m = lane & 15;
  int grp = blockIdx.x / GRP, sub = blockIdx.x % GRP;

  if (sub < A_END) {
    // ---------------- attention (fc fused) ----------------
    int bidl = grp * 22 + sub;
    int n = A.listpos[2];
    const int* lst = A.lists + 2 * (size_t)BN;
    float scale = A.avgp[2];
    u16* X  = smem;           // 32 vrows x 264
    u16* Mb = smem + 8448;    // 16 rows  x 264
    float bqv[4], bkv[4], bvv[4];
    #pragma unroll
    for (int i = 0; i < 4; ++i) {
      int c = wave * 64 + i * 16 + m;
      bqv[i] = A.abq[c]; bkv[i] = A.abk[c]; bvv[i] = A.abv[c];
    }
    for (int tile = bidl; tile * 16 < n; tile += G_ATTN) {
      int base = tile * 16;
      __syncthreads();
      if (tid < 16) rl[tid] = (base + tid < n) ? lst[base + tid] : -1;
      __syncthreads();
      #pragma unroll
      for (int j = 0; j < 8; ++j) {
        int t = tid + j * 256;
        int v = t >> 6, off = t & 63;
        int r = rl[v >> 1];
        float4 val = make_float4(0.f, 0.f, 0.f, 0.f);
        if (r >= 0)
          val = (v & 1) ? *(const float4*)(A.zn + (size_t)r * DD + off * 4)
                        : *(const float4*)(A.zg + (size_t)r * DD + off * 4);
        ushort4 pk; pk.x = f2bf(val.x); pk.y = f2bf(val.y); pk.z = f2bf(val.z); pk.w = f2bf(val.w);
        *(ushort4*)(X + v * 264 + off * 4) = pk;
      }
      __syncthreads();
      f32x4 qa[2][4] = {};
      mfma_gemm_p<8, 2>(X, 264, A.AWQ, wave, lane, qa);
      #pragma unroll
      for (int rb = 0; rb < 2; ++rb)
        #pragma unroll
        for (int i = 0; i < 4; ++i)
          #pragma unroll
          for (int r = 0; r < 4; ++r) qa[rb][i][r] += bqv[i];
      f32x4 ka[2][4] = {};
      mfma_gemm_p<8, 2>(X, 264, A.AWK, wave, lane, ka);
      #pragma unroll
      for (int rb = 0; rb < 2; ++rb)
        #pragma unroll
        for (int i = 0; i < 4; ++i)
          #pragma unroll
          for (int r = 0; r < 4; ++r) ka[rb][i][r] += bkv[i];
      float C0[2][2], C1[2][2];
      #pragma unroll
      for (int rb = 0; rb < 2; ++rb) {
        #pragma unroll
        for (int pr = 0; pr < 2; ++pr) {
          float p00 = 0.f, p01 = 0.f, p10 = 0.f, p11 = 0.f;
          #pragma unroll
          for (int i = 0; i < 4; ++i) {
            float q0 = qa[rb][i][2 * pr], q1 = qa[rb][i][2 * pr + 1];
            float ke = ka[rb][i][2 * pr], ko = ka[rb][i][2 * pr + 1];
            p00 += q0 * ke; p01 += q0 * ko;
            p10 += q1 * ke; p11 += q1 * ko;
          }
          #pragma unroll
          for (int msk = 1; msk < 16; msk <<= 1) {
            p00 += __shfl_xor(p00, msk);
            p01 += __shfl_xor(p01, msk);
            p10 += __shfl_xor(p10, msk);
            p11 += __shfl_xor(p11, msk);
          }
          float s00 = 1.f / (1.f + __expf((p01 - p00) * 0.125f));
          float s10 = 1.f / (1.f + __expf((p11 - p10) * 0.125f));
          float c0 = 0.5f * (s00 + s10);
          C0[rb][pr] = c0; C1[rb][pr] = 1.f - c0;
        }
      }
      f32x4 va[2][4] = {};
      mfma_gemm_p<8, 2>(X, 264, A.AWV, wave, lane, va);
      #pragma unroll
      for (int rb = 0; rb < 2; ++rb)
        #pragma unroll
        for (int pr = 0; pr < 2; ++pr) {
          int rloc = rb * 8 + q * 2 + pr;
          #pragma unroll
          for (int i = 0; i < 4; ++i) {
            float mv = C0[rb][pr] * va[rb][i][2 * pr]
                     + C1[rb][pr] * va[rb][i][2 * pr + 1] + bvv[i];
            Mb[rloc * 264 + wave * 64 + i * 16 + m] = f2bf(mv);
          }
        }
      __syncthreads();
      f32x4 ac[1][4] = {};
      mfma_gemm_p<8, 1>(Mb, 264, A.WCB, wave, lane, ac);
      #pragma unroll
      for (int i = 0; i < 4; ++i) {
        int c = (wave * 4 + i) * 16 + m;
        float bb = A.bcomb[c];
        #pragma unroll
        for (int r = 0; r < 4; ++r) {
          int row = rl[q * 4 + r];
          if (row >= 0) A.out[(size_t)row * DD + c] = (ac[0][i][r] + bb) * scale;
        }
      }
    }
  } else if (sub < C_END) {
    // ---------------- concat ----------------
    int bidl = grp * 10 + (sub - A_END);
    int n = A.listpos[0];
    const int* lst = A.lists + 0 * (size_t)BN;
    float scale = A.avgp[0];
    u16* X = smem;            // 32 x 520
    u16* H = smem + 16640;    // 32 x 264
    for (int tile = bidl; tile * 32 < n; tile += G_CONCAT) {
      int base = tile * 32;
      __syncthreads();
      if (tid < 32) rl[tid] = (base + tid < n) ? lst[base + tid] : -1;
      __syncthreads();
      #pragma unroll
      for (int j = 0; j < 16; ++j) {
        int t = tid + j * 256;
        int row = t >> 7, off = t & 127;
        int r = rl[row];
        float4 v = make_float4(0.f, 0.f, 0.f, 0.f);
        if (r >= 0)
          v = (off < 64) ? *(const float4*)(A.zg + (size_t)r * DD + off * 4)
                         : *(const float4*)(A.zn + (size_t)r * DD + (off - 64) * 4);
        ushort4 pk; pk.x = f2bf(v.x); pk.y = f2bf(v.y); pk.z = f2bf(v.z); pk.w = f2bf(v.w);
        *(ushort4*)(X + row * 520 + off * 4) = pk;
      }
      __syncthreads();
      f32x4 acc[2][4] = {};
      mfma_gemm_p<16, 2>(X, 520, A.CW1, wave, lane, acc);
      #pragma unroll
      for (int i = 0; i < 4; ++i) {
        int c = (wave * 4 + i) * 16 + m;
        float bb = A.cb1[c];
        #pragma unroll
        for (int rb = 0; rb < 2; ++rb)
          #pragma unroll
          for (int r = 0; r < 4; ++r)
            H[(rb * 16 + q * 4 + r) * 264 + c] = f2bf(fmaxf(acc[rb][i][r] + bb, 0.f));
      }
      __syncthreads();
      f32x4 acc2[2][4] = {};
      mfma_gemm_p<8, 2>(H, 264, A.CW2, wave, lane, acc2);
      #pragma unroll
      for (int i = 0; i < 4; ++i) {
        int c = (wave * 4 + i) * 16 + m;
        float bb = A.cb2[c];
        #pragma unroll
        for (int rb = 0; rb < 2; ++rb)
          #pragma unroll
          for (int r = 0; r < 4; ++r) {
            int row = rl[rb * 16 + q * 4 + r];
            if (row >= 0) A.out[(size_t)row * DD + c] = (acc2[rb][i][r] + bb) * scale;
          }
      }
    }
  } else if (sub < M_END) {
    // ---------------- mul ----------------
    int bidl = grp * 6 + (sub - C_END);
    int n = A.listpos[1];
    const int* lst = A.lists + 1 * (size_t)BN;
    float scale = A.avgp[1];
    u16* X = smem;            // 32 x 264
    u16* H = smem + 8448;     // 32 x 264
    for (int tile = bidl; tile * 32 < n; tile += G_MUL) {
      int base = tile * 32;
      __syncthreads();
      if (tid < 32) rl[tid] = (base + tid < n) ? lst[base + tid] : -1;
      __syncthreads();
      #pragma unroll
      for (int j = 0; j < 8; ++j) {
        int t = tid + j * 256;
        int row = t >> 6, off = t & 63;
        int r = rl[row];
        float4 v = make_float4(0.f, 0.f, 0.f, 0.f);
        if (r >= 0) {
          float4 g = *(const float4*)(A.zg + (size_t)r * DD + off * 4);
          float4 h = *(const float4*)(A.zn + (size_t)r * DD + off * 4);
          v = make_float4(g.x * h.x, g.y * h.y, g.z * h.z, g.w * h.w);
        }
        ushort4 pk; pk.x = f2bf(v.x); pk.y = f2bf(v.y); pk.z = f2bf(v.z); pk.w = f2bf(v.w);
        *(ushort4*)(X + row * 264 + off * 4) = pk;
      }
      __syncthreads();
      f32x4 acc[2][4] = {};
      mfma_gemm_p<8, 2>(X, 264, A.MW1, wave, lane, acc);
      #pragma unroll
      for (int i = 0; i < 4; ++i) {
        int c = (wave * 4 + i) * 16 + m;
        float bb = A.mb1[c];
        #pragma unroll
        for (int rb = 0; rb < 2; ++rb)
          #pragma unroll
          for (int r = 0; r < 4; ++r)
            H[(rb * 16 + q * 4 + r) * 264 + c] = f2bf(fmaxf(acc[rb][i][r] + bb, 0.f));
      }
      __syncthreads();
      f32x4 acc2[2][4] = {};
      mfma_gemm_p<8, 2>(H, 264, A.MW2, wave, lane, acc2);
      #pragma unroll
      for (int i = 0; i < 4; ++i) {
        int c = (wave * 4 + i) * 16 + m;
        float bb = A.mb2[c];
        #pragma unroll
        for (int rb = 0; rb < 2; ++rb)
          #pragma unroll
          for (int r = 0; r < 4; ++r) {
            int row = rl[rb * 16 + q * 4 + r];
            if (row >= 0) A.out[(size_t)row * DD + c] = (acc2[rb][i][r] + bb) * scale;
          }
      }
    }
  } else {
    // ---------------- wsum ----------------
    int bidl = grp * 10 + (sub - M_END);
    int n = A.listpos[3];
    const int* lst = A.lists + 3 * (size_t)BN;
    float scale = A.avgp[3];
    u16* X = smem;            // 32 x 520
    u16* H = smem + 16640;    // 32 x 264
    for (int tile = bidl; tile * 32 < n; tile += G_WSUM) {
      int base = tile * 32;
      __syncthreads();
      if (tid < 32) rl[tid] = (base + tid < n) ? lst[base + tid] : -1;
      __syncthreads();
      #pragma unroll
      for (int j = 0; j < 16; ++j) {
        int t = tid + j * 256;
        int row = t >> 7, off = t & 127;
        int r = rl[row];
        float4 v = make_float4(0.f, 0.f, 0.f, 0.f);
        if (r >= 0)
          v = (off < 64) ? *(const float4*)(A.zg + (size_t)r * DD + off * 4)
                         : *(const float4*)(A.zn + (size_t)r * DD + (off - 64) * 4);
        ushort4 pk; pk.x = f2bf(v.x); pk.y = f2bf(v.y); pk.z = f2bf(v.z); pk.w = f2bf(v.w);
        *(ushort4*)(X + row * 520 + off * 4) = pk;
      }
      __syncthreads();
      f32x4 acc[2][4] = {};
      mfma_gemm_p<16, 2>(X, 520, A.WWA, wave, lane, acc);
      #pragma unroll
      for (int i = 0; i < 4; ++i) {
        int c = (wave * 4 + i) * 16 + m;
        float bb = A.wba[c];
        #pragma unroll
        for (int rb = 0; rb < 2; ++rb)
          #pragma unroll
          for (int r = 0; r < 4; ++r) {
            int vr = rb * 16 + q * 4 + r;
            float al = 1.f / (1.f + __expf(-(acc[rb][i][r] + bb)));
            float xg = bf2f(X[vr * 520 + c]);
            float xn = bf2f(X[vr * 520 + 256 + c]);
            H[vr * 264 + c] = f2bf(al * xg + (1.f - al) * xn);
          }
      }
      __syncthreads();
      f32x4 acc2[2][4] = {};
      mfma_gemm_p<8, 2>(H, 264, A.WWO, wave, lane, acc2);
      #pragma unroll
      for (int i = 0; i < 4; ++i) {
        int c = (wave * 4 + i) * 16 + m;
        float bb = A.wbo[c];
        #pragma unroll
        for (int rb = 0; rb < 2; ++rb)
          #pragma unroll
          for (int r = 0; r < 4; ++r) {
            int row = rl[rb * 16 + q * 4 + r];
            if (row >= 0) A.out[(size_t)row * DD + c] = (acc2[rb][i][r] + bb) * scale;
          }
      }
    }
  }
}

// ============================================================
// launch
// ============================================================
extern "C" void kernel_launch(void* const* d_in, const int* in_sizes, int n_in,
                              void* d_out, int out_size, void* d_ws, size_t ws_size,
                              hipStream_t stream) {
  const float* zg   = (const float*)d_in[0];
  const float* zn   = (const float*)d_in[1];
  const float* gW   = (const float*)d_in[2];
  const float* gb   = (const float*)d_in[3];
  const float* cW1  = (const float*)d_in[4];
  const float* cb1  = (const float*)d_in[5];
  const float* cW2  = (const float*)d_in[6];
  const float* cb2  = (const float*)d_in[7];
  const float* mW1  = (const float*)d_in[8];
  const float* mb1  = (const float*)d_in[9];
  const float* mW2  = (const float*)d_in[10];
  const float* mb2  = (const float*)d_in[11];
  const float* aWq  = (const float*)d_in[12];
  const float* abq  = (const float*)d_in[13];
  const float* aWk  = (const float*)d_in[14];
  const float* abk  = (const float*)d_in[15];
  const float* aWv  = (const float*)d_in[16];
  const float* abv  = (const float*)d_in[17];
  const float* aWo  = (const float*)d_in[18];
  const float* abo  = (const float*)d_in[19];
  const float* aWfc = (const float*)d_in[20];
  const float* abfc = (const float*)d_in[21];
  const float* wWa  = (const float*)d_in[22];
  const float* wba  = (const float*)d_in[23];
  const float* wWo  = (const float*)d_in[24];
  const float* wbo  = (const float*)d_in[25];
  float* out = (float*)d_out;

  char* ws = (char*)d_ws;
  double* psum  = (double*)ws;
  int* listpos  = (int*)(ws + 32);
  float* avg    = (float*)(ws + 48);
  int* lists    = (int*)(ws + 64);
  u16* wsw      = (u16*)(ws + WS_SWZ_OFF);
  float* wcf32  = (float*)(ws + 64);          // transient: overlaps lists[0]
  float* bcomb  = (float*)(ws + BCOMB_OFF);   // persistent

  SwzArgs sa;
  const float* srcs[10] = {cW1, cW2, mW1, mW2, aWq, aWk, aWv, wcf32, wWa, wWo};
  const int   kss[10]  = {16, 8, 8, 8, 8, 8, 8, 8, 16, 8};
  const int   offs[10] = {OFF_CW1, OFF_CW2, OFF_MW1, OFF_MW2, OFF_AWQ, OFF_AWK,
                          OFF_AWV, OFF_WCB, OFF_WWA, OFF_WWO};
  int ks_acc = 0;
  for (int i = 0; i < 10; ++i) {
    sa.src[i] = srcs[i];
    sa.KS[i] = kss[i];
    sa.dstoff[i] = offs[i];
    sa.ksbase[i] = ks_acc;
    ks_acc += kss[i];
  }

  ExpArgs ea;
  ea.zg = zg; ea.zn = zn;
  ea.CW1 = wsw + OFF_CW1; ea.CW2 = wsw + OFF_CW2; ea.cb1 = cb1; ea.cb2 = cb2;
  ea.MW1 = wsw + OFF_MW1; ea.MW2 = wsw + OFF_MW2; ea.mb1 = mb1; ea.mb2 = mb2;
  ea.AWQ = wsw + OFF_AWQ; ea.AWK = wsw + OFF_AWK; ea.AWV = wsw + OFF_AWV;
  ea.abq = abq; ea.abk = abk; ea.abv = abv;
  ea.WCB = wsw + OFF_WCB; ea.bcomb = bcomb;
  ea.WWA = wsw + OFF_WWA; ea.WWO = wsw + OFF_WWO; ea.wba = wba; ea.wbo = wbo;
  ea.listpos = listpos; ea.lists = lists; ea.avgp = avg;
  ea.out = out;

  hipLaunchKernelGGL(k_init, dim3(1), dim3(64), 0, stream, listpos, psum);
  hipLaunchKernelGGL(k_wcomb, dim3(257), dim3(256), 0, stream,
                     aWo, abo, aWfc, abfc, wcf32, bcomb);
  hipLaunchKernelGGL(k_swz, dim3(96), dim3(256), 0, stream, sa, wsw);
  hipLaunchKernelGGL(k_gate, dim3(BN / 128), dim3(256), 0, stream,
                     zg, zn, gW, gb, listpos, psum, lists);
  hipLaunchKernelGGL(k_finalize, dim3(1), dim3(64), 0, stream,
                     listpos, psum, avg, out + (size_t)BN * DD);
  hipLaunchKernelGGL(k_experts, dim3(G_TOTAL), dim3(256), 0, stream, ea);
}